// Round 5
// baseline (1081.754 us; speedup 1.0000x reference)
//
#include <hip/hip_runtime.h>
#include <hip/hip_bf16.h>
#include <cstdint>
#include <cstddef>

// Problem dims
#define Bsz 512
#define Nsq 50
#define Hd  256
#define VM1 40000
static constexpr float SCALE_C = 0.0625f;   // 1/sqrt(256)
static constexpr float NEG_C   = -1.0e12f;

typedef __attribute__((ext_vector_type(8))) short bf16x8;
typedef __attribute__((ext_vector_type(4))) float f32x4;

__device__ __forceinline__ float sigmoidf_(float x) { return 1.0f / (1.0f + __expf(-x)); }
__device__ __forceinline__ float tanh_fast(float x) {
  float t = fminf(fmaxf(2.0f * x, -60.0f), 60.0f);
  float e = __expf(t);
  return (e - 1.0f) / (e + 1.0f);
}
__device__ __forceinline__ ushort f2b(float x) {   // fp32 -> bf16 (RNE)
  union { float f; uint32_t u; } c; c.f = x;
  uint32_t r = (c.u + 0x7fffu + ((c.u >> 16) & 1u)) >> 16;
  return (ushort)r;
}

// ---------------------------------------------------------------- TAB (50x256)
__global__ void build_tab(float* __restrict__ TAB) {
  int idx = blockIdx.x * 256 + threadIdx.x;
  int pos = idx >> 8, j = idx & 255;
  int pair = j >> 1;
  float expo = (2.0f * (float)pair) / 256.0f;
  float inv = powf(10000.0f, -expo);
  float ang = (float)pos * inv;
  TAB[idx] = (j & 1) ? cosf(ang) : sinf(ang);
}

// ------------------------------------------------- last[b], sr_l_1 = seq1[b,last]
__global__ __launch_bounds__(256) void last_srl_kernel(const int* __restrict__ mask,
    const float* __restrict__ seq1, int* __restrict__ lastp, float* __restrict__ srl) {
  int b = blockIdx.x, tid = threadIdx.x;
  __shared__ int ls;
  if (tid == 0) {
    int c = 0;
    for (int t = 0; t < Nsq; ++t) c += mask[b * Nsq + t];
    ls = c - 1;
    lastp[b] = c - 1;
  }
  __syncthreads();
  srl[b * Hd + tid] = seq1[((size_t)b * Nsq + ls) * Hd + tid];
}

// ---------------------------------------------------------------- fp32 GEMM (small shapes only)
template <int BT, int BIAS>
__global__ __launch_bounds__(256) void gemm_tile(const float* __restrict__ A,
    const float* __restrict__ B, const float* __restrict__ bias,
    float* __restrict__ C, int M, int N, int K) {
  __shared__ float As[16][132];
  __shared__ float Bs[16][68];
  int bm = blockIdx.y * 128, bn = blockIdx.x * 64;
  int tid = threadIdx.x;
  int tm = (tid >> 4) << 3;
  int tn = (tid & 15) << 2;
  float acc[8][4] = {};
  for (int k0 = 0; k0 < K; k0 += 16) {
#pragma unroll
    for (int u = 0; u < 8; ++u) {
      int i = tid + u * 256;
      int kk = i & 15, m = i >> 4;
      As[kk][m] = A[(size_t)(bm + m) * K + (k0 + kk)];
    }
#pragma unroll
    for (int u = 0; u < 4; ++u) {
      int i = tid + u * 256;
      if (BT) {
        int kk = i & 15, n = i >> 4;
        Bs[kk][n] = B[(size_t)(bn + n) * K + (k0 + kk)];
      } else {
        int n = i & 63, kk = i >> 6;
        Bs[kk][n] = B[(size_t)(k0 + kk) * N + (bn + n)];
      }
    }
    __syncthreads();
#pragma unroll
    for (int kk = 0; kk < 16; ++kk) {
      float a[8], bb[4];
#pragma unroll
      for (int r = 0; r < 8; ++r) a[r] = As[kk][tm + r];
#pragma unroll
      for (int c = 0; c < 4; ++c) bb[c] = Bs[kk][tn + c];
#pragma unroll
      for (int r = 0; r < 8; ++r)
#pragma unroll
        for (int c = 0; c < 4; ++c) acc[r][c] += a[r] * bb[c];
    }
    __syncthreads();
  }
#pragma unroll
  for (int r = 0; r < 8; ++r) {
    size_t row = (size_t)(bm + tm + r) * N + bn;
#pragma unroll
    for (int c = 0; c < 4; ++c) {
      float v = acc[r][c];
      if (BIAS) v += bias[bn + tn + c];
      C[row + tn + c] = v;
    }
  }
}

// ---------------------------------------------------------------- bf16 MFMA GEMM
// C[M,N] fp32 = A_bf[M,K] @ (BT ? B_bf[N,K]^T : B_bf[K,N]) (+epilogue)
// tile 128x128, BK=32, 256 threads = 4 waves (each 64x64 quadrant, 4x4 frags of 16x16x32).
// EPI: 0 = none; 1 = +bias[col]; 2 = +TAB[abs(t-last[b])*256+col] (bias ptr = TAB, rows are b*50+t);
//      3 = relu(bias[col] + addsrc[row][col] + out).
template <int BT, int EPI>
__global__ __launch_bounds__(256) void mfma_gemm(const ushort* __restrict__ A,
    const ushort* __restrict__ B, const float* __restrict__ bias,
    float* __restrict__ C, int M, int N, int K,
    const int* __restrict__ lastp, const float* __restrict__ addsrc) {
  __shared__ ushort Asm[128][40];   // [m][k], +8 pad
  __shared__ ushort Bsm[128][40];   // [n][k]
  int tid = threadIdx.x;
  int bm = blockIdx.y * 128, bn = blockIdx.x * 128;
  int lane = tid & 63, wave = tid >> 6;
  int quad = lane >> 4, l16 = lane & 15;
  int wm = (wave >> 1) * 64, wn = (wave & 1) * 64;
  f32x4 acc[4][4] = {};
  for (int k0 = 0; k0 < K; k0 += 32) {
#pragma unroll
    for (int u = 0; u < 2; ++u) {               // A: 128x32, 16B per thread x2
      int idx = tid + u * 256;
      int r = idx >> 2, kc = (idx & 3) * 8;
      uint4 v = *(const uint4*)(A + (size_t)(bm + r) * K + k0 + kc);
      *(uint4*)&Asm[r][kc] = v;
    }
    if (BT) {
#pragma unroll
      for (int u = 0; u < 2; ++u) {
        int idx = tid + u * 256;
        int r = idx >> 2, kc = (idx & 3) * 8;
        uint4 v = make_uint4(0u, 0u, 0u, 0u);
        if (bn + r < N) v = *(const uint4*)(B + (size_t)(bn + r) * K + k0 + kc);
        *(uint4*)&Bsm[r][kc] = v;
      }
    } else {
#pragma unroll
      for (int u = 0; u < 8; ++u) {             // transpose-stage: 2 n per thread
        int idx = tid + u * 256;
        int n2 = (idx & 63) * 2, kk = idx >> 6;
        uint v = *(const uint*)(B + (size_t)(k0 + kk) * N + bn + n2);
        Bsm[n2][kk] = (ushort)(v & 0xffffu);
        Bsm[n2 + 1][kk] = (ushort)(v >> 16);
      }
    }
    __syncthreads();
    bf16x8 af[4], bfr[4];
#pragma unroll
    for (int f = 0; f < 4; ++f) af[f] = *(const bf16x8*)&Asm[wm + f * 16 + l16][quad * 8];
#pragma unroll
    for (int f = 0; f < 4; ++f) bfr[f] = *(const bf16x8*)&Bsm[wn + f * 16 + l16][quad * 8];
#pragma unroll
    for (int mf = 0; mf < 4; ++mf)
#pragma unroll
      for (int nf = 0; nf < 4; ++nf)
        acc[mf][nf] = __builtin_amdgcn_mfma_f32_16x16x32_bf16(af[mf], bfr[nf], acc[mf][nf], 0, 0, 0);
    __syncthreads();
  }
#pragma unroll
  for (int mf = 0; mf < 4; ++mf) {
#pragma unroll
    for (int r = 0; r < 4; ++r) {
      int row = bm + wm + mf * 16 + quad * 4 + r;
      size_t rowo = (size_t)row * N;
      int dtab = 0;
      if (EPI == 2) {
        int bb = row / Nsq;                 // rows are b*50+t
        int tt = row - bb * Nsq;
        dtab = abs(tt - lastp[bb]) << 8;    // TAB row offset (x256 cols)
      }
#pragma unroll
      for (int nf = 0; nf < 4; ++nf) {
        int col = bn + wn + nf * 16 + l16;
        if (col < N) {
          float v = acc[mf][nf][r];
          if (EPI == 1 || EPI == 3) v += bias[col];
          if (EPI == 2) v += bias[dtab + col];            // bias ptr = TAB
          if (EPI == 3) v = fmaxf(v + addsrc[rowo + col], 0.0f);
          C[rowo + col] = v;
        }
      }
    }
  }
}

// ---------------------------------------------------------------- casts
__global__ void cast_f2b_k(const float* __restrict__ s, ushort* __restrict__ d, int n4) {
  int i = blockIdx.x * 256 + threadIdx.x;
  if (i >= n4) return;
  const float4 v = ((const float4*)s)[i];
  ushort4 o; o.x = f2b(v.x); o.y = f2b(v.y); o.z = f2b(v.z); o.w = f2b(v.w);
  ((ushort4*)d)[i] = o;
}

struct Cast7 { const float* s[7]; ushort* d[7]; };
__global__ void cast7_k(Cast7 p) {
  int m = blockIdx.y;
  int i = blockIdx.x * 256 + threadIdx.x;
  const float4 v = ((const float4*)p.s[m])[i];
  ushort4 o; o.x = f2b(v.x); o.y = f2b(v.y); o.z = f2b(v.z); o.w = f2b(v.w);
  ((ushort4*)p.d[m])[i] = o;
}

// ---------------------------------------------------------------- misc elementwise
__global__ void add_tab0(float* __restrict__ q) {
  int idx = blockIdx.x * 256 + threadIdx.x;
  q[idx] += (float)(threadIdx.x & 1);         // TAB[0]: sin(0)=0, cos(0)=1
}

__global__ void mask_mul_dual(const float* __restrict__ x, const int* __restrict__ m,
                              float* __restrict__ y, ushort* __restrict__ yb) {
  int idx = blockIdx.x * 256 + threadIdx.x;
  float v = m[idx >> 8] ? x[idx] : 0.0f;
  y[idx] = v;
  yb[idx] = f2b(v);
}

// ---------------------------------------------------------------- GRU layer (MFMA, reg-resident weights)
// 256 blocks x 8 waves (512 thr), 2 samples/block (all 256 CUs active, 2 waves/SIMD).
// Wave w owns N-slice [w*96, +96): bw[48] = 192 regs + 24 acc -> fits 256-reg cap.
// gi prefetched one timestep ahead into registers (proven pattern). h carry in register.
__global__ __launch_bounds__(512, 2) void gru_mfma8_kernel(const float* __restrict__ gi,
    const ushort* __restrict__ whhb, const float* __restrict__ bhh,
    ushort* __restrict__ ysb, const int* __restrict__ mask) {
  __shared__ ushort hbf[16][264];   // bf16 h (MFMA A-source), rows 0..1 valid, +8 pad
  __shared__ float  ghs[2][768];    // gh fp32 [sample][n] (conflict-free both sides)
  int tid = threadIdx.x;
  int lane = tid & 63, wave = tid >> 6;
  int quad = lane >> 4, l16 = lane & 15;
  int s0 = blockIdx.x * 2;

  for (int i = tid; i < 16 * 264 / 2; i += 512) ((uint*)hbf)[i] = 0u;

  // reg-resident whh slice: wave owns n in [wave*96, +96); frag (nf,kf):
  // B-frag lane l16 = n, quad*8+j = k  (same layout as proven mfma_gemm B-read)
  bf16x8 bw[48];
  const ushort* wb = whhb + (size_t)(wave * 96 + l16) * 256 + quad * 8;
#pragma unroll
  for (int f = 0; f < 48; ++f) {
    int nf = f >> 3, kf = f & 7;
    bw[f] = *(const bf16x8*)(wb + nf * (16 * 256) + kf * 32);
  }

  // elementwise mapping: thread handles sample sh = tid>>8, dim d = tid&255
  int d = tid & 255, sh = tid >> 8;
  float bh0 = bhh[d], bh1 = bhh[256 + d], bh2 = bhh[512 + d];
  const float* gib = gi + (size_t)(s0 + sh) * Nsq * 768;
  float g0 = gib[d], g1 = gib[256 + d], g2 = gib[512 + d];
  float hreg = 0.0f;
  __syncthreads();

  for (int t = 0; t < Nsq; ++t) {
    int tn = (t + 1 < Nsq) ? t + 1 : t;
    float p0 = gib[tn * 768 + d], p1 = gib[tn * 768 + 256 + d], p2 = gib[tn * 768 + 512 + d];

    // ---- gh = h @ whh_slice^T  (A rows = samples; only rows 0..1 nonzero)
    f32x4 acc[6] = {};
#pragma unroll
    for (int kf = 0; kf < 8; ++kf) {
      bf16x8 a = *(const bf16x8*)&hbf[l16][kf * 32 + quad * 8];
#pragma unroll
      for (int nf = 0; nf < 6; ++nf)
        acc[nf] = __builtin_amdgcn_mfma_f32_16x16x32_bf16(a, bw[nf * 8 + kf], acc[nf], 0, 0, 0);
    }
    if (quad == 0) {
#pragma unroll
      for (int nf = 0; nf < 6; ++nf) {
        int n = wave * 96 + nf * 16 + l16;     // C row = sample, col = l16
        ghs[0][n] = acc[nf][0];
        ghs[1][n] = acc[nf][1];
      }
    }
    __syncthreads();

    // ---- elementwise: 1 (sample, dim) unit per thread
    {
      float rr = sigmoidf_(g0 + ghs[sh][d] + bh0);
      float zz = sigmoidf_(g1 + ghs[sh][256 + d] + bh1);
      float nn = tanh_fast(g2 + rr * (ghs[sh][512 + d] + bh2));
      float h2 = (1.0f - zz) * nn + zz * hreg;
      hreg = h2;
      hbf[sh][d] = f2b(h2);
      float ov = h2;
      if (mask) ov = mask[(s0 + sh) * Nsq + t] ? h2 : 0.0f;
      ysb[((size_t)(s0 + sh) * Nsq + t) * 256 + d] = f2b(ov);
    }
    g0 = p0; g1 = p1; g2 = p2;
    __syncthreads();
  }
}

// ---------------------------------------------------------------- MFMA attention
// One block per batch sample, 256 threads = 4 waves.
// S = Q[50,256] K^T[*,256] via MFMA; masked softmax; O = P V via MFMA.
// NMEM = 0 (attn1) or 8 (attn2: mem rows prepended). Output bf16, mask-zeroed.
template <int NMEM>
__global__ __launch_bounds__(256) void attn_mfma(const float* __restrict__ q1,
    const float* __restrict__ kseq, const float* __restrict__ vseq,
    const float* __restrict__ kmem, const float* __restrict__ vmem,
    const int* __restrict__ mask, ushort* __restrict__ out) {
  constexpr int NK = NMEM + Nsq;            // valid K/V rows (50 or 58)
  __shared__ ushort KV[64][264];            // Q -> K -> V staging (bf16)
  __shared__ float Ss[64][66];              // scores fp32
  __shared__ ushort Ps[64][72];             // probabilities bf16
  __shared__ int msk[64];
  int tid = threadIdx.x;
  int lane = tid & 63, wave = tid >> 6;
  int quad = lane >> 4, l16 = lane & 15;
  int b = blockIdx.x;

  if (tid < 64) msk[tid] = (tid < Nsq) ? mask[b * Nsq + tid] : 0;

  // ---- stage Q (rows t<50, else 0)
#pragma unroll
  for (int it = 0; it < 16; ++it) {
    int idx = tid + it * 256;
    int r = idx >> 6, c4 = (idx & 63) * 4;
    float4 v = make_float4(0.f, 0.f, 0.f, 0.f);
    if (r < Nsq) v = *(const float4*)(q1 + ((size_t)(b * Nsq + r)) * 256 + c4);
    ushort4 o; o.x = f2b(v.x); o.y = f2b(v.y); o.z = f2b(v.z); o.w = f2b(v.w);
    *(ushort4*)&KV[r][c4] = o;
  }
  __syncthreads();
  // Q A-frags: wave w owns t rows [w*16, w*16+16)
  bf16x8 qa[8];
#pragma unroll
  for (int kf = 0; kf < 8; ++kf)
    qa[kf] = *(const bf16x8*)&KV[wave * 16 + l16][kf * 32 + quad * 8];
  __syncthreads();

  // ---- stage K (rows: [0,NMEM) mem, [NMEM,NK) seq, else 0)
#pragma unroll
  for (int it = 0; it < 16; ++it) {
    int idx = tid + it * 256;
    int r = idx >> 6, c4 = (idx & 63) * 4;
    float4 v = make_float4(0.f, 0.f, 0.f, 0.f);
    if (r < NK) {
      const float* src = (NMEM > 0 && r < NMEM)
          ? (kmem + (size_t)r * 256 + c4)
          : (kseq + ((size_t)(b * Nsq + (r - NMEM))) * 256 + c4);
      v = *(const float4*)src;
    }
    ushort4 o; o.x = f2b(v.x); o.y = f2b(v.y); o.z = f2b(v.z); o.w = f2b(v.w);
    *(ushort4*)&KV[r][c4] = o;
  }
  __syncthreads();

  // ---- S = Q K^T  (wave w: rows [w*16, +16) x all 64 cols)
  {
    f32x4 acc[4] = {};
#pragma unroll
    for (int kf = 0; kf < 8; ++kf) {
#pragma unroll
      for (int nf = 0; nf < 4; ++nf) {
        bf16x8 bf = *(const bf16x8*)&KV[nf * 16 + l16][kf * 32 + quad * 8];
        acc[nf] = __builtin_amdgcn_mfma_f32_16x16x32_bf16(qa[kf], bf, acc[nf], 0, 0, 0);
      }
    }
#pragma unroll
    for (int nf = 0; nf < 4; ++nf)
#pragma unroll
      for (int r = 0; r < 4; ++r)
        Ss[wave * 16 + quad * 4 + r][nf * 16 + l16] = acc[nf][r];
  }
  __syncthreads();

  // ---- stage V over K region (all threads) ...
#pragma unroll
  for (int it = 0; it < 16; ++it) {
    int idx = tid + it * 256;
    int r = idx >> 6, c4 = (idx & 63) * 4;
    float4 v = make_float4(0.f, 0.f, 0.f, 0.f);
    if (r < NK) {
      const float* src = (NMEM > 0 && r < NMEM)
          ? (vmem + (size_t)r * 256 + c4)
          : (vseq + ((size_t)(b * Nsq + (r - NMEM))) * 256 + c4);
      v = *(const float4*)src;
    }
    ushort4 o; o.x = f2b(v.x); o.y = f2b(v.y); o.z = f2b(v.z); o.w = f2b(v.w);
    *(ushort4*)&KV[r][c4] = o;
  }
  // ... while lane-per-row softmax runs on wave 0
  if (tid < 64) {
    int t = tid;
    if (t < Nsq) {
      float m = -1e30f;
      for (int j = 0; j < NK; ++j) {
        bool ok = (j < NMEM) || (((j - NMEM) <= t) && (msk[j - NMEM] != 0));
        if (ok) m = fmaxf(m, Ss[t][j] * SCALE_C);
      }
      float sum = 0.0f;
      for (int j = 0; j < NK; ++j) {
        bool ok = (j < NMEM) || (((j - NMEM) <= t) && (msk[j - NMEM] != 0));
        if (ok) sum += __expf(Ss[t][j] * SCALE_C - m);
      }
      float inv = 1.0f / sum;
      for (int j = 0; j < 64; ++j) {
        float p = 0.0f;
        if (j < NK) {
          bool ok = (j < NMEM) || (((j - NMEM) <= t) && (msk[j - NMEM] != 0));
          if (ok) p = __expf(Ss[t][j] * SCALE_C - m) * inv;
        }
        Ps[t][j] = f2b(p);
      }
    } else {
      for (int j = 0; j < 64; ++j) Ps[t][j] = 0;
    }
  }
  __syncthreads();

  // ---- O = P V  (wave w: all 64 t-rows x h in [w*64, +64))
  {
    f32x4 o[4][4] = {};
#pragma unroll
    for (int kf = 0; kf < 2; ++kf) {
      bf16x8 pa[4];
#pragma unroll
      for (int mf = 0; mf < 4; ++mf)
        pa[mf] = *(const bf16x8*)&Ps[mf * 16 + l16][kf * 32 + quad * 8];
#pragma unroll
      for (int nf = 0; nf < 4; ++nf) {
        int h = wave * 64 + nf * 16 + l16;
        ushort e0 = KV[kf * 32 + quad * 8 + 0][h];
        ushort e1 = KV[kf * 32 + quad * 8 + 1][h];
        ushort e2 = KV[kf * 32 + quad * 8 + 2][h];
        ushort e3 = KV[kf * 32 + quad * 8 + 3][h];
        ushort e4 = KV[kf * 32 + quad * 8 + 4][h];
        ushort e5 = KV[kf * 32 + quad * 8 + 5][h];
        ushort e6 = KV[kf * 32 + quad * 8 + 6][h];
        ushort e7 = KV[kf * 32 + quad * 8 + 7][h];
        bf16x8 vb = {(short)e0, (short)e1, (short)e2, (short)e3,
                     (short)e4, (short)e5, (short)e6, (short)e7};
#pragma unroll
        for (int mf = 0; mf < 4; ++mf)
          o[mf][nf] = __builtin_amdgcn_mfma_f32_16x16x32_bf16(pa[mf], vb, o[mf][nf], 0, 0, 0);
      }
    }
#pragma unroll
    for (int mf = 0; mf < 4; ++mf) {
#pragma unroll
      for (int r = 0; r < 4; ++r) {
        int t = mf * 16 + quad * 4 + r;
        if (t < Nsq) {
          int zero = (msk[t] == 0);
#pragma unroll
          for (int nf = 0; nf < 4; ++nf) {
            int h = wave * 64 + nf * 16 + l16;
            float val = zero ? 0.0f : o[mf][nf][r];
            out[((size_t)(b * Nsq + t)) * 256 + h] = f2b(val);
          }
        }
      }
    }
  }
}

// ---------------------------------------------------------------- alpha + sess (→ sesscat)
__global__ __launch_bounds__(256) void alpha_sess_kernel(const float* __restrict__ att,
    const float* __restrict__ W3, const float* __restrict__ q11,
    const float* __restrict__ se1, const int* __restrict__ mask,
    const float* __restrict__ srl, float* __restrict__ sesscat) {
  int b = blockIdx.x, tid = threadIdx.x;
  __shared__ float red[256];
  __shared__ float ash[50];
  red[tid] = q11[b * Hd + tid] * W3[256 + tid];
  __syncthreads();
  for (int s = 128; s; s >>= 1) { if (tid < s) red[tid] += red[tid + s]; __syncthreads(); }
  float cq = red[0];
  float aval = 0.0f;
  if (tid < 50) {
    float s = cq;
    const float* ar = att + ((size_t)b * Nsq + tid) * Hd;
    for (int hh = 0; hh < 256; ++hh) s += ar[hh] * W3[hh];
    aval = mask[b * Nsq + tid] ? s : NEG_C;
  }
  if (tid < 64) {
    float s = (tid < 50) ? aval : NEG_C;
    float m = s;
    for (int off = 32; off; off >>= 1) m = fmaxf(m, __shfl_xor(m, off));
    float e = expf(s - m);
    float sum = e;
    for (int off = 32; off; off >>= 1) sum += __shfl_xor(sum, off);
    if (tid < 50) ash[tid] = e / sum;
  }
  __syncthreads();
  float acc = 0.0f;
  const float* se = se1 + (size_t)b * Nsq * Hd;
  for (int t = 0; t < Nsq; ++t) acc += ash[t] * se[t * 256 + tid];
  sesscat[(size_t)b * 512 + tid] = acc;
  sesscat[(size_t)b * 512 + 256 + tid] = srl[b * Hd + tid];
}

// ---------------------------------------------------------------- beta + boundary (fp32)
__global__ __launch_bounds__(256) void beta_kernel(const float* __restrict__ sess2,
    const float* __restrict__ Wt1, const float* __restrict__ bt1,
    const float* __restrict__ Wt2, float* __restrict__ beta, float* __restrict__ bnd) {
  int b = blockIdx.x, tid = threadIdx.x;
  __shared__ float xs[256];
  __shared__ float r0[256], r1[256];
  xs[tid] = sess2[b * Hd + tid];
  __syncthreads();
  float hsum = bt1[tid];
  for (int k = 0; k < 256; ++k) hsum += xs[k] * Wt1[k * 256 + tid];
  float hid = fmaxf(hsum, 0.0f);
  r0[tid] = hid * Wt2[tid * 2 + 0];
  r1[tid] = hid * Wt2[tid * 2 + 1];
  __syncthreads();
  for (int s = 128; s; s >>= 1) {
    if (tid < s) { r0[tid] += r0[tid + s]; r1[tid] += r1[tid + s]; }
    __syncthreads();
  }
  if (tid == 0) {
    float t0 = r0[0], t1 = r1[0];
    float m = fmaxf(t0, t1);
    float e0 = expf(t0 - m), e1 = expf(t1 - m);
    float bb0 = e0 / (e0 + e1), bb1 = e1 / (e0 + e1);
    beta[b * 2] = bb0; beta[b * 2 + 1] = bb1;
    atomicAdd(bnd, fabsf(bb0 - bb1) * (1.0f / 512.0f));
  }
}

// ---------------------------------------------------------------- fused score softmax + final
// One block (1024 thr) per row b. Flags packed once into a 5 KB LDS bitmask (pass 1);
// passes 2-3 never re-read flag. No intermediate stores: pass 2 only sums, pass 3
// recomputes the exp and writes fin directly. Score row (160 KB) stays L3-resident
// across passes. Each element contributes to exactly one side (exp(NEG-M) == 0).
__global__ __launch_bounds__(1024) void score_final_fused(float* __restrict__ score,
    const int* __restrict__ flag, const float* __restrict__ beta) {
  int b = blockIdx.x, tid = threadIdx.x;
  float4* sr = (float4*)(score + (size_t)b * VM1);
  const int4* fr = (const int4*)(flag + (size_t)b * VM1);
  constexpr int NV = VM1 / 4;        // 10000 int4/float4 groups
  constexpr int NW = (NV + 7) / 8;   // 1250 bitmask words (4 bits per group)

  __shared__ uint bits[NW];
  __shared__ float red[1024], red2[1024];

  for (int i = tid; i < NW; i += 1024) bits[i] = 0u;
  __syncthreads();

  // ---- pass 1: per-side maxes + flag bitmask
  float mi = -INFINITY, me = -INFINITY;
  for (int i = tid; i < NV; i += 1024) {
    float4 s = sr[i];
    int4 f = fr[i];
    uint nib = (f.x ? 1u : 0u) | (f.y ? 2u : 0u) | (f.z ? 4u : 0u) | (f.w ? 8u : 0u);
    if (nib) atomicOr(&bits[i >> 3], nib << ((i & 7) * 4));
    if (f.x) mi = fmaxf(mi, s.x); else me = fmaxf(me, s.x);
    if (f.y) mi = fmaxf(mi, s.y); else me = fmaxf(me, s.y);
    if (f.z) mi = fmaxf(mi, s.z); else me = fmaxf(me, s.z);
    if (f.w) mi = fmaxf(mi, s.w); else me = fmaxf(me, s.w);
  }
  red[tid] = mi; red2[tid] = me;
  __syncthreads();
  for (int s = 512; s; s >>= 1) {
    if (tid < s) { red[tid] = fmaxf(red[tid], red[tid + s]); red2[tid] = fmaxf(red2[tid], red2[tid + s]); }
    __syncthreads();
  }
  float Mi = red[0], Me = red2[0];
  __syncthreads();

  // ---- pass 2: per-side sums (no stores; score re-read from L3)
  float si = 0.0f, se = 0.0f;
  for (int i = tid; i < NV; i += 1024) {
    float4 s = sr[i];
    uint nib = bits[i >> 3] >> ((i & 7) * 4);
    float e0 = __expf(s.x - ((nib & 1u) ? Mi : Me));
    float e1 = __expf(s.y - ((nib & 2u) ? Mi : Me));
    float e2 = __expf(s.z - ((nib & 4u) ? Mi : Me));
    float e3 = __expf(s.w - ((nib & 8u) ? Mi : Me));
    si += ((nib & 1u) ? e0 : 0.0f) + ((nib & 2u) ? e1 : 0.0f)
        + ((nib & 4u) ? e2 : 0.0f) + ((nib & 8u) ? e3 : 0.0f);
    se += ((nib & 1u) ? 0.0f : e0) + ((nib & 2u) ? 0.0f : e1)
        + ((nib & 4u) ? 0.0f : e2) + ((nib & 8u) ? 0.0f : e3);
  }
  red[tid] = si; red2[tid] = se;
  __syncthreads();
  for (int s = 512; s; s >>= 1) {
    if (tid < s) { red[tid] += red[tid + s]; red2[tid] += red2[tid + s]; }
    __syncthreads();
  }
  float c0 = beta[b * 2] / red[0];
  float c1 = beta[b * 2 + 1] / red2[0];
  __syncthreads();

  // ---- pass 3: recompute exp, write fin in place
  for (int i = tid; i < NV; i += 1024) {
    float4 s = sr[i];
    uint nib = bits[i >> 3] >> ((i & 7) * 4);
    s.x = ((nib & 1u) ? c0 : c1) * __expf(s.x - ((nib & 1u) ? Mi : Me));
    s.y = ((nib & 2u) ? c0 : c1) * __expf(s.y - ((nib & 2u) ? Mi : Me));
    s.z = ((nib & 4u) ? c0 : c1) * __expf(s.z - ((nib & 4u) ? Mi : Me));
    s.w = ((nib & 8u) ? c0 : c1) * __expf(s.w - ((nib & 8u) ? Mi : Me));
    sr[i] = s;
  }
}

// ================================================================ launch
extern "C" void kernel_launch(void* const* d_in, const int* in_sizes, int n_in,
                              void* d_out, int out_size, void* d_ws, size_t ws_size,
                              hipStream_t stream) {
  const float* seq1  = (const float*)d_in[0];
  const float* seq2  = (const float*)d_in[1];
  const int*   mask  = (const int*)d_in[2];
  const int*   iflag = (const int*)d_in[3];
  const float* wih0  = (const float*)d_in[4];
  const float* whh0  = (const float*)d_in[5];
  const float* bih0  = (const float*)d_in[6];
  const float* bhh0  = (const float*)d_in[7];
  const float* wih1  = (const float*)d_in[8];
  const float* whh1  = (const float*)d_in[9];
  const float* bih1  = (const float*)d_in[10];
  const float* bhh1  = (const float*)d_in[11];
  const float* Wq1   = (const float*)d_in[12];
  const float* Wk1   = (const float*)d_in[13];
  const float* Wv1   = (const float*)d_in[14];
  const float* Wk2   = (const float*)d_in[16];
  const float* Wv2   = (const float*)d_in[17];
  const float* Wffn1 = (const float*)d_in[18];
  const float* bffn1 = (const float*)d_in[19];
  const float* Wffn2 = (const float*)d_in[20];
  const float* bffn2 = (const float*)d_in[21];
  const float* Wone  = (const float*)d_in[22];
  const float* bone  = (const float*)d_in[23];
  const float* W3    = (const float*)d_in[24];
  const float* Wtr   = (const float*)d_in[25];
  const float* btr   = (const float*)d_in[26];
  const float* Wt1   = (const float*)d_in[27];
  const float* bt1   = (const float*)d_in[28];
  const float* Wt2   = (const float*)d_in[29];
  const float* memk  = (const float*)d_in[30];
  const float* memv  = (const float*)d_in[31];
  const float* emb1  = (const float*)d_in[32];
  float* out = (float*)d_out;

  // Workspace layout (byte offsets, all 16B-aligned). Total ≈ 214.1 MB.
  char* wsb = (char*)d_ws;
  float*  TAB    = (float*)(wsb + 0);            // 51,200
  int*    lastp  = (int*)  (wsb + 51200);        // 2,048
  float*  srl    = (float*)(wsb + 53248);        // 524,288
  float*  q11    = (float*)(wsb + 577536);       // 524,288
  ushort* whh0b  = (ushort*)(wsb + 1101824);     // 393,216 (bf16 whh, layer 0)
  ushort* whh1b  = (ushort*)(wsb + 1888256);     // 393,216 (bf16 whh, layer 1)
  ushort* wih0b  = (ushort*)(wsb + 2674688);     // 393,216
  ushort* wih1b  = (ushort*)(wsb + 3067904);     // 393,216
  ushort* w7b    = (ushort*)(wsb + 3461120);     // 7 x 131,072
  ushort* bufS   = (ushort*)(wsb + 4378624);     // 13,107,200  seq2b -> ys1b -> se2b
  float*  se1    = (float*)(wsb + 17485824);     // 26,214,400
  ushort* se1b   = (ushort*)(wsb + 43700224);    // 13,107,200
  float*  giQ    = (float*)(wsb + 56807424);     // 78,643,200  gi -> q1|k1|v1 -> tail
  float*  kv2a   = (float*)(wsb + 135450624);    // 26,214,400  k2 -> att1p
  float*  kv2b   = (float*)(wsb + 161665024);    // 26,214,400  v2 -> att2p
  ushort* ao1b   = (ushort*)(wsb + 187879424);   // 13,107,200
  ushort* ao2b   = (ushort*)(wsb + 200986624);   // 13,107,200

  float* gi = giQ;
  float* q1 = giQ;
  float* k1 = giQ + 6553600;
  float* v1 = giQ + 13107200;
  // tail block (reuses giQ after attn2):
  ushort* embB    = (ushort*)giQ;                             // 20,480,000 B
  float*  sesscat = (float*)((char*)giQ + 20480000);          // 1,048,576
  float*  sess2   = (float*)((char*)giQ + 21528576);          // 524,288
  ushort* sess2b  = (ushort*)((char*)giQ + 22052864);         // 262,144
  float*  betab   = (float*)((char*)giQ + 22315008);          // 4,096
  float*  stats   = (float*)((char*)giQ + 22319104);          // 8,192
  float*  bnd     = out + (size_t)Bsz * VM1;                  // boundary output slot

  ushort* Wq1b = w7b;              ushort* Wk1b = w7b + 65536;
  ushort* Wv1b = w7b + 131072;     ushort* Wk2b = w7b + 196608;
  ushort* Wv2b = w7b + 262144;     ushort* Wf1b = w7b + 327680;
  ushort* Wf2b = w7b + 393216;

  // ---- table / last / q1_1 (fp32 path)
  build_tab<<<50, 256, 0, stream>>>(TAB);
  last_srl_kernel<<<Bsz, 256, 0, stream>>>(mask, seq1, lastp, srl);
  gemm_tile<0, 1><<<dim3(4, 4), 256, 0, stream>>>(srl, Wone, bone, q11, 512, 256, 256);
  add_tab0<<<512, 256, 0, stream>>>(q11);

  // ---- weight casts
  cast_f2b_k<<<6400, 256, 0, stream>>>(seq2, bufS, 1638400);
  cast_f2b_k<<<192, 256, 0, stream>>>(wih0, wih0b, 49152);
  cast_f2b_k<<<192, 256, 0, stream>>>(wih1, wih1b, 49152);
  cast_f2b_k<<<192, 256, 0, stream>>>(whh0, whh0b, 49152);
  cast_f2b_k<<<192, 256, 0, stream>>>(whh1, whh1b, 49152);
  Cast7 c7;
  c7.s[0] = Wq1; c7.s[1] = Wk1; c7.s[2] = Wv1; c7.s[3] = Wk2; c7.s[4] = Wv2;
  c7.s[5] = Wffn1; c7.s[6] = Wffn2;
  c7.d[0] = Wq1b; c7.d[1] = Wk1b; c7.d[2] = Wv1b; c7.d[3] = Wk2b; c7.d[4] = Wv2b;
  c7.d[5] = Wf1b; c7.d[6] = Wf2b;
  cast7_k<<<dim3(64, 7), 256, 0, stream>>>(c7);

  // ---- GRU (gi via MFMA, recurrence via 8-wave/2-sample MFMA kernel)
  mfma_gemm<1, 1><<<dim3(6, 200), 256, 0, stream>>>(bufS, wih0b, bih0, gi, 25600, 768, 256, nullptr, nullptr);
  gru_mfma8_kernel<<<256, 512, 0, stream>>>(gi, whh0b, bhh0, bufS, nullptr);
  mfma_gemm<1, 1><<<dim3(6, 200), 256, 0, stream>>>(bufS, wih1b, bih1, gi, 25600, 768, 256, nullptr, nullptr);
  gru_mfma8_kernel<<<256, 512, 0, stream>>>(gi, whh1b, bhh1, bufS, mask);   // -> se2 bf16

  // ---- masked seq1 (fp32 + bf16)
  mask_mul_dual<<<25600, 256, 0, stream>>>(seq1, mask, se1, se1b);

  // ---- projections (MFMA); q1/k1/v1 get the PE table added in-epilogue (EPI=2)
  mfma_gemm<0, 0><<<dim3(2, 200), 256, 0, stream>>>(bufS, Wk2b, nullptr, kv2a, 25600, 256, 256, nullptr, nullptr);
  mfma_gemm<0, 0><<<dim3(2, 200), 256, 0, stream>>>(bufS, Wv2b, nullptr, kv2b, 25600, 256, 256, nullptr, nullptr);
  mfma_gemm<0, 2><<<dim3(2, 200), 256, 0, stream>>>(se1b, Wq1b, TAB, q1, 25600, 256, 256, lastp, nullptr);
  mfma_gemm<0, 2><<<dim3(2, 200), 256, 0, stream>>>(se1b, Wk1b, TAB, k1, 25600, 256, 256, lastp, nullptr);
  mfma_gemm<0, 2><<<dim3(2, 200), 256, 0, stream>>>(se1b, Wv1b, TAB, v1, 25600, 256, 256, lastp, nullptr);

  // ---- attentions (MFMA, fp32 in, bf16 out)
  attn_mfma<0><<<Bsz, 256, 0, stream>>>(q1, k1, v1, nullptr, nullptr, mask, ao1b);
  attn_mfma<8><<<Bsz, 256, 0, stream>>>(q1, kv2a, kv2b, memk, memv, mask, ao2b);
  mfma_gemm<0, 1><<<dim3(2, 200), 256, 0, stream>>>(ao1b, Wf1b, bffn1, kv2a, 25600, 256, 256, nullptr, nullptr);
  // FFN2 fused: att = relu(att1p + ao2b@Wf2b + bffn2), written in place over att1p
  mfma_gemm<0, 3><<<dim3(2, 200), 256, 0, stream>>>(ao2b, Wf2b, bffn2, kv2a, 25600, 256, 256, nullptr, kv2a);

  // ---- pooling + session (fp32)
  alpha_sess_kernel<<<Bsz, 256, 0, stream>>>(kv2a, W3, q11, se1, mask, srl, sesscat);
  gemm_tile<0, 1><<<dim3(4, 4), 256, 0, stream>>>(sesscat, Wtr, btr, sess2, 512, 256, 512);
  cast_f2b_k<<<128, 256, 0, stream>>>(sess2, sess2b, 32768);

  // ---- tail gating (fp32) + scoring (MFMA) + fused softmax/final
  hipMemsetAsync(bnd, 0, 4, stream);
  beta_kernel<<<Bsz, 256, 0, stream>>>(sess2, Wt1, bt1, Wt2, betab, bnd);
  cast_f2b_k<<<10000, 256, 0, stream>>>(emb1 + 256, embB, 2560000);
  mfma_gemm<1, 0><<<dim3(313, 4), 256, 0, stream>>>(sess2b, embB, nullptr, out, 512, VM1, 256, nullptr, nullptr);
  score_final_fused<<<Bsz, 1024, 0, stream>>>(out, iflag, betab);

  (void)in_sizes; (void)n_in; (void)out_size; (void)ws_size;
}

// Round 6
// 963.569 us; speedup vs baseline: 1.1227x; 1.1227x over previous
//
#include <hip/hip_runtime.h>
#include <hip/hip_bf16.h>
#include <cstdint>
#include <cstddef>

// Problem dims
#define Bsz 512
#define Nsq 50
#define Hd  256
#define VM1 40000
static constexpr float SCALE_C = 0.0625f;   // 1/sqrt(256)
static constexpr float NEG_C   = -1.0e12f;

typedef __attribute__((ext_vector_type(8))) short bf16x8;
typedef __attribute__((ext_vector_type(4))) float f32x4;

__device__ __forceinline__ float sigmoidf_(float x) { return 1.0f / (1.0f + __expf(-x)); }
__device__ __forceinline__ float tanh_fast(float x) {
  float t = fminf(fmaxf(2.0f * x, -60.0f), 60.0f);
  float e = __expf(t);
  return (e - 1.0f) / (e + 1.0f);
}
__device__ __forceinline__ ushort f2b(float x) {   // fp32 -> bf16 (RNE)
  union { float f; uint32_t u; } c; c.f = x;
  uint32_t r = (c.u + 0x7fffu + ((c.u >> 16) & 1u)) >> 16;
  return (ushort)r;
}

// ---------------------------------------------------------------- TAB (50x256)
__global__ void build_tab(float* __restrict__ TAB) {
  int idx = blockIdx.x * 256 + threadIdx.x;
  int pos = idx >> 8, j = idx & 255;
  int pair = j >> 1;
  float expo = (2.0f * (float)pair) / 256.0f;
  float inv = powf(10000.0f, -expo);
  float ang = (float)pos * inv;
  TAB[idx] = (j & 1) ? cosf(ang) : sinf(ang);
}

// ------------------------------------------------- last[b], sr_l_1 = seq1[b,last]
__global__ __launch_bounds__(256) void last_srl_kernel(const int* __restrict__ mask,
    const float* __restrict__ seq1, int* __restrict__ lastp, float* __restrict__ srl) {
  int b = blockIdx.x, tid = threadIdx.x;
  __shared__ int ls;
  if (tid == 0) {
    int c = 0;
    for (int t = 0; t < Nsq; ++t) c += mask[b * Nsq + t];
    ls = c - 1;
    lastp[b] = c - 1;
  }
  __syncthreads();
  srl[b * Hd + tid] = seq1[((size_t)b * Nsq + ls) * Hd + tid];
}

// ---------------------------------------------------------------- fp32 GEMM (small shapes only)
template <int BT, int BIAS>
__global__ __launch_bounds__(256) void gemm_tile(const float* __restrict__ A,
    const float* __restrict__ B, const float* __restrict__ bias,
    float* __restrict__ C, int M, int N, int K) {
  __shared__ float As[16][132];
  __shared__ float Bs[16][68];
  int bm = blockIdx.y * 128, bn = blockIdx.x * 64;
  int tid = threadIdx.x;
  int tm = (tid >> 4) << 3;
  int tn = (tid & 15) << 2;
  float acc[8][4] = {};
  for (int k0 = 0; k0 < K; k0 += 16) {
#pragma unroll
    for (int u = 0; u < 8; ++u) {
      int i = tid + u * 256;
      int kk = i & 15, m = i >> 4;
      As[kk][m] = A[(size_t)(bm + m) * K + (k0 + kk)];
    }
#pragma unroll
    for (int u = 0; u < 4; ++u) {
      int i = tid + u * 256;
      if (BT) {
        int kk = i & 15, n = i >> 4;
        Bs[kk][n] = B[(size_t)(bn + n) * K + (k0 + kk)];
      } else {
        int n = i & 63, kk = i >> 6;
        Bs[kk][n] = B[(size_t)(k0 + kk) * N + (bn + n)];
      }
    }
    __syncthreads();
#pragma unroll
    for (int kk = 0; kk < 16; ++kk) {
      float a[8], bb[4];
#pragma unroll
      for (int r = 0; r < 8; ++r) a[r] = As[kk][tm + r];
#pragma unroll
      for (int c = 0; c < 4; ++c) bb[c] = Bs[kk][tn + c];
#pragma unroll
      for (int r = 0; r < 8; ++r)
#pragma unroll
        for (int c = 0; c < 4; ++c) acc[r][c] += a[r] * bb[c];
    }
    __syncthreads();
  }
#pragma unroll
  for (int r = 0; r < 8; ++r) {
    size_t row = (size_t)(bm + tm + r) * N + bn;
#pragma unroll
    for (int c = 0; c < 4; ++c) {
      float v = acc[r][c];
      if (BIAS) v += bias[bn + tn + c];
      C[row + tn + c] = v;
    }
  }
}

// ---------------------------------------------------------------- bf16 MFMA GEMM
// C[M,N] fp32 = A_bf[M,K] @ (BT ? B_bf[N,K]^T : B_bf[K,N]) (+bias)
// tile 128x128, BK=32, 256 threads = 4 waves (each 64x64 quadrant, 4x4 frags of 16x16x32).
template <int BT, int BIAS>
__global__ __launch_bounds__(256) void mfma_gemm(const ushort* __restrict__ A,
    const ushort* __restrict__ B, const float* __restrict__ bias,
    float* __restrict__ C, int M, int N, int K) {
  __shared__ ushort Asm[128][40];   // [m][k], +8 pad
  __shared__ ushort Bsm[128][40];   // [n][k]
  int tid = threadIdx.x;
  int bm = blockIdx.y * 128, bn = blockIdx.x * 128;
  int lane = tid & 63, wave = tid >> 6;
  int quad = lane >> 4, l16 = lane & 15;
  int wm = (wave >> 1) * 64, wn = (wave & 1) * 64;
  f32x4 acc[4][4] = {};
  for (int k0 = 0; k0 < K; k0 += 32) {
#pragma unroll
    for (int u = 0; u < 2; ++u) {               // A: 128x32, 16B per thread x2
      int idx = tid + u * 256;
      int r = idx >> 2, kc = (idx & 3) * 8;
      uint4 v = *(const uint4*)(A + (size_t)(bm + r) * K + k0 + kc);
      *(uint4*)&Asm[r][kc] = v;
    }
    if (BT) {
#pragma unroll
      for (int u = 0; u < 2; ++u) {
        int idx = tid + u * 256;
        int r = idx >> 2, kc = (idx & 3) * 8;
        uint4 v = make_uint4(0u, 0u, 0u, 0u);
        if (bn + r < N) v = *(const uint4*)(B + (size_t)(bn + r) * K + k0 + kc);
        *(uint4*)&Bsm[r][kc] = v;
      }
    } else {
#pragma unroll
      for (int u = 0; u < 8; ++u) {             // transpose-stage: 2 n per thread
        int idx = tid + u * 256;
        int n2 = (idx & 63) * 2, kk = idx >> 6;
        uint v = *(const uint*)(B + (size_t)(k0 + kk) * N + bn + n2);
        Bsm[n2][kk] = (ushort)(v & 0xffffu);
        Bsm[n2 + 1][kk] = (ushort)(v >> 16);
      }
    }
    __syncthreads();
    bf16x8 af[4], bfr[4];
#pragma unroll
    for (int f = 0; f < 4; ++f) af[f] = *(const bf16x8*)&Asm[wm + f * 16 + l16][quad * 8];
#pragma unroll
    for (int f = 0; f < 4; ++f) bfr[f] = *(const bf16x8*)&Bsm[wn + f * 16 + l16][quad * 8];
#pragma unroll
    for (int mf = 0; mf < 4; ++mf)
#pragma unroll
      for (int nf = 0; nf < 4; ++nf)
        acc[mf][nf] = __builtin_amdgcn_mfma_f32_16x16x32_bf16(af[mf], bfr[nf], acc[mf][nf], 0, 0, 0);
    __syncthreads();
  }
#pragma unroll
  for (int mf = 0; mf < 4; ++mf) {
#pragma unroll
    for (int r = 0; r < 4; ++r) {
      int row = bm + wm + mf * 16 + quad * 4 + r;
      size_t rowo = (size_t)row * N;
#pragma unroll
      for (int nf = 0; nf < 4; ++nf) {
        int col = bn + wn + nf * 16 + l16;
        if (col < N) {
          float v = acc[mf][nf][r];
          if (BIAS) v += bias[col];
          C[rowo + col] = v;
        }
      }
    }
  }
}

// ---------------------------------------------------------------- casts
__global__ void cast_f2b_k(const float* __restrict__ s, ushort* __restrict__ d, int n4) {
  int i = blockIdx.x * 256 + threadIdx.x;
  if (i >= n4) return;
  const float4 v = ((const float4*)s)[i];
  ushort4 o; o.x = f2b(v.x); o.y = f2b(v.y); o.z = f2b(v.z); o.w = f2b(v.w);
  ((ushort4*)d)[i] = o;
}

struct Cast7 { const float* s[7]; ushort* d[7]; };
__global__ void cast7_k(Cast7 p) {
  int m = blockIdx.y;
  int i = blockIdx.x * 256 + threadIdx.x;
  const float4 v = ((const float4*)p.s[m])[i];
  ushort4 o; o.x = f2b(v.x); o.y = f2b(v.y); o.z = f2b(v.z); o.w = f2b(v.w);
  ((ushort4*)p.d[m])[i] = o;
}

// ---------------------------------------------------------------- misc elementwise
__global__ void add_tab0(float* __restrict__ q) {
  int idx = blockIdx.x * 256 + threadIdx.x;
  q[idx] += (float)(threadIdx.x & 1);         // TAB[0]: sin(0)=0, cos(0)=1
}

__global__ void mask_mul_dual(const float* __restrict__ x, const int* __restrict__ m,
                              float* __restrict__ y, ushort* __restrict__ yb) {
  int idx = blockIdx.x * 256 + threadIdx.x;
  float v = m[idx >> 8] ? x[idx] : 0.0f;
  y[idx] = v;
  yb[idx] = f2b(v);
}

__global__ void add_pe3(float* __restrict__ q, float* __restrict__ k, float* __restrict__ v,
                        const float* __restrict__ TAB, const int* __restrict__ lastp) {
  int idx = blockIdx.x * 256 + threadIdx.x;
  int j = idx & 255, bt = idx >> 8;
  int b = bt / Nsq, t = bt - b * Nsq;
  int d = abs(t - lastp[b]);
  float pe = TAB[d * 256 + j];
  q[idx] += pe; k[idx] += pe; v[idx] += pe;
}

__global__ void relu_add(float* __restrict__ a, const float* __restrict__ b) {
  int idx = blockIdx.x * 256 + threadIdx.x;
  a[idx] = fmaxf(a[idx] + b[idx], 0.0f);
}

// ---------------------------------------------------------------- GRU layer (MFMA, reg-resident weights)
// 256 blocks x 8 waves (512 thr), 2 samples/block. ONE barrier per timestep:
// wave w computes ALL THREE gates for dims [w*32, w*32+32) (whh rows {d, 256+d, 512+d}),
// so its own MFMA output feeds its own 64 lanes' elementwise (2 samples x 32 dims).
// gh handoff via wave-private LDS scratch (same-wave DS ops are in-order -> no barrier).
// hbf double-buffered (write next, read cur) -> no WAR across the single barrier.
__global__ __launch_bounds__(512, 2) void gru_mfma8_kernel(const float* __restrict__ gi,
    const ushort* __restrict__ whhb, const float* __restrict__ bhh,
    ushort* __restrict__ ysb, const int* __restrict__ mask) {
  __shared__ ushort hbf[2][16][264];   // bf16 h, double-buffered (+8 pad)
  __shared__ float  gsc[8][2][3][32];  // per-wave gate scratch [wave][sample][gate][dim]
  int tid = threadIdx.x;
  int lane = tid & 63, wave = tid >> 6;
  int quad = lane >> 4, l16 = lane & 15;
  int s0 = blockIdx.x * 2;

  for (int i = tid; i < 2 * 16 * 264 / 2; i += 512) ((uint*)hbf)[i] = 0u;

  // reg-resident whh slice: wave w, frag nf: rows (nf>>1)*256 + w*32 + (nf&1)*16 + l16
  // (B-frag lane l16 = output row n, quad*8+j = k; same layout as proven mfma_gemm B-read)
  bf16x8 bw[48];
#pragma unroll
  for (int f = 0; f < 48; ++f) {
    int nf = f >> 3, kf = f & 7;
    int row = (nf >> 1) * 256 + wave * 32 + (nf & 1) * 16 + l16;
    bw[f] = *(const bf16x8*)(whhb + (size_t)row * 256 + kf * 32 + quad * 8);
  }

  // elementwise mapping: lane handles sample s = lane>>5, dim d = wave*32 + (lane&31)
  int s = lane >> 5, dloc = lane & 31;
  int d = wave * 32 + dloc;
  float bh0 = bhh[d], bh1 = bhh[256 + d], bh2 = bhh[512 + d];
  const float* gib = gi + (size_t)(s0 + s) * Nsq * 768 + d;
  float g0 = gib[0], g1 = gib[256], g2 = gib[512];
  float hreg = 0.0f;
  const int* mrow = mask + (s0 + s) * Nsq;   // only dereferenced if mask != null
  ushort* yrow = ysb + ((size_t)(s0 + s) * Nsq) * 256 + d;
  __syncthreads();

  int cur = 0;
  for (int t = 0; t < Nsq; ++t) {
    int tn = (t + 1 < Nsq) ? t + 1 : t;
    float p0 = gib[tn * 768], p1 = gib[tn * 768 + 256], p2 = gib[tn * 768 + 512];

    // ---- gh = h @ whh_slice^T  (A rows = samples; only rows 0..1 nonzero)
    f32x4 acc[6] = {};
#pragma unroll
    for (int kf = 0; kf < 8; ++kf) {
      bf16x8 a = *(const bf16x8*)&hbf[cur][l16][kf * 32 + quad * 8];
#pragma unroll
      for (int nf = 0; nf < 6; ++nf)
        acc[nf] = __builtin_amdgcn_mfma_f32_16x16x32_bf16(a, bw[nf * 8 + kf], acc[nf], 0, 0, 0);
    }
    // C layout: col = l16, row = quad*4 + reg = sample (rows 0,1 valid -> quad 0)
    if (quad == 0) {
#pragma unroll
      for (int g = 0; g < 3; ++g)
#pragma unroll
        for (int j = 0; j < 2; ++j) {
          gsc[wave][0][g][j * 16 + l16] = acc[g * 2 + j][0];
          gsc[wave][1][g][j * 16 + l16] = acc[g * 2 + j][1];
        }
    }
    __builtin_amdgcn_sched_barrier(0);   // pin gsc writes before reads (same-wave RAW)

    // ---- elementwise, fully in-wave (no block barrier needed for gh)
    {
      float ghr = gsc[wave][s][0][dloc];
      float ghz = gsc[wave][s][1][dloc];
      float ghn = gsc[wave][s][2][dloc];
      float rr = sigmoidf_(g0 + ghr + bh0);
      float zz = sigmoidf_(g1 + ghz + bh1);
      float nn = tanh_fast(g2 + rr * (ghn + bh2));
      float h2 = (1.0f - zz) * nn + zz * hreg;
      hreg = h2;
      hbf[cur ^ 1][s][d] = f2b(h2);
      float ov = h2;
      if (mask) ov = mrow[t] ? h2 : 0.0f;
      yrow[t * 256] = f2b(ov);
    }
    g0 = p0; g1 = p1; g2 = p2;
    cur ^= 1;
    __syncthreads();   // hbf[next] visible to all waves for step t+1
  }
}

// ---------------------------------------------------------------- MFMA attention
// One block per batch sample, 256 threads = 4 waves.
// S = Q[50,256] K^T[*,256] via MFMA; masked softmax; O = P V via MFMA.
// NMEM = 0 (attn1) or 8 (attn2: mem rows prepended). Output bf16, mask-zeroed.
template <int NMEM>
__global__ __launch_bounds__(256) void attn_mfma(const float* __restrict__ q1,
    const float* __restrict__ kseq, const float* __restrict__ vseq,
    const float* __restrict__ kmem, const float* __restrict__ vmem,
    const int* __restrict__ mask, ushort* __restrict__ out) {
  constexpr int NK = NMEM + Nsq;            // valid K/V rows (50 or 58)
  __shared__ ushort KV[64][264];            // Q -> K -> V staging (bf16)
  __shared__ float Ss[64][66];              // scores fp32
  __shared__ ushort Ps[64][72];             // probabilities bf16
  __shared__ int msk[64];
  int tid = threadIdx.x;
  int lane = tid & 63, wave = tid >> 6;
  int quad = lane >> 4, l16 = lane & 15;
  int b = blockIdx.x;

  if (tid < 64) msk[tid] = (tid < Nsq) ? mask[b * Nsq + tid] : 0;

  // ---- stage Q (rows t<50, else 0)
#pragma unroll
  for (int it = 0; it < 16; ++it) {
    int idx = tid + it * 256;
    int r = idx >> 6, c4 = (idx & 63) * 4;
    float4 v = make_float4(0.f, 0.f, 0.f, 0.f);
    if (r < Nsq) v = *(const float4*)(q1 + ((size_t)(b * Nsq + r)) * 256 + c4);
    ushort4 o; o.x = f2b(v.x); o.y = f2b(v.y); o.z = f2b(v.z); o.w = f2b(v.w);
    *(ushort4*)&KV[r][c4] = o;
  }
  __syncthreads();
  // Q A-frags: wave w owns t rows [w*16, w*16+16)
  bf16x8 qa[8];
#pragma unroll
  for (int kf = 0; kf < 8; ++kf)
    qa[kf] = *(const bf16x8*)&KV[wave * 16 + l16][kf * 32 + quad * 8];
  __syncthreads();

  // ---- stage K (rows: [0,NMEM) mem, [NMEM,NK) seq, else 0)
#pragma unroll
  for (int it = 0; it < 16; ++it) {
    int idx = tid + it * 256;
    int r = idx >> 6, c4 = (idx & 63) * 4;
    float4 v = make_float4(0.f, 0.f, 0.f, 0.f);
    if (r < NK) {
      const float* src = (NMEM > 0 && r < NMEM)
          ? (kmem + (size_t)r * 256 + c4)
          : (kseq + ((size_t)(b * Nsq + (r - NMEM))) * 256 + c4);
      v = *(const float4*)src;
    }
    ushort4 o; o.x = f2b(v.x); o.y = f2b(v.y); o.z = f2b(v.z); o.w = f2b(v.w);
    *(ushort4*)&KV[r][c4] = o;
  }
  __syncthreads();

  // ---- S = Q K^T  (wave w: rows [w*16, +16) x all 64 cols)
  {
    f32x4 acc[4] = {};
#pragma unroll
    for (int kf = 0; kf < 8; ++kf) {
#pragma unroll
      for (int nf = 0; nf < 4; ++nf) {
        bf16x8 bf = *(const bf16x8*)&KV[nf * 16 + l16][kf * 32 + quad * 8];
        acc[nf] = __builtin_amdgcn_mfma_f32_16x16x32_bf16(qa[kf], bf, acc[nf], 0, 0, 0);
      }
    }
#pragma unroll
    for (int nf = 0; nf < 4; ++nf)
#pragma unroll
      for (int r = 0; r < 4; ++r)
        Ss[wave * 16 + quad * 4 + r][nf * 16 + l16] = acc[nf][r];
  }
  __syncthreads();

  // ---- stage V over K region (all threads) ...
#pragma unroll
  for (int it = 0; it < 16; ++it) {
    int idx = tid + it * 256;
    int r = idx >> 6, c4 = (idx & 63) * 4;
    float4 v = make_float4(0.f, 0.f, 0.f, 0.f);
    if (r < NK) {
      const float* src = (NMEM > 0 && r < NMEM)
          ? (vmem + (size_t)r * 256 + c4)
          : (vseq + ((size_t)(b * Nsq + (r - NMEM))) * 256 + c4);
      v = *(const float4*)src;
    }
    ushort4 o; o.x = f2b(v.x); o.y = f2b(v.y); o.z = f2b(v.z); o.w = f2b(v.w);
    *(ushort4*)&KV[r][c4] = o;
  }
  // ... while lane-per-row softmax runs on wave 0
  if (tid < 64) {
    int t = tid;
    if (t < Nsq) {
      float m = -1e30f;
      for (int j = 0; j < NK; ++j) {
        bool ok = (j < NMEM) || (((j - NMEM) <= t) && (msk[j - NMEM] != 0));
        if (ok) m = fmaxf(m, Ss[t][j] * SCALE_C);
      }
      float sum = 0.0f;
      for (int j = 0; j < NK; ++j) {
        bool ok = (j < NMEM) || (((j - NMEM) <= t) && (msk[j - NMEM] != 0));
        if (ok) sum += __expf(Ss[t][j] * SCALE_C - m);
      }
      float inv = 1.0f / sum;
      for (int j = 0; j < 64; ++j) {
        float p = 0.0f;
        if (j < NK) {
          bool ok = (j < NMEM) || (((j - NMEM) <= t) && (msk[j - NMEM] != 0));
          if (ok) p = __expf(Ss[t][j] * SCALE_C - m) * inv;
        }
        Ps[t][j] = f2b(p);
      }
    } else {
      for (int j = 0; j < 64; ++j) Ps[t][j] = 0;
    }
  }
  __syncthreads();

  // ---- O = P V  (wave w: all 64 t-rows x h in [w*64, +64))
  {
    f32x4 o[4][4] = {};
#pragma unroll
    for (int kf = 0; kf < 2; ++kf) {
      bf16x8 pa[4];
#pragma unroll
      for (int mf = 0; mf < 4; ++mf)
        pa[mf] = *(const bf16x8*)&Ps[mf * 16 + l16][kf * 32 + quad * 8];
#pragma unroll
      for (int nf = 0; nf < 4; ++nf) {
        int h = wave * 64 + nf * 16 + l16;
        ushort e0 = KV[kf * 32 + quad * 8 + 0][h];
        ushort e1 = KV[kf * 32 + quad * 8 + 1][h];
        ushort e2 = KV[kf * 32 + quad * 8 + 2][h];
        ushort e3 = KV[kf * 32 + quad * 8 + 3][h];
        ushort e4 = KV[kf * 32 + quad * 8 + 4][h];
        ushort e5 = KV[kf * 32 + quad * 8 + 5][h];
        ushort e6 = KV[kf * 32 + quad * 8 + 6][h];
        ushort e7 = KV[kf * 32 + quad * 8 + 7][h];
        bf16x8 vb = {(short)e0, (short)e1, (short)e2, (short)e3,
                     (short)e4, (short)e5, (short)e6, (short)e7};
#pragma unroll
        for (int mf = 0; mf < 4; ++mf)
          o[mf][nf] = __builtin_amdgcn_mfma_f32_16x16x32_bf16(pa[mf], vb, o[mf][nf], 0, 0, 0);
      }
    }
#pragma unroll
    for (int mf = 0; mf < 4; ++mf) {
#pragma unroll
      for (int r = 0; r < 4; ++r) {
        int t = mf * 16 + quad * 4 + r;
        if (t < Nsq) {
          int zero = (msk[t] == 0);
#pragma unroll
          for (int nf = 0; nf < 4; ++nf) {
            int h = wave * 64 + nf * 16 + l16;
            float val = zero ? 0.0f : o[mf][nf][r];
            out[((size_t)(b * Nsq + t)) * 256 + h] = f2b(val);
          }
        }
      }
    }
  }
}

// ---------------------------------------------------------------- alpha + sess (→ sesscat)
__global__ __launch_bounds__(256) void alpha_sess_kernel(const float* __restrict__ att,
    const float* __restrict__ W3, const float* __restrict__ q11,
    const float* __restrict__ se1, const int* __restrict__ mask,
    const float* __restrict__ srl, float* __restrict__ sesscat) {
  int b = blockIdx.x, tid = threadIdx.x;
  __shared__ float red[256];
  __shared__ float ash[50];
  red[tid] = q11[b * Hd + tid] * W3[256 + tid];
  __syncthreads();
  for (int s = 128; s; s >>= 1) { if (tid < s) red[tid] += red[tid + s]; __syncthreads(); }
  float cq = red[0];
  float aval = 0.0f;
  if (tid < 50) {
    float s = cq;
    const float* ar = att + ((size_t)b * Nsq + tid) * Hd;
    for (int hh = 0; hh < 256; ++hh) s += ar[hh] * W3[hh];
    aval = mask[b * Nsq + tid] ? s : NEG_C;
  }
  if (tid < 64) {
    float s = (tid < 50) ? aval : NEG_C;
    float m = s;
    for (int off = 32; off; off >>= 1) m = fmaxf(m, __shfl_xor(m, off));
    float e = expf(s - m);
    float sum = e;
    for (int off = 32; off; off >>= 1) sum += __shfl_xor(sum, off);
    if (tid < 50) ash[tid] = e / sum;
  }
  __syncthreads();
  float acc = 0.0f;
  const float* se = se1 + (size_t)b * Nsq * Hd;
  for (int t = 0; t < Nsq; ++t) acc += ash[t] * se[t * 256 + tid];
  sesscat[(size_t)b * 512 + tid] = acc;
  sesscat[(size_t)b * 512 + 256 + tid] = srl[b * Hd + tid];
}

// ---------------------------------------------------------------- beta + boundary (fp32)
__global__ __launch_bounds__(256) void beta_kernel(const float* __restrict__ sess2,
    const float* __restrict__ Wt1, const float* __restrict__ bt1,
    const float* __restrict__ Wt2, float* __restrict__ beta, float* __restrict__ bnd) {
  int b = blockIdx.x, tid = threadIdx.x;
  __shared__ float xs[256];
  __shared__ float r0[256], r1[256];
  xs[tid] = sess2[b * Hd + tid];
  __syncthreads();
  float hsum = bt1[tid];
  for (int k = 0; k < 256; ++k) hsum += xs[k] * Wt1[k * 256 + tid];
  float hid = fmaxf(hsum, 0.0f);
  r0[tid] = hid * Wt2[tid * 2 + 0];
  r1[tid] = hid * Wt2[tid * 2 + 1];
  __syncthreads();
  for (int s = 128; s; s >>= 1) {
    if (tid < s) { r0[tid] += r0[tid + s]; r1[tid] += r1[tid + s]; }
    __syncthreads();
  }
  if (tid == 0) {
    float t0 = r0[0], t1 = r1[0];
    float m = fmaxf(t0, t1);
    float e0 = expf(t0 - m), e1 = expf(t1 - m);
    float bb0 = e0 / (e0 + e1), bb1 = e1 / (e0 + e1);
    beta[b * 2] = bb0; beta[b * 2 + 1] = bb1;
    atomicAdd(bnd, fabsf(bb0 - bb1) * (1.0f / 512.0f));
  }
}

// ---------------------------------------------------------------- fused score softmax + final
// One block (1024 thr) per row b. Flags packed once into a 5 KB LDS bitmask (pass 1);
// passes 2-3 never re-read flag. No intermediate stores: pass 2 only sums, pass 3
// recomputes the exp and writes fin directly. Score row (160 KB) stays L3-resident
// across passes. Each element contributes to exactly one side (exp(NEG-M) == 0).
__global__ __launch_bounds__(1024) void score_final_fused(float* __restrict__ score,
    const int* __restrict__ flag, const float* __restrict__ beta) {
  int b = blockIdx.x, tid = threadIdx.x;
  float4* sr = (float4*)(score + (size_t)b * VM1);
  const int4* fr = (const int4*)(flag + (size_t)b * VM1);
  constexpr int NV = VM1 / 4;        // 10000 int4/float4 groups
  constexpr int NW = (NV + 7) / 8;   // 1250 bitmask words (4 bits per group)

  __shared__ uint bits[NW];
  __shared__ float red[1024], red2[1024];

  for (int i = tid; i < NW; i += 1024) bits[i] = 0u;
  __syncthreads();

  // ---- pass 1: per-side maxes + flag bitmask
  float mi = -INFINITY, me = -INFINITY;
  for (int i = tid; i < NV; i += 1024) {
    float4 s = sr[i];
    int4 f = fr[i];
    uint nib = (f.x ? 1u : 0u) | (f.y ? 2u : 0u) | (f.z ? 4u : 0u) | (f.w ? 8u : 0u);
    if (nib) atomicOr(&bits[i >> 3], nib << ((i & 7) * 4));
    if (f.x) mi = fmaxf(mi, s.x); else me = fmaxf(me, s.x);
    if (f.y) mi = fmaxf(mi, s.y); else me = fmaxf(me, s.y);
    if (f.z) mi = fmaxf(mi, s.z); else me = fmaxf(me, s.z);
    if (f.w) mi = fmaxf(mi, s.w); else me = fmaxf(me, s.w);
  }
  red[tid] = mi; red2[tid] = me;
  __syncthreads();
  for (int s = 512; s; s >>= 1) {
    if (tid < s) { red[tid] = fmaxf(red[tid], red[tid + s]); red2[tid] = fmaxf(red2[tid], red2[tid + s]); }
    __syncthreads();
  }
  float Mi = red[0], Me = red2[0];
  __syncthreads();

  // ---- pass 2: per-side sums (no stores; score re-read from L3)
  float si = 0.0f, se = 0.0f;
  for (int i = tid; i < NV; i += 1024) {
    float4 s = sr[i];
    uint nib = bits[i >> 3] >> ((i & 7) * 4);
    float e0 = __expf(s.x - ((nib & 1u) ? Mi : Me));
    float e1 = __expf(s.y - ((nib & 2u) ? Mi : Me));
    float e2 = __expf(s.z - ((nib & 4u) ? Mi : Me));
    float e3 = __expf(s.w - ((nib & 8u) ? Mi : Me));
    si += ((nib & 1u) ? e0 : 0.0f) + ((nib & 2u) ? e1 : 0.0f)
        + ((nib & 4u) ? e2 : 0.0f) + ((nib & 8u) ? e3 : 0.0f);
    se += ((nib & 1u) ? 0.0f : e0) + ((nib & 2u) ? 0.0f : e1)
        + ((nib & 4u) ? 0.0f : e2) + ((nib & 8u) ? 0.0f : e3);
  }
  red[tid] = si; red2[tid] = se;
  __syncthreads();
  for (int s = 512; s; s >>= 1) {
    if (tid < s) { red[tid] += red[tid + s]; red2[tid] += red2[tid + s]; }
    __syncthreads();
  }
  float c0 = beta[b * 2] / red[0];
  float c1 = beta[b * 2 + 1] / red2[0];
  __syncthreads();

  // ---- pass 3: recompute exp, write fin in place
  for (int i = tid; i < NV; i += 1024) {
    float4 s = sr[i];
    uint nib = bits[i >> 3] >> ((i & 7) * 4);
    s.x = ((nib & 1u) ? c0 : c1) * __expf(s.x - ((nib & 1u) ? Mi : Me));
    s.y = ((nib & 2u) ? c0 : c1) * __expf(s.y - ((nib & 2u) ? Mi : Me));
    s.z = ((nib & 4u) ? c0 : c1) * __expf(s.z - ((nib & 4u) ? Mi : Me));
    s.w = ((nib & 8u) ? c0 : c1) * __expf(s.w - ((nib & 8u) ? Mi : Me));
    sr[i] = s;
  }
}

// ================================================================ launch
extern "C" void kernel_launch(void* const* d_in, const int* in_sizes, int n_in,
                              void* d_out, int out_size, void* d_ws, size_t ws_size,
                              hipStream_t stream) {
  const float* seq1  = (const float*)d_in[0];
  const float* seq2  = (const float*)d_in[1];
  const int*   mask  = (const int*)d_in[2];
  const int*   iflag = (const int*)d_in[3];
  const float* wih0  = (const float*)d_in[4];
  const float* whh0  = (const float*)d_in[5];
  const float* bih0  = (const float*)d_in[6];
  const float* bhh0  = (const float*)d_in[7];
  const float* wih1  = (const float*)d_in[8];
  const float* whh1  = (const float*)d_in[9];
  const float* bih1  = (const float*)d_in[10];
  const float* bhh1  = (const float*)d_in[11];
  const float* Wq1   = (const float*)d_in[12];
  const float* Wk1   = (const float*)d_in[13];
  const float* Wv1   = (const float*)d_in[14];
  const float* Wk2   = (const float*)d_in[16];
  const float* Wv2   = (const float*)d_in[17];
  const float* Wffn1 = (const float*)d_in[18];
  const float* bffn1 = (const float*)d_in[19];
  const float* Wffn2 = (const float*)d_in[20];
  const float* bffn2 = (const float*)d_in[21];
  const float* Wone  = (const float*)d_in[22];
  const float* bone  = (const float*)d_in[23];
  const float* W3    = (const float*)d_in[24];
  const float* Wtr   = (const float*)d_in[25];
  const float* btr   = (const float*)d_in[26];
  const float* Wt1   = (const float*)d_in[27];
  const float* bt1   = (const float*)d_in[28];
  const float* Wt2   = (const float*)d_in[29];
  const float* memk  = (const float*)d_in[30];
  const float* memv  = (const float*)d_in[31];
  const float* emb1  = (const float*)d_in[32];
  float* out = (float*)d_out;

  // Workspace layout (byte offsets, all 16B-aligned). Total ≈ 214.1 MB.
  char* wsb = (char*)d_ws;
  float*  TAB    = (float*)(wsb + 0);            // 51,200
  int*    lastp  = (int*)  (wsb + 51200);        // 2,048
  float*  srl    = (float*)(wsb + 53248);        // 524,288
  float*  q11    = (float*)(wsb + 577536);       // 524,288
  ushort* whh0b  = (ushort*)(wsb + 1101824);     // 393,216 (bf16 whh, layer 0)
  ushort* whh1b  = (ushort*)(wsb + 1888256);     // 393,216 (bf16 whh, layer 1)
  ushort* wih0b  = (ushort*)(wsb + 2674688);     // 393,216
  ushort* wih1b  = (ushort*)(wsb + 3067904);     // 393,216
  ushort* w7b    = (ushort*)(wsb + 3461120);     // 7 x 131,072
  ushort* bufS   = (ushort*)(wsb + 4378624);     // 13,107,200  seq2b -> ys1b -> se2b
  float*  se1    = (float*)(wsb + 17485824);     // 26,214,400
  ushort* se1b   = (ushort*)(wsb + 43700224);    // 13,107,200
  float*  giQ    = (float*)(wsb + 56807424);     // 78,643,200  gi -> q1|k1|v1 -> tail
  float*  kv2a   = (float*)(wsb + 135450624);    // 26,214,400  k2 -> att1p
  float*  kv2b   = (float*)(wsb + 161665024);    // 26,214,400  v2 -> att2p
  ushort* ao1b   = (ushort*)(wsb + 187879424);   // 13,107,200
  ushort* ao2b   = (ushort*)(wsb + 200986624);   // 13,107,200

  float* gi = giQ;
  float* q1 = giQ;
  float* k1 = giQ + 6553600;
  float* v1 = giQ + 13107200;
  // tail block (reuses giQ after attn2):
  ushort* embB    = (ushort*)giQ;                             // 20,480,000 B
  float*  sesscat = (float*)((char*)giQ + 20480000);          // 1,048,576
  float*  sess2   = (float*)((char*)giQ + 21528576);          // 524,288
  ushort* sess2b  = (ushort*)((char*)giQ + 22052864);         // 262,144
  float*  betab   = (float*)((char*)giQ + 22315008);          // 4,096
  float*  stats   = (float*)((char*)giQ + 22319104);          // 8,192
  float*  bnd     = out + (size_t)Bsz * VM1;                  // boundary output slot

  ushort* Wq1b = w7b;              ushort* Wk1b = w7b + 65536;
  ushort* Wv1b = w7b + 131072;     ushort* Wk2b = w7b + 196608;
  ushort* Wv2b = w7b + 262144;     ushort* Wf1b = w7b + 327680;
  ushort* Wf2b = w7b + 393216;

  // ---- table / last / q1_1 (fp32 path)
  build_tab<<<50, 256, 0, stream>>>(TAB);
  last_srl_kernel<<<Bsz, 256, 0, stream>>>(mask, seq1, lastp, srl);
  gemm_tile<0, 1><<<dim3(4, 4), 256, 0, stream>>>(srl, Wone, bone, q11, 512, 256, 256);
  add_tab0<<<512, 256, 0, stream>>>(q11);

  // ---- weight casts
  cast_f2b_k<<<6400, 256, 0, stream>>>(seq2, bufS, 1638400);
  cast_f2b_k<<<192, 256, 0, stream>>>(wih0, wih0b, 49152);
  cast_f2b_k<<<192, 256, 0, stream>>>(wih1, wih1b, 49152);
  cast_f2b_k<<<192, 256, 0, stream>>>(whh0, whh0b, 49152);
  cast_f2b_k<<<192, 256, 0, stream>>>(whh1, whh1b, 49152);
  Cast7 c7;
  c7.s[0] = Wq1; c7.s[1] = Wk1; c7.s[2] = Wv1; c7.s[3] = Wk2; c7.s[4] = Wv2;
  c7.s[5] = Wffn1; c7.s[6] = Wffn2;
  c7.d[0] = Wq1b; c7.d[1] = Wk1b; c7.d[2] = Wv1b; c7.d[3] = Wk2b; c7.d[4] = Wv2b;
  c7.d[5] = Wf1b; c7.d[6] = Wf2b;
  cast7_k<<<dim3(64, 7), 256, 0, stream>>>(c7);

  // ---- GRU (gi via MFMA, recurrence via 8-wave/2-sample MFMA kernel, 1 barrier/step)
  mfma_gemm<1, 1><<<dim3(6, 200), 256, 0, stream>>>(bufS, wih0b, bih0, gi, 25600, 768, 256);
  gru_mfma8_kernel<<<256, 512, 0, stream>>>(gi, whh0b, bhh0, bufS, nullptr);
  mfma_gemm<1, 1><<<dim3(6, 200), 256, 0, stream>>>(bufS, wih1b, bih1, gi, 25600, 768, 256);
  gru_mfma8_kernel<<<256, 512, 0, stream>>>(gi, whh1b, bhh1, bufS, mask);   // -> se2 bf16

  // ---- masked seq1 (fp32 + bf16)
  mask_mul_dual<<<25600, 256, 0, stream>>>(seq1, mask, se1, se1b);

  // ---- projections (MFMA)
  mfma_gemm<0, 0><<<dim3(2, 200), 256, 0, stream>>>(bufS, Wk2b, nullptr, kv2a, 25600, 256, 256);
  mfma_gemm<0, 0><<<dim3(2, 200), 256, 0, stream>>>(bufS, Wv2b, nullptr, kv2b, 25600, 256, 256);
  mfma_gemm<0, 0><<<dim3(2, 200), 256, 0, stream>>>(se1b, Wq1b, nullptr, q1, 25600, 256, 256);
  mfma_gemm<0, 0><<<dim3(2, 200), 256, 0, stream>>>(se1b, Wk1b, nullptr, k1, 25600, 256, 256);
  mfma_gemm<0, 0><<<dim3(2, 200), 256, 0, stream>>>(se1b, Wv1b, nullptr, v1, 25600, 256, 256);
  add_pe3<<<25600, 256, 0, stream>>>(q1, k1, v1, TAB, lastp);

  // ---- attentions (MFMA, fp32 in, bf16 out)
  attn_mfma<0><<<Bsz, 256, 0, stream>>>(q1, k1, v1, nullptr, nullptr, mask, ao1b);
  attn_mfma<8><<<Bsz, 256, 0, stream>>>(q1, kv2a, kv2b, memk, memv, mask, ao2b);
  mfma_gemm<0, 1><<<dim3(2, 200), 256, 0, stream>>>(ao1b, Wf1b, bffn1, kv2a, 25600, 256, 256);
  mfma_gemm<0, 1><<<dim3(2, 200), 256, 0, stream>>>(ao2b, Wf2b, bffn2, kv2b, 25600, 256, 256);
  relu_add<<<25600, 256, 0, stream>>>(kv2a, kv2b);          // att

  // ---- pooling + session (fp32)
  alpha_sess_kernel<<<Bsz, 256, 0, stream>>>(kv2a, W3, q11, se1, mask, srl, sesscat);
  gemm_tile<0, 1><<<dim3(4, 4), 256, 0, stream>>>(sesscat, Wtr, btr, sess2, 512, 256, 512);
  cast_f2b_k<<<128, 256, 0, stream>>>(sess2, sess2b, 32768);

  // ---- tail gating (fp32) + scoring (MFMA) + fused softmax/final
  hipMemsetAsync(bnd, 0, 4, stream);
  beta_kernel<<<Bsz, 256, 0, stream>>>(sess2, Wt1, bt1, Wt2, betab, bnd);
  cast_f2b_k<<<10000, 256, 0, stream>>>(emb1 + 256, embB, 2560000);
  mfma_gemm<1, 0><<<dim3(313, 4), 256, 0, stream>>>(sess2b, embB, nullptr, out, 512, VM1, 256);
  score_final_fused<<<Bsz, 1024, 0, stream>>>(out, iflag, betab);

  (void)in_sizes; (void)n_in; (void)out_size; (void)ws_size;
}

// Round 7
// 933.130 us; speedup vs baseline: 1.1593x; 1.0326x over previous
//
#include <hip/hip_runtime.h>
#include <hip/hip_bf16.h>
#include <cstdint>
#include <cstddef>

// Problem dims
#define Bsz 512
#define Nsq 50
#define Hd  256
#define VM1 40000
static constexpr float SCALE_C = 0.0625f;   // 1/sqrt(256)
static constexpr float NEG_C   = -1.0e12f;

typedef __attribute__((ext_vector_type(8))) short bf16x8;
typedef __attribute__((ext_vector_type(4))) float f32x4;

__device__ __forceinline__ float sigmoidf_(float x) { return 1.0f / (1.0f + __expf(-x)); }
__device__ __forceinline__ float tanh_fast(float x) {
  float t = fminf(fmaxf(2.0f * x, -60.0f), 60.0f);
  float e = __expf(t);
  return (e - 1.0f) / (e + 1.0f);
}
__device__ __forceinline__ ushort f2b(float x) {   // fp32 -> bf16 (RNE)
  union { float f; uint32_t u; } c; c.f = x;
  uint32_t r = (c.u + 0x7fffu + ((c.u >> 16) & 1u)) >> 16;
  return (ushort)r;
}

// ---------------------------------------------------------------- TAB (50x256)
__global__ void build_tab(float* __restrict__ TAB) {
  int idx = blockIdx.x * 256 + threadIdx.x;
  int pos = idx >> 8, j = idx & 255;
  int pair = j >> 1;
  float expo = (2.0f * (float)pair) / 256.0f;
  float inv = powf(10000.0f, -expo);
  float ang = (float)pos * inv;
  TAB[idx] = (j & 1) ? cosf(ang) : sinf(ang);
}

// ------------------------------------------------- last[b], sr_l_1 = seq1[b,last]
__global__ __launch_bounds__(256) void last_srl_kernel(const int* __restrict__ mask,
    const float* __restrict__ seq1, int* __restrict__ lastp, float* __restrict__ srl) {
  int b = blockIdx.x, tid = threadIdx.x;
  __shared__ int ls;
  if (tid == 0) {
    int c = 0;
    for (int t = 0; t < Nsq; ++t) c += mask[b * Nsq + t];
    ls = c - 1;
    lastp[b] = c - 1;
  }
  __syncthreads();
  srl[b * Hd + tid] = seq1[((size_t)b * Nsq + ls) * Hd + tid];
}

// ---------------------------------------------------------------- fp32 GEMM (small shapes only)
template <int BT, int BIAS>
__global__ __launch_bounds__(256) void gemm_tile(const float* __restrict__ A,
    const float* __restrict__ B, const float* __restrict__ bias,
    float* __restrict__ C, int M, int N, int K) {
  __shared__ float As[16][132];
  __shared__ float Bs[16][68];
  int bm = blockIdx.y * 128, bn = blockIdx.x * 64;
  int tid = threadIdx.x;
  int tm = (tid >> 4) << 3;
  int tn = (tid & 15) << 2;
  float acc[8][4] = {};
  for (int k0 = 0; k0 < K; k0 += 16) {
#pragma unroll
    for (int u = 0; u < 8; ++u) {
      int i = tid + u * 256;
      int kk = i & 15, m = i >> 4;
      As[kk][m] = A[(size_t)(bm + m) * K + (k0 + kk)];
    }
#pragma unroll
    for (int u = 0; u < 4; ++u) {
      int i = tid + u * 256;
      if (BT) {
        int kk = i & 15, n = i >> 4;
        Bs[kk][n] = B[(size_t)(bn + n) * K + (k0 + kk)];
      } else {
        int n = i & 63, kk = i >> 6;
        Bs[kk][n] = B[(size_t)(k0 + kk) * N + (bn + n)];
      }
    }
    __syncthreads();
#pragma unroll
    for (int kk = 0; kk < 16; ++kk) {
      float a[8], bb[4];
#pragma unroll
      for (int r = 0; r < 8; ++r) a[r] = As[kk][tm + r];
#pragma unroll
      for (int c = 0; c < 4; ++c) bb[c] = Bs[kk][tn + c];
#pragma unroll
      for (int r = 0; r < 8; ++r)
#pragma unroll
        for (int c = 0; c < 4; ++c) acc[r][c] += a[r] * bb[c];
    }
    __syncthreads();
  }
#pragma unroll
  for (int r = 0; r < 8; ++r) {
    size_t row = (size_t)(bm + tm + r) * N + bn;
#pragma unroll
    for (int c = 0; c < 4; ++c) {
      float v = acc[r][c];
      if (BIAS) v += bias[bn + tn + c];
      C[row + tn + c] = v;
    }
  }
}

// ---------------------------------------------------------------- bf16 MFMA GEMM
// C[M,N] fp32 = A_bf[M,K] @ (BT ? B_bf[N,K]^T : B_bf[K,N]) (+bias)
// tile 128x128, BK=32, 256 threads = 4 waves (each 64x64 quadrant, 4x4 frags of 16x16x32).
template <int BT, int BIAS>
__global__ __launch_bounds__(256) void mfma_gemm(const ushort* __restrict__ A,
    const ushort* __restrict__ B, const float* __restrict__ bias,
    float* __restrict__ C, int M, int N, int K) {
  __shared__ ushort Asm[128][40];   // [m][k], +8 pad
  __shared__ ushort Bsm[128][40];   // [n][k]
  int tid = threadIdx.x;
  int bm = blockIdx.y * 128, bn = blockIdx.x * 128;
  int lane = tid & 63, wave = tid >> 6;
  int quad = lane >> 4, l16 = lane & 15;
  int wm = (wave >> 1) * 64, wn = (wave & 1) * 64;
  f32x4 acc[4][4] = {};
  for (int k0 = 0; k0 < K; k0 += 32) {
#pragma unroll
    for (int u = 0; u < 2; ++u) {               // A: 128x32, 16B per thread x2
      int idx = tid + u * 256;
      int r = idx >> 2, kc = (idx & 3) * 8;
      uint4 v = *(const uint4*)(A + (size_t)(bm + r) * K + k0 + kc);
      *(uint4*)&Asm[r][kc] = v;
    }
    if (BT) {
#pragma unroll
      for (int u = 0; u < 2; ++u) {
        int idx = tid + u * 256;
        int r = idx >> 2, kc = (idx & 3) * 8;
        uint4 v = make_uint4(0u, 0u, 0u, 0u);
        if (bn + r < N) v = *(const uint4*)(B + (size_t)(bn + r) * K + k0 + kc);
        *(uint4*)&Bsm[r][kc] = v;
      }
    } else {
#pragma unroll
      for (int u = 0; u < 8; ++u) {             // transpose-stage: 2 n per thread
        int idx = tid + u * 256;
        int n2 = (idx & 63) * 2, kk = idx >> 6;
        uint v = *(const uint*)(B + (size_t)(k0 + kk) * N + bn + n2);
        Bsm[n2][kk] = (ushort)(v & 0xffffu);
        Bsm[n2 + 1][kk] = (ushort)(v >> 16);
      }
    }
    __syncthreads();
    bf16x8 af[4], bfr[4];
#pragma unroll
    for (int f = 0; f < 4; ++f) af[f] = *(const bf16x8*)&Asm[wm + f * 16 + l16][quad * 8];
#pragma unroll
    for (int f = 0; f < 4; ++f) bfr[f] = *(const bf16x8*)&Bsm[wn + f * 16 + l16][quad * 8];
#pragma unroll
    for (int mf = 0; mf < 4; ++mf)
#pragma unroll
      for (int nf = 0; nf < 4; ++nf)
        acc[mf][nf] = __builtin_amdgcn_mfma_f32_16x16x32_bf16(af[mf], bfr[nf], acc[mf][nf], 0, 0, 0);
    __syncthreads();
  }
#pragma unroll
  for (int mf = 0; mf < 4; ++mf) {
#pragma unroll
    for (int r = 0; r < 4; ++r) {
      int row = bm + wm + mf * 16 + quad * 4 + r;
      size_t rowo = (size_t)row * N;
#pragma unroll
      for (int nf = 0; nf < 4; ++nf) {
        int col = bn + wn + nf * 16 + l16;
        if (col < N) {
          float v = acc[mf][nf][r];
          if (BIAS) v += bias[col];
          C[rowo + col] = v;
        }
      }
    }
  }
}

// ---------------------------------------------------------------- casts
__global__ void cast_f2b_k(const float* __restrict__ s, ushort* __restrict__ d, int n4) {
  int i = blockIdx.x * 256 + threadIdx.x;
  if (i >= n4) return;
  const float4 v = ((const float4*)s)[i];
  ushort4 o; o.x = f2b(v.x); o.y = f2b(v.y); o.z = f2b(v.z); o.w = f2b(v.w);
  ((ushort4*)d)[i] = o;
}

struct Cast7 { const float* s[7]; ushort* d[7]; };
__global__ void cast7_k(Cast7 p) {
  int m = blockIdx.y;
  int i = blockIdx.x * 256 + threadIdx.x;
  const float4 v = ((const float4*)p.s[m])[i];
  ushort4 o; o.x = f2b(v.x); o.y = f2b(v.y); o.z = f2b(v.z); o.w = f2b(v.w);
  ((ushort4*)p.d[m])[i] = o;
}

// ---------------------------------------------------------------- misc elementwise
__global__ void add_tab0(float* __restrict__ q) {
  int idx = blockIdx.x * 256 + threadIdx.x;
  q[idx] += (float)(threadIdx.x & 1);         // TAB[0]: sin(0)=0, cos(0)=1
}

__global__ void mask_mul_dual(const float* __restrict__ x, const int* __restrict__ m,
                              float* __restrict__ y, ushort* __restrict__ yb) {
  int idx = blockIdx.x * 256 + threadIdx.x;
  float v = m[idx >> 8] ? x[idx] : 0.0f;
  y[idx] = v;
  yb[idx] = f2b(v);
}

// ---------------------------------------------------------------- GRU layer (MFMA, reg-resident weights)
// 256 blocks x 8 waves (512 thr), 2 samples/block. ONE barrier per timestep:
// wave w computes ALL THREE gates for dims [w*32, w*32+32) (whh rows {d, 256+d, 512+d}),
// so its own MFMA output feeds its own 64 lanes' elementwise (2 samples x 32 dims).
// gh handoff via wave-private LDS scratch (same-wave DS ops are in-order -> no barrier).
// hbf double-buffered (write next, read cur) -> no WAR across the single barrier.
__global__ __launch_bounds__(512, 2) void gru_mfma8_kernel(const float* __restrict__ gi,
    const ushort* __restrict__ whhb, const float* __restrict__ bhh,
    ushort* __restrict__ ysb, const int* __restrict__ mask) {
  __shared__ ushort hbf[2][16][264];   // bf16 h, double-buffered (+8 pad)
  __shared__ float  gsc[8][2][3][32];  // per-wave gate scratch [wave][sample][gate][dim]
  int tid = threadIdx.x;
  int lane = tid & 63, wave = tid >> 6;
  int quad = lane >> 4, l16 = lane & 15;
  int s0 = blockIdx.x * 2;

  for (int i = tid; i < 2 * 16 * 264 / 2; i += 512) ((uint*)hbf)[i] = 0u;

  // reg-resident whh slice: wave w, frag nf: rows (nf>>1)*256 + w*32 + (nf&1)*16 + l16
  // (B-frag lane l16 = output row n, quad*8+j = k; same layout as proven mfma_gemm B-read)
  bf16x8 bw[48];
#pragma unroll
  for (int f = 0; f < 48; ++f) {
    int nf = f >> 3, kf = f & 7;
    int row = (nf >> 1) * 256 + wave * 32 + (nf & 1) * 16 + l16;
    bw[f] = *(const bf16x8*)(whhb + (size_t)row * 256 + kf * 32 + quad * 8);
  }

  // elementwise mapping: lane handles sample s = lane>>5, dim d = wave*32 + (lane&31)
  int s = lane >> 5, dloc = lane & 31;
  int d = wave * 32 + dloc;
  float bh0 = bhh[d], bh1 = bhh[256 + d], bh2 = bhh[512 + d];
  const float* gib = gi + (size_t)(s0 + s) * Nsq * 768 + d;
  float g0 = gib[0], g1 = gib[256], g2 = gib[512];
  float hreg = 0.0f;
  const int* mrow = mask + (s0 + s) * Nsq;   // only dereferenced if mask != null
  ushort* yrow = ysb + ((size_t)(s0 + s) * Nsq) * 256 + d;
  __syncthreads();

  int cur = 0;
  for (int t = 0; t < Nsq; ++t) {
    int tn = (t + 1 < Nsq) ? t + 1 : t;
    float p0 = gib[tn * 768], p1 = gib[tn * 768 + 256], p2 = gib[tn * 768 + 512];

    // ---- gh = h @ whh_slice^T  (A rows = samples; only rows 0..1 nonzero)
    f32x4 acc[6] = {};
#pragma unroll
    for (int kf = 0; kf < 8; ++kf) {
      bf16x8 a = *(const bf16x8*)&hbf[cur][l16][kf * 32 + quad * 8];
#pragma unroll
      for (int nf = 0; nf < 6; ++nf)
        acc[nf] = __builtin_amdgcn_mfma_f32_16x16x32_bf16(a, bw[nf * 8 + kf], acc[nf], 0, 0, 0);
    }
    // C layout: col = l16, row = quad*4 + reg = sample (rows 0,1 valid -> quad 0)
    if (quad == 0) {
#pragma unroll
      for (int g = 0; g < 3; ++g)
#pragma unroll
        for (int j = 0; j < 2; ++j) {
          gsc[wave][0][g][j * 16 + l16] = acc[g * 2 + j][0];
          gsc[wave][1][g][j * 16 + l16] = acc[g * 2 + j][1];
        }
    }
    __builtin_amdgcn_sched_barrier(0);   // pin gsc writes before reads (same-wave RAW)

    // ---- elementwise, fully in-wave (no block barrier needed for gh)
    {
      float ghr = gsc[wave][s][0][dloc];
      float ghz = gsc[wave][s][1][dloc];
      float ghn = gsc[wave][s][2][dloc];
      float rr = sigmoidf_(g0 + ghr + bh0);
      float zz = sigmoidf_(g1 + ghz + bh1);
      float nn = tanh_fast(g2 + rr * (ghn + bh2));
      float h2 = (1.0f - zz) * nn + zz * hreg;
      hreg = h2;
      hbf[cur ^ 1][s][d] = f2b(h2);
      float ov = h2;
      if (mask) ov = mrow[t] ? h2 : 0.0f;
      yrow[t * 256] = f2b(ov);
    }
    g0 = p0; g1 = p1; g2 = p2;
    cur ^= 1;
    __syncthreads();   // hbf[next] visible to all waves for step t+1
  }
}

// ---------------------------------------------------------------- MFMA attention
// One block per batch sample, 256 threads = 4 waves.
// S = Q[50,256] K^T[*,256] via MFMA; masked softmax; O = P V via MFMA.
// NMEM = 0 (attn1) or 8 (attn2: mem rows prepended). Output bf16, mask-zeroed.
// PEQ/PEKV: add PE table TAB[abs(t-last[b])*256+c] while staging (fused add_pe3).
template <int NMEM, int PEQ, int PEKV>
__global__ __launch_bounds__(256) void attn_mfma(const float* __restrict__ q1,
    const float* __restrict__ kseq, const float* __restrict__ vseq,
    const float* __restrict__ kmem, const float* __restrict__ vmem,
    const int* __restrict__ mask, ushort* __restrict__ out,
    const float* __restrict__ TAB, const int* __restrict__ lastp) {
  constexpr int NK = NMEM + Nsq;            // valid K/V rows (50 or 58)
  __shared__ ushort KV[64][264];            // Q -> K -> V staging (bf16)
  __shared__ float Ss[64][66];              // scores fp32
  __shared__ ushort Ps[64][72];             // probabilities bf16
  __shared__ int msk[64];
  int tid = threadIdx.x;
  int lane = tid & 63, wave = tid >> 6;
  int quad = lane >> 4, l16 = lane & 15;
  int b = blockIdx.x;
  int last = lastp[b];

  if (tid < 64) msk[tid] = (tid < Nsq) ? mask[b * Nsq + tid] : 0;

  // ---- stage Q (rows t<50, else 0); PE added in-flight
#pragma unroll
  for (int it = 0; it < 16; ++it) {
    int idx = tid + it * 256;
    int r = idx >> 6, c4 = (idx & 63) * 4;
    float4 v = make_float4(0.f, 0.f, 0.f, 0.f);
    if (r < Nsq) {
      v = *(const float4*)(q1 + ((size_t)(b * Nsq + r)) * 256 + c4);
      if (PEQ) {
        float4 pe = *(const float4*)(TAB + abs(r - last) * 256 + c4);
        v.x += pe.x; v.y += pe.y; v.z += pe.z; v.w += pe.w;
      }
    }
    ushort4 o; o.x = f2b(v.x); o.y = f2b(v.y); o.z = f2b(v.z); o.w = f2b(v.w);
    *(ushort4*)&KV[r][c4] = o;
  }
  __syncthreads();
  // Q A-frags: wave w owns t rows [w*16, w*16+16)
  bf16x8 qa[8];
#pragma unroll
  for (int kf = 0; kf < 8; ++kf)
    qa[kf] = *(const bf16x8*)&KV[wave * 16 + l16][kf * 32 + quad * 8];
  __syncthreads();

  // ---- stage K (rows: [0,NMEM) mem, [NMEM,NK) seq, else 0); PE on seq rows
#pragma unroll
  for (int it = 0; it < 16; ++it) {
    int idx = tid + it * 256;
    int r = idx >> 6, c4 = (idx & 63) * 4;
    float4 v = make_float4(0.f, 0.f, 0.f, 0.f);
    if (r < NK) {
      if (NMEM > 0 && r < NMEM) {
        v = *(const float4*)(kmem + (size_t)r * 256 + c4);
      } else {
        v = *(const float4*)(kseq + ((size_t)(b * Nsq + (r - NMEM))) * 256 + c4);
        if (PEKV) {
          float4 pe = *(const float4*)(TAB + abs((r - NMEM) - last) * 256 + c4);
          v.x += pe.x; v.y += pe.y; v.z += pe.z; v.w += pe.w;
        }
      }
    }
    ushort4 o; o.x = f2b(v.x); o.y = f2b(v.y); o.z = f2b(v.z); o.w = f2b(v.w);
    *(ushort4*)&KV[r][c4] = o;
  }
  __syncthreads();

  // ---- S = Q K^T  (wave w: rows [w*16, +16) x all 64 cols)
  {
    f32x4 acc[4] = {};
#pragma unroll
    for (int kf = 0; kf < 8; ++kf) {
#pragma unroll
      for (int nf = 0; nf < 4; ++nf) {
        bf16x8 bf = *(const bf16x8*)&KV[nf * 16 + l16][kf * 32 + quad * 8];
        acc[nf] = __builtin_amdgcn_mfma_f32_16x16x32_bf16(qa[kf], bf, acc[nf], 0, 0, 0);
      }
    }
#pragma unroll
    for (int nf = 0; nf < 4; ++nf)
#pragma unroll
      for (int r = 0; r < 4; ++r)
        Ss[wave * 16 + quad * 4 + r][nf * 16 + l16] = acc[nf][r];
  }
  __syncthreads();

  // ---- stage V over K region (all threads); PE on seq rows ...
#pragma unroll
  for (int it = 0; it < 16; ++it) {
    int idx = tid + it * 256;
    int r = idx >> 6, c4 = (idx & 63) * 4;
    float4 v = make_float4(0.f, 0.f, 0.f, 0.f);
    if (r < NK) {
      if (NMEM > 0 && r < NMEM) {
        v = *(const float4*)(vmem + (size_t)r * 256 + c4);
      } else {
        v = *(const float4*)(vseq + ((size_t)(b * Nsq + (r - NMEM))) * 256 + c4);
        if (PEKV) {
          float4 pe = *(const float4*)(TAB + abs((r - NMEM) - last) * 256 + c4);
          v.x += pe.x; v.y += pe.y; v.z += pe.z; v.w += pe.w;
        }
      }
    }
    ushort4 o; o.x = f2b(v.x); o.y = f2b(v.y); o.z = f2b(v.z); o.w = f2b(v.w);
    *(ushort4*)&KV[r][c4] = o;
  }
  // ... while lane-per-row softmax runs on wave 0
  if (tid < 64) {
    int t = tid;
    if (t < Nsq) {
      float m = -1e30f;
      for (int j = 0; j < NK; ++j) {
        bool ok = (j < NMEM) || (((j - NMEM) <= t) && (msk[j - NMEM] != 0));
        if (ok) m = fmaxf(m, Ss[t][j] * SCALE_C);
      }
      float sum = 0.0f;
      for (int j = 0; j < NK; ++j) {
        bool ok = (j < NMEM) || (((j - NMEM) <= t) && (msk[j - NMEM] != 0));
        if (ok) sum += __expf(Ss[t][j] * SCALE_C - m);
      }
      float inv = 1.0f / sum;
      for (int j = 0; j < 64; ++j) {
        float p = 0.0f;
        if (j < NK) {
          bool ok = (j < NMEM) || (((j - NMEM) <= t) && (msk[j - NMEM] != 0));
          if (ok) p = __expf(Ss[t][j] * SCALE_C - m) * inv;
        }
        Ps[t][j] = f2b(p);
      }
    } else {
      for (int j = 0; j < 64; ++j) Ps[t][j] = 0;
    }
  }
  __syncthreads();

  // ---- O = P V  (wave w: all 64 t-rows x h in [w*64, +64))
  {
    f32x4 o[4][4] = {};
#pragma unroll
    for (int kf = 0; kf < 2; ++kf) {
      bf16x8 pa[4];
#pragma unroll
      for (int mf = 0; mf < 4; ++mf)
        pa[mf] = *(const bf16x8*)&Ps[mf * 16 + l16][kf * 32 + quad * 8];
#pragma unroll
      for (int nf = 0; nf < 4; ++nf) {
        int h = wave * 64 + nf * 16 + l16;
        ushort e0 = KV[kf * 32 + quad * 8 + 0][h];
        ushort e1 = KV[kf * 32 + quad * 8 + 1][h];
        ushort e2 = KV[kf * 32 + quad * 8 + 2][h];
        ushort e3 = KV[kf * 32 + quad * 8 + 3][h];
        ushort e4 = KV[kf * 32 + quad * 8 + 4][h];
        ushort e5 = KV[kf * 32 + quad * 8 + 5][h];
        ushort e6 = KV[kf * 32 + quad * 8 + 6][h];
        ushort e7 = KV[kf * 32 + quad * 8 + 7][h];
        bf16x8 vb = {(short)e0, (short)e1, (short)e2, (short)e3,
                     (short)e4, (short)e5, (short)e6, (short)e7};
#pragma unroll
        for (int mf = 0; mf < 4; ++mf)
          o[mf][nf] = __builtin_amdgcn_mfma_f32_16x16x32_bf16(pa[mf], vb, o[mf][nf], 0, 0, 0);
      }
    }
#pragma unroll
    for (int mf = 0; mf < 4; ++mf) {
#pragma unroll
      for (int r = 0; r < 4; ++r) {
        int t = mf * 16 + quad * 4 + r;
        if (t < Nsq) {
          int zero = (msk[t] == 0);
#pragma unroll
          for (int nf = 0; nf < 4; ++nf) {
            int h = wave * 64 + nf * 16 + l16;
            float val = zero ? 0.0f : o[mf][nf][r];
            out[((size_t)(b * Nsq + t)) * 256 + h] = f2b(val);
          }
        }
      }
    }
  }
}

// ---------------------------------------------------------------- alpha + sess (→ sesscat)
// att = relu(att1p + att2p) computed inline (fused relu_add).
__global__ __launch_bounds__(256) void alpha_sess_kernel(const float* __restrict__ att1,
    const float* __restrict__ att2,
    const float* __restrict__ W3, const float* __restrict__ q11,
    const float* __restrict__ se1, const int* __restrict__ mask,
    const float* __restrict__ srl, float* __restrict__ sesscat) {
  int b = blockIdx.x, tid = threadIdx.x;
  __shared__ float red[256];
  __shared__ float ash[50];
  red[tid] = q11[b * Hd + tid] * W3[256 + tid];
  __syncthreads();
  for (int s = 128; s; s >>= 1) { if (tid < s) red[tid] += red[tid + s]; __syncthreads(); }
  float cq = red[0];
  float aval = 0.0f;
  if (tid < 50) {
    float s = cq;
    const float* a1 = att1 + ((size_t)b * Nsq + tid) * Hd;
    const float* a2 = att2 + ((size_t)b * Nsq + tid) * Hd;
    for (int hh = 0; hh < 256; ++hh) s += fmaxf(a1[hh] + a2[hh], 0.0f) * W3[hh];
    aval = mask[b * Nsq + tid] ? s : NEG_C;
  }
  if (tid < 64) {
    float s = (tid < 50) ? aval : NEG_C;
    float m = s;
    for (int off = 32; off; off >>= 1) m = fmaxf(m, __shfl_xor(m, off));
    float e = expf(s - m);
    float sum = e;
    for (int off = 32; off; off >>= 1) sum += __shfl_xor(sum, off);
    if (tid < 50) ash[tid] = e / sum;
  }
  __syncthreads();
  float acc = 0.0f;
  const float* se = se1 + (size_t)b * Nsq * Hd;
  for (int t = 0; t < Nsq; ++t) acc += ash[t] * se[t * 256 + tid];
  sesscat[(size_t)b * 512 + tid] = acc;
  sesscat[(size_t)b * 512 + 256 + tid] = srl[b * Hd + tid];
}

// ---------------------------------------------------------------- beta + boundary (fp32)
__global__ __launch_bounds__(256) void beta_kernel(const float* __restrict__ sess2,
    const float* __restrict__ Wt1, const float* __restrict__ bt1,
    const float* __restrict__ Wt2, float* __restrict__ beta, float* __restrict__ bnd) {
  int b = blockIdx.x, tid = threadIdx.x;
  __shared__ float xs[256];
  __shared__ float r0[256], r1[256];
  xs[tid] = sess2[b * Hd + tid];
  __syncthreads();
  float hsum = bt1[tid];
  for (int k = 0; k < 256; ++k) hsum += xs[k] * Wt1[k * 256 + tid];
  float hid = fmaxf(hsum, 0.0f);
  r0[tid] = hid * Wt2[tid * 2 + 0];
  r1[tid] = hid * Wt2[tid * 2 + 1];
  __syncthreads();
  for (int s = 128; s; s >>= 1) {
    if (tid < s) { r0[tid] += r0[tid + s]; r1[tid] += r1[tid + s]; }
    __syncthreads();
  }
  if (tid == 0) {
    float t0 = r0[0], t1 = r1[0];
    float m = fmaxf(t0, t1);
    float e0 = expf(t0 - m), e1 = expf(t1 - m);
    float bb0 = e0 / (e0 + e1), bb1 = e1 / (e0 + e1);
    beta[b * 2] = bb0; beta[b * 2 + 1] = bb1;
    atomicAdd(bnd, fabsf(bb0 - bb1) * (1.0f / 512.0f));
  }
}

// ---------------------------------------------------------------- fused score softmax + final
// One block (1024 thr) per row b. Flags packed once into a 5 KB LDS bitmask (pass 1);
// passes 2-3 never re-read flag. No intermediate stores: pass 2 only sums, pass 3
// recomputes the exp and writes fin directly. Score row (160 KB) stays L3-resident
// across passes. Each element contributes to exactly one side (exp(NEG-M) == 0).
__global__ __launch_bounds__(1024) void score_final_fused(float* __restrict__ score,
    const int* __restrict__ flag, const float* __restrict__ beta) {
  int b = blockIdx.x, tid = threadIdx.x;
  float4* sr = (float4*)(score + (size_t)b * VM1);
  const int4* fr = (const int4*)(flag + (size_t)b * VM1);
  constexpr int NV = VM1 / 4;        // 10000 int4/float4 groups
  constexpr int NW = (NV + 7) / 8;   // 1250 bitmask words (4 bits per group)

  __shared__ uint bits[NW];
  __shared__ float red[1024], red2[1024];

  for (int i = tid; i < NW; i += 1024) bits[i] = 0u;
  __syncthreads();

  // ---- pass 1: per-side maxes + flag bitmask
  float mi = -INFINITY, me = -INFINITY;
  for (int i = tid; i < NV; i += 1024) {
    float4 s = sr[i];
    int4 f = fr[i];
    uint nib = (f.x ? 1u : 0u) | (f.y ? 2u : 0u) | (f.z ? 4u : 0u) | (f.w ? 8u : 0u);
    if (nib) atomicOr(&bits[i >> 3], nib << ((i & 7) * 4));
    if (f.x) mi = fmaxf(mi, s.x); else me = fmaxf(me, s.x);
    if (f.y) mi = fmaxf(mi, s.y); else me = fmaxf(me, s.y);
    if (f.z) mi = fmaxf(mi, s.z); else me = fmaxf(me, s.z);
    if (f.w) mi = fmaxf(mi, s.w); else me = fmaxf(me, s.w);
  }
  red[tid] = mi; red2[tid] = me;
  __syncthreads();
  for (int s = 512; s; s >>= 1) {
    if (tid < s) { red[tid] = fmaxf(red[tid], red[tid + s]); red2[tid] = fmaxf(red2[tid], red2[tid + s]); }
    __syncthreads();
  }
  float Mi = red[0], Me = red2[0];
  __syncthreads();

  // ---- pass 2: per-side sums (no stores; score re-read from L3)
  float si = 0.0f, se = 0.0f;
  for (int i = tid; i < NV; i += 1024) {
    float4 s = sr[i];
    uint nib = bits[i >> 3] >> ((i & 7) * 4);
    float e0 = __expf(s.x - ((nib & 1u) ? Mi : Me));
    float e1 = __expf(s.y - ((nib & 2u) ? Mi : Me));
    float e2 = __expf(s.z - ((nib & 4u) ? Mi : Me));
    float e3 = __expf(s.w - ((nib & 8u) ? Mi : Me));
    si += ((nib & 1u) ? e0 : 0.0f) + ((nib & 2u) ? e1 : 0.0f)
        + ((nib & 4u) ? e2 : 0.0f) + ((nib & 8u) ? e3 : 0.0f);
    se += ((nib & 1u) ? 0.0f : e0) + ((nib & 2u) ? 0.0f : e1)
        + ((nib & 4u) ? 0.0f : e2) + ((nib & 8u) ? 0.0f : e3);
  }
  red[tid] = si; red2[tid] = se;
  __syncthreads();
  for (int s = 512; s; s >>= 1) {
    if (tid < s) { red[tid] += red[tid + s]; red2[tid] += red2[tid + s]; }
    __syncthreads();
  }
  float c0 = beta[b * 2] / red[0];
  float c1 = beta[b * 2 + 1] / red2[0];
  __syncthreads();

  // ---- pass 3: recompute exp, write fin in place
  for (int i = tid; i < NV; i += 1024) {
    float4 s = sr[i];
    uint nib = bits[i >> 3] >> ((i & 7) * 4);
    s.x = ((nib & 1u) ? c0 : c1) * __expf(s.x - ((nib & 1u) ? Mi : Me));
    s.y = ((nib & 2u) ? c0 : c1) * __expf(s.y - ((nib & 2u) ? Mi : Me));
    s.z = ((nib & 4u) ? c0 : c1) * __expf(s.z - ((nib & 4u) ? Mi : Me));
    s.w = ((nib & 8u) ? c0 : c1) * __expf(s.w - ((nib & 8u) ? Mi : Me));
    sr[i] = s;
  }
}

// ================================================================ launch
extern "C" void kernel_launch(void* const* d_in, const int* in_sizes, int n_in,
                              void* d_out, int out_size, void* d_ws, size_t ws_size,
                              hipStream_t stream) {
  const float* seq1  = (const float*)d_in[0];
  const float* seq2  = (const float*)d_in[1];
  const int*   mask  = (const int*)d_in[2];
  const int*   iflag = (const int*)d_in[3];
  const float* wih0  = (const float*)d_in[4];
  const float* whh0  = (const float*)d_in[5];
  const float* bih0  = (const float*)d_in[6];
  const float* bhh0  = (const float*)d_in[7];
  const float* wih1  = (const float*)d_in[8];
  const float* whh1  = (const float*)d_in[9];
  const float* bih1  = (const float*)d_in[10];
  const float* bhh1  = (const float*)d_in[11];
  const float* Wq1   = (const float*)d_in[12];
  const float* Wk1   = (const float*)d_in[13];
  const float* Wv1   = (const float*)d_in[14];
  const float* Wk2   = (const float*)d_in[16];
  const float* Wv2   = (const float*)d_in[17];
  const float* Wffn1 = (const float*)d_in[18];
  const float* bffn1 = (const float*)d_in[19];
  const float* Wffn2 = (const float*)d_in[20];
  const float* bffn2 = (const float*)d_in[21];
  const float* Wone  = (const float*)d_in[22];
  const float* bone  = (const float*)d_in[23];
  const float* W3    = (const float*)d_in[24];
  const float* Wtr   = (const float*)d_in[25];
  const float* btr   = (const float*)d_in[26];
  const float* Wt1   = (const float*)d_in[27];
  const float* bt1   = (const float*)d_in[28];
  const float* Wt2   = (const float*)d_in[29];
  const float* memk  = (const float*)d_in[30];
  const float* memv  = (const float*)d_in[31];
  const float* emb1  = (const float*)d_in[32];
  float* out = (float*)d_out;

  // Workspace layout (byte offsets, all 16B-aligned). Total ≈ 214.1 MB.
  char* wsb = (char*)d_ws;
  float*  TAB    = (float*)(wsb + 0);            // 51,200
  int*    lastp  = (int*)  (wsb + 51200);        // 2,048
  float*  srl    = (float*)(wsb + 53248);        // 524,288
  float*  q11    = (float*)(wsb + 577536);       // 524,288
  ushort* whh0b  = (ushort*)(wsb + 1101824);     // 393,216 (bf16 whh, layer 0)
  ushort* whh1b  = (ushort*)(wsb + 1888256);     // 393,216 (bf16 whh, layer 1)
  ushort* wih0b  = (ushort*)(wsb + 2674688);     // 393,216
  ushort* wih1b  = (ushort*)(wsb + 3067904);     // 393,216
  ushort* w7b    = (ushort*)(wsb + 3461120);     // 7 x 131,072
  ushort* bufS   = (ushort*)(wsb + 4378624);     // 13,107,200  seq2b -> ys1b -> se2b
  float*  se1    = (float*)(wsb + 17485824);     // 26,214,400
  ushort* se1b   = (ushort*)(wsb + 43700224);    // 13,107,200
  float*  giQ    = (float*)(wsb + 56807424);     // 78,643,200  gi -> q1|k1|v1 -> tail
  float*  kv2a   = (float*)(wsb + 135450624);    // 26,214,400  k2 -> att1p
  float*  kv2b   = (float*)(wsb + 161665024);    // 26,214,400  v2 -> att2p
  ushort* ao1b   = (ushort*)(wsb + 187879424);   // 13,107,200
  ushort* ao2b   = (ushort*)(wsb + 200986624);   // 13,107,200

  float* gi = giQ;
  float* q1 = giQ;
  float* k1 = giQ + 6553600;
  float* v1 = giQ + 13107200;
  // tail block (reuses giQ after attn2):
  ushort* embB    = (ushort*)giQ;                             // 20,480,000 B
  float*  sesscat = (float*)((char*)giQ + 20480000);          // 1,048,576
  float*  sess2   = (float*)((char*)giQ + 21528576);          // 524,288
  ushort* sess2b  = (ushort*)((char*)giQ + 22052864);         // 262,144
  float*  betab   = (float*)((char*)giQ + 22315008);          // 4,096
  float*  stats   = (float*)((char*)giQ + 22319104);          // 8,192
  float*  bnd     = out + (size_t)Bsz * VM1;                  // boundary output slot

  ushort* Wq1b = w7b;              ushort* Wk1b = w7b + 65536;
  ushort* Wv1b = w7b + 131072;     ushort* Wk2b = w7b + 196608;
  ushort* Wv2b = w7b + 262144;     ushort* Wf1b = w7b + 327680;
  ushort* Wf2b = w7b + 393216;

  // ---- table / last / q1_1 (fp32 path)
  build_tab<<<50, 256, 0, stream>>>(TAB);
  last_srl_kernel<<<Bsz, 256, 0, stream>>>(mask, seq1, lastp, srl);
  gemm_tile<0, 1><<<dim3(4, 4), 256, 0, stream>>>(srl, Wone, bone, q11, 512, 256, 256);
  add_tab0<<<512, 256, 0, stream>>>(q11);

  // ---- weight casts
  cast_f2b_k<<<6400, 256, 0, stream>>>(seq2, bufS, 1638400);
  cast_f2b_k<<<192, 256, 0, stream>>>(wih0, wih0b, 49152);
  cast_f2b_k<<<192, 256, 0, stream>>>(wih1, wih1b, 49152);
  cast_f2b_k<<<192, 256, 0, stream>>>(whh0, whh0b, 49152);
  cast_f2b_k<<<192, 256, 0, stream>>>(whh1, whh1b, 49152);
  Cast7 c7;
  c7.s[0] = Wq1; c7.s[1] = Wk1; c7.s[2] = Wv1; c7.s[3] = Wk2; c7.s[4] = Wv2;
  c7.s[5] = Wffn1; c7.s[6] = Wffn2;
  c7.d[0] = Wq1b; c7.d[1] = Wk1b; c7.d[2] = Wv1b; c7.d[3] = Wk2b; c7.d[4] = Wv2b;
  c7.d[5] = Wf1b; c7.d[6] = Wf2b;
  cast7_k<<<dim3(64, 7), 256, 0, stream>>>(c7);

  // ---- GRU (gi via MFMA, recurrence via 8-wave/2-sample MFMA kernel, 1 barrier/step)
  mfma_gemm<1, 1><<<dim3(6, 200), 256, 0, stream>>>(bufS, wih0b, bih0, gi, 25600, 768, 256);
  gru_mfma8_kernel<<<256, 512, 0, stream>>>(gi, whh0b, bhh0, bufS, nullptr);
  mfma_gemm<1, 1><<<dim3(6, 200), 256, 0, stream>>>(bufS, wih1b, bih1, gi, 25600, 768, 256);
  gru_mfma8_kernel<<<256, 512, 0, stream>>>(gi, whh1b, bhh1, bufS, mask);   // -> se2 bf16

  // ---- masked seq1 (fp32 + bf16)
  mask_mul_dual<<<25600, 256, 0, stream>>>(seq1, mask, se1, se1b);

  // ---- projections (MFMA); PE is added during attention staging (fused)
  mfma_gemm<0, 0><<<dim3(2, 200), 256, 0, stream>>>(bufS, Wk2b, nullptr, kv2a, 25600, 256, 256);
  mfma_gemm<0, 0><<<dim3(2, 200), 256, 0, stream>>>(bufS, Wv2b, nullptr, kv2b, 25600, 256, 256);
  mfma_gemm<0, 0><<<dim3(2, 200), 256, 0, stream>>>(se1b, Wq1b, nullptr, q1, 25600, 256, 256);
  mfma_gemm<0, 0><<<dim3(2, 200), 256, 0, stream>>>(se1b, Wk1b, nullptr, k1, 25600, 256, 256);
  mfma_gemm<0, 0><<<dim3(2, 200), 256, 0, stream>>>(se1b, Wv1b, nullptr, v1, 25600, 256, 256);

  // ---- attentions (MFMA, fp32 in, bf16 out; PE fused into staging)
  attn_mfma<0, 1, 1><<<Bsz, 256, 0, stream>>>(q1, k1, v1, nullptr, nullptr, mask, ao1b, TAB, lastp);
  attn_mfma<8, 1, 0><<<Bsz, 256, 0, stream>>>(q1, kv2a, kv2b, memk, memv, mask, ao2b, TAB, lastp);
  mfma_gemm<0, 1><<<dim3(2, 200), 256, 0, stream>>>(ao1b, Wf1b, bffn1, kv2a, 25600, 256, 256);
  mfma_gemm<0, 1><<<dim3(2, 200), 256, 0, stream>>>(ao2b, Wf2b, bffn2, kv2b, 25600, 256, 256);

  // ---- pooling + session (fp32; relu(att1p+att2p) fused into alpha)
  alpha_sess_kernel<<<Bsz, 256, 0, stream>>>(kv2a, kv2b, W3, q11, se1, mask, srl, sesscat);
  gemm_tile<0, 1><<<dim3(4, 4), 256, 0, stream>>>(sesscat, Wtr, btr, sess2, 512, 256, 512);
  cast_f2b_k<<<128, 256, 0, stream>>>(sess2, sess2b, 32768);

  // ---- tail gating (fp32) + scoring (MFMA) + fused softmax/final
  hipMemsetAsync(bnd, 0, 4, stream);
  beta_kernel<<<Bsz, 256, 0, stream>>>(sess2, Wt1, bt1, Wt2, betab, bnd);
  cast_f2b_k<<<10000, 256, 0, stream>>>(emb1 + 256, embB, 2560000);
  mfma_gemm<1, 0><<<dim3(313, 4), 256, 0, stream>>>(sess2b, embB, nullptr, out, 512, VM1, 256);
  score_final_fused<<<Bsz, 1024, 0, stream>>>(out, iflag, betab);

  (void)in_sizes; (void)n_in; (void)out_size; (void)ws_size;
}

// Round 8
// 912.297 us; speedup vs baseline: 1.1857x; 1.0228x over previous
//
#include <hip/hip_runtime.h>
#include <hip/hip_bf16.h>
#include <cstdint>
#include <cstddef>

// Problem dims
#define Bsz 512
#define Nsq 50
#define Hd  256
#define VM1 40000
static constexpr float SCALE_C = 0.0625f;   // 1/sqrt(256)
static constexpr float NEG_C   = -1.0e12f;

typedef __attribute__((ext_vector_type(8))) short bf16x8;
typedef __attribute__((ext_vector_type(4))) float f32x4;

__device__ __forceinline__ float sigmoidf_(float x) { return 1.0f / (1.0f + __expf(-x)); }
__device__ __forceinline__ float tanh_fast(float x) {
  float t = fminf(fmaxf(2.0f * x, -60.0f), 60.0f);
  float e = __expf(t);
  return (e - 1.0f) / (e + 1.0f);
}
__device__ __forceinline__ ushort f2b(float x) {   // fp32 -> bf16 (RNE)
  union { float f; uint32_t u; } c; c.f = x;
  uint32_t r = (c.u + 0x7fffu + ((c.u >> 16) & 1u)) >> 16;
  return (ushort)r;
}

// ---------------------------------------------------------------- TAB (50x256)
__global__ void build_tab(float* __restrict__ TAB) {
  int idx = blockIdx.x * 256 + threadIdx.x;
  int pos = idx >> 8, j = idx & 255;
  int pair = j >> 1;
  float expo = (2.0f * (float)pair) / 256.0f;
  float inv = powf(10000.0f, -expo);
  float ang = (float)pos * inv;
  TAB[idx] = (j & 1) ? cosf(ang) : sinf(ang);
}

// ------------------------------------------------- last[b], sr_l_1 = seq1[b,last]
__global__ __launch_bounds__(256) void last_srl_kernel(const int* __restrict__ mask,
    const float* __restrict__ seq1, int* __restrict__ lastp, float* __restrict__ srl) {
  int b = blockIdx.x, tid = threadIdx.x;
  __shared__ int ls;
  if (tid == 0) {
    int c = 0;
    for (int t = 0; t < Nsq; ++t) c += mask[b * Nsq + t];
    ls = c - 1;
    lastp[b] = c - 1;
  }
  __syncthreads();
  srl[b * Hd + tid] = seq1[((size_t)b * Nsq + ls) * Hd + tid];
}

// ---------------------------------------------------------------- fp32 GEMM (small shapes only)
template <int BT, int BIAS>
__global__ __launch_bounds__(256) void gemm_tile(const float* __restrict__ A,
    const float* __restrict__ B, const float* __restrict__ bias,
    float* __restrict__ C, int M, int N, int K) {
  __shared__ float As[16][132];
  __shared__ float Bs[16][68];
  int bm = blockIdx.y * 128, bn = blockIdx.x * 64;
  int tid = threadIdx.x;
  int tm = (tid >> 4) << 3;
  int tn = (tid & 15) << 2;
  float acc[8][4] = {};
  for (int k0 = 0; k0 < K; k0 += 16) {
#pragma unroll
    for (int u = 0; u < 8; ++u) {
      int i = tid + u * 256;
      int kk = i & 15, m = i >> 4;
      As[kk][m] = A[(size_t)(bm + m) * K + (k0 + kk)];
    }
#pragma unroll
    for (int u = 0; u < 4; ++u) {
      int i = tid + u * 256;
      if (BT) {
        int kk = i & 15, n = i >> 4;
        Bs[kk][n] = B[(size_t)(bn + n) * K + (k0 + kk)];
      } else {
        int n = i & 63, kk = i >> 6;
        Bs[kk][n] = B[(size_t)(k0 + kk) * N + (bn + n)];
      }
    }
    __syncthreads();
#pragma unroll
    for (int kk = 0; kk < 16; ++kk) {
      float a[8], bb[4];
#pragma unroll
      for (int r = 0; r < 8; ++r) a[r] = As[kk][tm + r];
#pragma unroll
      for (int c = 0; c < 4; ++c) bb[c] = Bs[kk][tn + c];
#pragma unroll
      for (int r = 0; r < 8; ++r)
#pragma unroll
        for (int c = 0; c < 4; ++c) acc[r][c] += a[r] * bb[c];
    }
    __syncthreads();
  }
#pragma unroll
  for (int r = 0; r < 8; ++r) {
    size_t row = (size_t)(bm + tm + r) * N + bn;
#pragma unroll
    for (int c = 0; c < 4; ++c) {
      float v = acc[r][c];
      if (BIAS) v += bias[bn + tn + c];
      C[row + tn + c] = v;
    }
  }
}

// ---------------------------------------------------------------- bf16 MFMA GEMM
// C[M,N] fp32 = A_bf[M,K] @ (BT ? B_bf[N,K]^T : B_bf[K,N]) (+bias)
// tile 128x128, BK=32, 256 threads = 4 waves (each 64x64 quadrant, 4x4 frags of 16x16x32).
// A staged via global_load_lds width=16 into linear [128][32] LDS (m97-proven pattern);
// BT=1 B likewise; BT=0 B keeps the padded transpose-stage (gload_lds can't transpose).
template <int BT, int BIAS>
__global__ __launch_bounds__(256) void mfma_gemm(const ushort* __restrict__ A,
    const ushort* __restrict__ B, const float* __restrict__ bias,
    float* __restrict__ C, int M, int N, int K) {
  __shared__ ushort Asm[128 * 32];   // linear: Asm[r*32+c] = A[bm+r][k0+c]
  __shared__ ushort Bsm[128 * 40];   // BT=1: linear [r*32+c]; BT=0: padded [n*40+k]
  constexpr int SB = BT ? 32 : 40;
  int tid = threadIdx.x;
  int bm = blockIdx.y * 128, bn = blockIdx.x * 128;
  int lane = tid & 63, wave = tid >> 6;
  int quad = lane >> 4, l16 = lane & 15;
  int wm = (wave >> 1) * 64, wn = (wave & 1) * 64;

  // gload_lds chunk mapping: chunk chn = rows [chn*16,+16); lane l -> row chn*16+(l>>2),
  // col (l&3)*8; dest byte = chn*1024 + l*16  (wave-uniform base, HW adds lane*16).
  int chn0 = wave * 2, chn1 = wave * 2 + 1;
  int ra0 = chn0 * 16 + (lane >> 2), ra1 = chn1 * 16 + (lane >> 2);
  int kc = (lane & 3) * 8;
  const ushort* srcA0 = A + (size_t)(bm + ra0) * K + kc;
  const ushort* srcA1 = A + (size_t)(bm + ra1) * K + kc;
  char* dstA0 = (char*)Asm + chn0 * 1024;
  char* dstA1 = (char*)Asm + chn1 * 1024;
  const ushort* srcB0 = nullptr;
  const ushort* srcB1 = nullptr;
  if (BT) {
    int rb0 = bn + ra0; if (rb0 > N - 1) rb0 = N - 1;   // clamp: cols >= N never stored
    int rb1 = bn + ra1; if (rb1 > N - 1) rb1 = N - 1;
    srcB0 = B + (size_t)rb0 * K + kc;
    srcB1 = B + (size_t)rb1 * K + kc;
  }
  char* dstB0 = (char*)Bsm + chn0 * 1024;
  char* dstB1 = (char*)Bsm + chn1 * 1024;

  f32x4 acc[4][4] = {};
  for (int k0 = 0; k0 < K; k0 += 32) {
    __builtin_amdgcn_global_load_lds(
        (const __attribute__((address_space(1))) void*)(srcA0 + k0),
        (__attribute__((address_space(3))) void*)dstA0, 16, 0, 0);
    __builtin_amdgcn_global_load_lds(
        (const __attribute__((address_space(1))) void*)(srcA1 + k0),
        (__attribute__((address_space(3))) void*)dstA1, 16, 0, 0);
    if (BT) {
      __builtin_amdgcn_global_load_lds(
          (const __attribute__((address_space(1))) void*)(srcB0 + k0),
          (__attribute__((address_space(3))) void*)dstB0, 16, 0, 0);
      __builtin_amdgcn_global_load_lds(
          (const __attribute__((address_space(1))) void*)(srcB1 + k0),
          (__attribute__((address_space(3))) void*)dstB1, 16, 0, 0);
    } else {
#pragma unroll
      for (int u = 0; u < 8; ++u) {             // transpose-stage: 2 n per thread
        int idx = tid + u * 256;
        int n2 = (idx & 63) * 2, kk = idx >> 6;
        uint v = *(const uint*)(B + (size_t)(k0 + kk) * N + bn + n2);
        Bsm[n2 * 40 + kk] = (ushort)(v & 0xffffu);
        Bsm[(n2 + 1) * 40 + kk] = (ushort)(v >> 16);
      }
    }
    __syncthreads();                            // drains vmcnt (gload_lds) + lgkm
    bf16x8 af[4], bfr[4];
#pragma unroll
    for (int f = 0; f < 4; ++f) af[f] = *(const bf16x8*)(Asm + (wm + f * 16 + l16) * 32 + quad * 8);
#pragma unroll
    for (int f = 0; f < 4; ++f) bfr[f] = *(const bf16x8*)(Bsm + (wn + f * 16 + l16) * SB + quad * 8);
#pragma unroll
    for (int mf = 0; mf < 4; ++mf)
#pragma unroll
      for (int nf = 0; nf < 4; ++nf)
        acc[mf][nf] = __builtin_amdgcn_mfma_f32_16x16x32_bf16(af[mf], bfr[nf], acc[mf][nf], 0, 0, 0);
    __syncthreads();
  }
#pragma unroll
  for (int mf = 0; mf < 4; ++mf) {
#pragma unroll
    for (int r = 0; r < 4; ++r) {
      int row = bm + wm + mf * 16 + quad * 4 + r;
      size_t rowo = (size_t)row * N;
#pragma unroll
      for (int nf = 0; nf < 4; ++nf) {
        int col = bn + wn + nf * 16 + l16;
        if (col < N) {
          float v = acc[mf][nf][r];
          if (BIAS) v += bias[col];
          C[rowo + col] = v;
        }
      }
    }
  }
}

// ---------------------------------------------------------------- casts
__global__ void cast_f2b_k(const float* __restrict__ s, ushort* __restrict__ d, int n4) {
  int i = blockIdx.x * 256 + threadIdx.x;
  if (i >= n4) return;
  const float4 v = ((const float4*)s)[i];
  ushort4 o; o.x = f2b(v.x); o.y = f2b(v.y); o.z = f2b(v.z); o.w = f2b(v.w);
  ((ushort4*)d)[i] = o;
}

struct Cast7 { const float* s[7]; ushort* d[7]; };
__global__ void cast7_k(Cast7 p) {
  int m = blockIdx.y;
  int i = blockIdx.x * 256 + threadIdx.x;
  const float4 v = ((const float4*)p.s[m])[i];
  ushort4 o; o.x = f2b(v.x); o.y = f2b(v.y); o.z = f2b(v.z); o.w = f2b(v.w);
  ((ushort4*)p.d[m])[i] = o;
}

// ---------------------------------------------------------------- misc elementwise
__global__ void add_tab0(float* __restrict__ q) {
  int idx = blockIdx.x * 256 + threadIdx.x;
  q[idx] += (float)(threadIdx.x & 1);         // TAB[0]: sin(0)=0, cos(0)=1
}

__global__ void mask_mul_dual(const float* __restrict__ x, const int* __restrict__ m,
                              float* __restrict__ y, ushort* __restrict__ yb) {
  int idx = blockIdx.x * 256 + threadIdx.x;
  float v = m[idx >> 8] ? x[idx] : 0.0f;
  y[idx] = v;
  yb[idx] = f2b(v);
}

// ---------------------------------------------------------------- GRU layer (MFMA, reg-resident weights)
// 256 blocks x 8 waves (512 thr), 2 samples/block. ONE barrier per timestep:
// wave w computes ALL THREE gates for dims [w*32, w*32+32) (whh rows {d, 256+d, 512+d}),
// so its own MFMA output feeds its own 64 lanes' elementwise (2 samples x 32 dims).
// gh handoff via wave-private LDS scratch (same-wave DS ops are in-order -> no barrier).
// hbf double-buffered (write next, read cur) -> no WAR across the single barrier.
__global__ __launch_bounds__(512, 2) void gru_mfma8_kernel(const float* __restrict__ gi,
    const ushort* __restrict__ whhb, const float* __restrict__ bhh,
    ushort* __restrict__ ysb, const int* __restrict__ mask) {
  __shared__ ushort hbf[2][16][264];   // bf16 h, double-buffered (+8 pad)
  __shared__ float  gsc[8][2][3][32];  // per-wave gate scratch [wave][sample][gate][dim]
  int tid = threadIdx.x;
  int lane = tid & 63, wave = tid >> 6;
  int quad = lane >> 4, l16 = lane & 15;
  int s0 = blockIdx.x * 2;

  for (int i = tid; i < 2 * 16 * 264 / 2; i += 512) ((uint*)hbf)[i] = 0u;

  // reg-resident whh slice: wave w, frag nf: rows (nf>>1)*256 + w*32 + (nf&1)*16 + l16
  // (B-frag lane l16 = output row n, quad*8+j = k; same layout as proven mfma_gemm B-read)
  bf16x8 bw[48];
#pragma unroll
  for (int f = 0; f < 48; ++f) {
    int nf = f >> 3, kf = f & 7;
    int row = (nf >> 1) * 256 + wave * 32 + (nf & 1) * 16 + l16;
    bw[f] = *(const bf16x8*)(whhb + (size_t)row * 256 + kf * 32 + quad * 8);
  }

  // elementwise mapping: lane handles sample s = lane>>5, dim d = wave*32 + (lane&31)
  int s = lane >> 5, dloc = lane & 31;
  int d = wave * 32 + dloc;
  float bh0 = bhh[d], bh1 = bhh[256 + d], bh2 = bhh[512 + d];
  const float* gib = gi + (size_t)(s0 + s) * Nsq * 768 + d;
  float g0 = gib[0], g1 = gib[256], g2 = gib[512];
  float hreg = 0.0f;
  const int* mrow = mask + (s0 + s) * Nsq;   // only dereferenced if mask != null
  ushort* yrow = ysb + ((size_t)(s0 + s) * Nsq) * 256 + d;
  __syncthreads();

  int cur = 0;
  for (int t = 0; t < Nsq; ++t) {
    int tn = (t + 1 < Nsq) ? t + 1 : t;
    float p0 = gib[tn * 768], p1 = gib[tn * 768 + 256], p2 = gib[tn * 768 + 512];

    // ---- gh = h @ whh_slice^T  (A rows = samples; only rows 0..1 nonzero)
    f32x4 acc[6] = {};
#pragma unroll
    for (int kf = 0; kf < 8; ++kf) {
      bf16x8 a = *(const bf16x8*)&hbf[cur][l16][kf * 32 + quad * 8];
#pragma unroll
      for (int nf = 0; nf < 6; ++nf)
        acc[nf] = __builtin_amdgcn_mfma_f32_16x16x32_bf16(a, bw[nf * 8 + kf], acc[nf], 0, 0, 0);
    }
    // C layout: col = l16, row = quad*4 + reg = sample (rows 0,1 valid -> quad 0)
    if (quad == 0) {
#pragma unroll
      for (int g = 0; g < 3; ++g)
#pragma unroll
        for (int j = 0; j < 2; ++j) {
          gsc[wave][0][g][j * 16 + l16] = acc[g * 2 + j][0];
          gsc[wave][1][g][j * 16 + l16] = acc[g * 2 + j][1];
        }
    }
    __builtin_amdgcn_sched_barrier(0);   // pin gsc writes before reads (same-wave RAW)

    // ---- elementwise, fully in-wave (no block barrier needed for gh)
    {
      float ghr = gsc[wave][s][0][dloc];
      float ghz = gsc[wave][s][1][dloc];
      float ghn = gsc[wave][s][2][dloc];
      float rr = sigmoidf_(g0 + ghr + bh0);
      float zz = sigmoidf_(g1 + ghz + bh1);
      float nn = tanh_fast(g2 + rr * (ghn + bh2));
      float h2 = (1.0f - zz) * nn + zz * hreg;
      hreg = h2;
      hbf[cur ^ 1][s][d] = f2b(h2);
      float ov = h2;
      if (mask) ov = mrow[t] ? h2 : 0.0f;
      yrow[t * 256] = f2b(ov);
    }
    g0 = p0; g1 = p1; g2 = p2;
    cur ^= 1;
    __syncthreads();   // hbf[next] visible to all waves for step t+1
  }
}

// ---------------------------------------------------------------- MFMA attention
// One block per batch sample, 256 threads = 4 waves.
// S = Q[50,256] K^T[*,256] via MFMA; masked softmax; O = P V via MFMA.
// NMEM = 0 (attn1) or 8 (attn2: mem rows prepended). Output bf16, mask-zeroed.
// PEQ/PEKV: add PE table TAB[abs(t-last[b])*256+c] while staging (fused add_pe3).
template <int NMEM, int PEQ, int PEKV>
__global__ __launch_bounds__(256) void attn_mfma(const float* __restrict__ q1,
    const float* __restrict__ kseq, const float* __restrict__ vseq,
    const float* __restrict__ kmem, const float* __restrict__ vmem,
    const int* __restrict__ mask, ushort* __restrict__ out,
    const float* __restrict__ TAB, const int* __restrict__ lastp) {
  constexpr int NK = NMEM + Nsq;            // valid K/V rows (50 or 58)
  __shared__ ushort KV[64][264];            // Q -> K -> V staging (bf16)
  __shared__ float Ss[64][66];              // scores fp32
  __shared__ ushort Ps[64][72];             // probabilities bf16
  __shared__ int msk[64];
  int tid = threadIdx.x;
  int lane = tid & 63, wave = tid >> 6;
  int quad = lane >> 4, l16 = lane & 15;
  int b = blockIdx.x;
  int last = lastp[b];

  if (tid < 64) msk[tid] = (tid < Nsq) ? mask[b * Nsq + tid] : 0;

  // ---- stage Q (rows t<50, else 0); PE added in-flight
#pragma unroll
  for (int it = 0; it < 16; ++it) {
    int idx = tid + it * 256;
    int r = idx >> 6, c4 = (idx & 63) * 4;
    float4 v = make_float4(0.f, 0.f, 0.f, 0.f);
    if (r < Nsq) {
      v = *(const float4*)(q1 + ((size_t)(b * Nsq + r)) * 256 + c4);
      if (PEQ) {
        float4 pe = *(const float4*)(TAB + abs(r - last) * 256 + c4);
        v.x += pe.x; v.y += pe.y; v.z += pe.z; v.w += pe.w;
      }
    }
    ushort4 o; o.x = f2b(v.x); o.y = f2b(v.y); o.z = f2b(v.z); o.w = f2b(v.w);
    *(ushort4*)&KV[r][c4] = o;
  }
  __syncthreads();
  // Q A-frags: wave w owns t rows [w*16, w*16+16)
  bf16x8 qa[8];
#pragma unroll
  for (int kf = 0; kf < 8; ++kf)
    qa[kf] = *(const bf16x8*)&KV[wave * 16 + l16][kf * 32 + quad * 8];
  __syncthreads();

  // ---- stage K (rows: [0,NMEM) mem, [NMEM,NK) seq, else 0); PE on seq rows
#pragma unroll
  for (int it = 0; it < 16; ++it) {
    int idx = tid + it * 256;
    int r = idx >> 6, c4 = (idx & 63) * 4;
    float4 v = make_float4(0.f, 0.f, 0.f, 0.f);
    if (r < NK) {
      if (NMEM > 0 && r < NMEM) {
        v = *(const float4*)(kmem + (size_t)r * 256 + c4);
      } else {
        v = *(const float4*)(kseq + ((size_t)(b * Nsq + (r - NMEM))) * 256 + c4);
        if (PEKV) {
          float4 pe = *(const float4*)(TAB + abs((r - NMEM) - last) * 256 + c4);
          v.x += pe.x; v.y += pe.y; v.z += pe.z; v.w += pe.w;
        }
      }
    }
    ushort4 o; o.x = f2b(v.x); o.y = f2b(v.y); o.z = f2b(v.z); o.w = f2b(v.w);
    *(ushort4*)&KV[r][c4] = o;
  }
  __syncthreads();

  // ---- S = Q K^T  (wave w: rows [w*16, +16) x all 64 cols)
  {
    f32x4 acc[4] = {};
#pragma unroll
    for (int kf = 0; kf < 8; ++kf) {
#pragma unroll
      for (int nf = 0; nf < 4; ++nf) {
        bf16x8 bf = *(const bf16x8*)&KV[nf * 16 + l16][kf * 32 + quad * 8];
        acc[nf] = __builtin_amdgcn_mfma_f32_16x16x32_bf16(qa[kf], bf, acc[nf], 0, 0, 0);
      }
    }
#pragma unroll
    for (int nf = 0; nf < 4; ++nf)
#pragma unroll
      for (int r = 0; r < 4; ++r)
        Ss[wave * 16 + quad * 4 + r][nf * 16 + l16] = acc[nf][r];
  }
  __syncthreads();

  // ---- stage V over K region (all threads); PE on seq rows ...
#pragma unroll
  for (int it = 0; it < 16; ++it) {
    int idx = tid + it * 256;
    int r = idx >> 6, c4 = (idx & 63) * 4;
    float4 v = make_float4(0.f, 0.f, 0.f, 0.f);
    if (r < NK) {
      if (NMEM > 0 && r < NMEM) {
        v = *(const float4*)(vmem + (size_t)r * 256 + c4);
      } else {
        v = *(const float4*)(vseq + ((size_t)(b * Nsq + (r - NMEM))) * 256 + c4);
        if (PEKV) {
          float4 pe = *(const float4*)(TAB + abs((r - NMEM) - last) * 256 + c4);
          v.x += pe.x; v.y += pe.y; v.z += pe.z; v.w += pe.w;
        }
      }
    }
    ushort4 o; o.x = f2b(v.x); o.y = f2b(v.y); o.z = f2b(v.z); o.w = f2b(v.w);
    *(ushort4*)&KV[r][c4] = o;
  }
  // ... while lane-per-row softmax runs on wave 0
  if (tid < 64) {
    int t = tid;
    if (t < Nsq) {
      float m = -1e30f;
      for (int j = 0; j < NK; ++j) {
        bool ok = (j < NMEM) || (((j - NMEM) <= t) && (msk[j - NMEM] != 0));
        if (ok) m = fmaxf(m, Ss[t][j] * SCALE_C);
      }
      float sum = 0.0f;
      for (int j = 0; j < NK; ++j) {
        bool ok = (j < NMEM) || (((j - NMEM) <= t) && (msk[j - NMEM] != 0));
        if (ok) sum += __expf(Ss[t][j] * SCALE_C - m);
      }
      float inv = 1.0f / sum;
      for (int j = 0; j < 64; ++j) {
        float p = 0.0f;
        if (j < NK) {
          bool ok = (j < NMEM) || (((j - NMEM) <= t) && (msk[j - NMEM] != 0));
          if (ok) p = __expf(Ss[t][j] * SCALE_C - m) * inv;
        }
        Ps[t][j] = f2b(p);
      }
    } else {
      for (int j = 0; j < 64; ++j) Ps[t][j] = 0;
    }
  }
  __syncthreads();

  // ---- O = P V  (wave w: all 64 t-rows x h in [w*64, +64))
  {
    f32x4 o[4][4] = {};
#pragma unroll
    for (int kf = 0; kf < 2; ++kf) {
      bf16x8 pa[4];
#pragma unroll
      for (int mf = 0; mf < 4; ++mf)
        pa[mf] = *(const bf16x8*)&Ps[mf * 16 + l16][kf * 32 + quad * 8];
#pragma unroll
      for (int nf = 0; nf < 4; ++nf) {
        int h = wave * 64 + nf * 16 + l16;
        ushort e0 = KV[kf * 32 + quad * 8 + 0][h];
        ushort e1 = KV[kf * 32 + quad * 8 + 1][h];
        ushort e2 = KV[kf * 32 + quad * 8 + 2][h];
        ushort e3 = KV[kf * 32 + quad * 8 + 3][h];
        ushort e4 = KV[kf * 32 + quad * 8 + 4][h];
        ushort e5 = KV[kf * 32 + quad * 8 + 5][h];
        ushort e6 = KV[kf * 32 + quad * 8 + 6][h];
        ushort e7 = KV[kf * 32 + quad * 8 + 7][h];
        bf16x8 vb = {(short)e0, (short)e1, (short)e2, (short)e3,
                     (short)e4, (short)e5, (short)e6, (short)e7};
#pragma unroll
        for (int mf = 0; mf < 4; ++mf)
          o[mf][nf] = __builtin_amdgcn_mfma_f32_16x16x32_bf16(pa[mf], vb, o[mf][nf], 0, 0, 0);
      }
    }
#pragma unroll
    for (int mf = 0; mf < 4; ++mf) {
#pragma unroll
      for (int r = 0; r < 4; ++r) {
        int t = mf * 16 + quad * 4 + r;
        if (t < Nsq) {
          int zero = (msk[t] == 0);
#pragma unroll
          for (int nf = 0; nf < 4; ++nf) {
            int h = wave * 64 + nf * 16 + l16;
            float val = zero ? 0.0f : o[mf][nf][r];
            out[((size_t)(b * Nsq + t)) * 256 + h] = f2b(val);
          }
        }
      }
    }
  }
}

// ---------------------------------------------------------------- alpha + sess (→ sesscat)
// att = relu(att1p + att2p) computed inline (fused relu_add).
__global__ __launch_bounds__(256) void alpha_sess_kernel(const float* __restrict__ att1,
    const float* __restrict__ att2,
    const float* __restrict__ W3, const float* __restrict__ q11,
    const float* __restrict__ se1, const int* __restrict__ mask,
    const float* __restrict__ srl, float* __restrict__ sesscat) {
  int b = blockIdx.x, tid = threadIdx.x;
  __shared__ float red[256];
  __shared__ float ash[50];
  red[tid] = q11[b * Hd + tid] * W3[256 + tid];
  __syncthreads();
  for (int s = 128; s; s >>= 1) { if (tid < s) red[tid] += red[tid + s]; __syncthreads(); }
  float cq = red[0];
  float aval = 0.0f;
  if (tid < 50) {
    float s = cq;
    const float* a1 = att1 + ((size_t)b * Nsq + tid) * Hd;
    const float* a2 = att2 + ((size_t)b * Nsq + tid) * Hd;
    for (int hh = 0; hh < 256; ++hh) s += fmaxf(a1[hh] + a2[hh], 0.0f) * W3[hh];
    aval = mask[b * Nsq + tid] ? s : NEG_C;
  }
  if (tid < 64) {
    float s = (tid < 50) ? aval : NEG_C;
    float m = s;
    for (int off = 32; off; off >>= 1) m = fmaxf(m, __shfl_xor(m, off));
    float e = expf(s - m);
    float sum = e;
    for (int off = 32; off; off >>= 1) sum += __shfl_xor(sum, off);
    if (tid < 50) ash[tid] = e / sum;
  }
  __syncthreads();
  float acc = 0.0f;
  const float* se = se1 + (size_t)b * Nsq * Hd;
  for (int t = 0; t < Nsq; ++t) acc += ash[t] * se[t * 256 + tid];
  sesscat[(size_t)b * 512 + tid] = acc;
  sesscat[(size_t)b * 512 + 256 + tid] = srl[b * Hd + tid];
}

// ---------------------------------------------------------------- beta + boundary (fp32)
__global__ __launch_bounds__(256) void beta_kernel(const float* __restrict__ sess2,
    const float* __restrict__ Wt1, const float* __restrict__ bt1,
    const float* __restrict__ Wt2, float* __restrict__ beta, float* __restrict__ bnd) {
  int b = blockIdx.x, tid = threadIdx.x;
  __shared__ float xs[256];
  __shared__ float r0[256], r1[256];
  xs[tid] = sess2[b * Hd + tid];
  __syncthreads();
  float hsum = bt1[tid];
  for (int k = 0; k < 256; ++k) hsum += xs[k] * Wt1[k * 256 + tid];
  float hid = fmaxf(hsum, 0.0f);
  r0[tid] = hid * Wt2[tid * 2 + 0];
  r1[tid] = hid * Wt2[tid * 2 + 1];
  __syncthreads();
  for (int s = 128; s; s >>= 1) {
    if (tid < s) { r0[tid] += r0[tid + s]; r1[tid] += r1[tid + s]; }
    __syncthreads();
  }
  if (tid == 0) {
    float t0 = r0[0], t1 = r1[0];
    float m = fmaxf(t0, t1);
    float e0 = expf(t0 - m), e1 = expf(t1 - m);
    float bb0 = e0 / (e0 + e1), bb1 = e1 / (e0 + e1);
    beta[b * 2] = bb0; beta[b * 2 + 1] = bb1;
    atomicAdd(bnd, fabsf(bb0 - bb1) * (1.0f / 512.0f));
  }
}

// ---------------------------------------------------------------- fused score softmax + final
// One block (1024 thr) per row b. Flags packed once into a 5 KB LDS bitmask (pass 1);
// passes 2-3 never re-read flag. No intermediate stores: pass 2 only sums, pass 3
// recomputes the exp and writes fin directly. Score row (160 KB) stays L3-resident
// across passes. Each element contributes to exactly one side (exp(NEG-M) == 0).
__global__ __launch_bounds__(1024) void score_final_fused(float* __restrict__ score,
    const int* __restrict__ flag, const float* __restrict__ beta) {
  int b = blockIdx.x, tid = threadIdx.x;
  float4* sr = (float4*)(score + (size_t)b * VM1);
  const int4* fr = (const int4*)(flag + (size_t)b * VM1);
  constexpr int NV = VM1 / 4;        // 10000 int4/float4 groups
  constexpr int NW = (NV + 7) / 8;   // 1250 bitmask words (4 bits per group)

  __shared__ uint bits[NW];
  __shared__ float red[1024], red2[1024];

  for (int i = tid; i < NW; i += 1024) bits[i] = 0u;
  __syncthreads();

  // ---- pass 1: per-side maxes + flag bitmask
  float mi = -INFINITY, me = -INFINITY;
  for (int i = tid; i < NV; i += 1024) {
    float4 s = sr[i];
    int4 f = fr[i];
    uint nib = (f.x ? 1u : 0u) | (f.y ? 2u : 0u) | (f.z ? 4u : 0u) | (f.w ? 8u : 0u);
    if (nib) atomicOr(&bits[i >> 3], nib << ((i & 7) * 4));
    if (f.x) mi = fmaxf(mi, s.x); else me = fmaxf(me, s.x);
    if (f.y) mi = fmaxf(mi, s.y); else me = fmaxf(me, s.y);
    if (f.z) mi = fmaxf(mi, s.z); else me = fmaxf(me, s.z);
    if (f.w) mi = fmaxf(mi, s.w); else me = fmaxf(me, s.w);
  }
  red[tid] = mi; red2[tid] = me;
  __syncthreads();
  for (int s = 512; s; s >>= 1) {
    if (tid < s) { red[tid] = fmaxf(red[tid], red[tid + s]); red2[tid] = fmaxf(red2[tid], red2[tid + s]); }
    __syncthreads();
  }
  float Mi = red[0], Me = red2[0];
  __syncthreads();

  // ---- pass 2: per-side sums (no stores; score re-read from L3)
  float si = 0.0f, se = 0.0f;
  for (int i = tid; i < NV; i += 1024) {
    float4 s = sr[i];
    uint nib = bits[i >> 3] >> ((i & 7) * 4);
    float e0 = __expf(s.x - ((nib & 1u) ? Mi : Me));
    float e1 = __expf(s.y - ((nib & 2u) ? Mi : Me));
    float e2 = __expf(s.z - ((nib & 4u) ? Mi : Me));
    float e3 = __expf(s.w - ((nib & 8u) ? Mi : Me));
    si += ((nib & 1u) ? e0 : 0.0f) + ((nib & 2u) ? e1 : 0.0f)
        + ((nib & 4u) ? e2 : 0.0f) + ((nib & 8u) ? e3 : 0.0f);
    se += ((nib & 1u) ? 0.0f : e0) + ((nib & 2u) ? 0.0f : e1)
        + ((nib & 4u) ? 0.0f : e2) + ((nib & 8u) ? 0.0f : e3);
  }
  red[tid] = si; red2[tid] = se;
  __syncthreads();
  for (int s = 512; s; s >>= 1) {
    if (tid < s) { red[tid] += red[tid + s]; red2[tid] += red2[tid + s]; }
    __syncthreads();
  }
  float c0 = beta[b * 2] / red[0];
  float c1 = beta[b * 2 + 1] / red2[0];
  __syncthreads();

  // ---- pass 3: recompute exp, write fin in place
  for (int i = tid; i < NV; i += 1024) {
    float4 s = sr[i];
    uint nib = bits[i >> 3] >> ((i & 7) * 4);
    s.x = ((nib & 1u) ? c0 : c1) * __expf(s.x - ((nib & 1u) ? Mi : Me));
    s.y = ((nib & 2u) ? c0 : c1) * __expf(s.y - ((nib & 2u) ? Mi : Me));
    s.z = ((nib & 4u) ? c0 : c1) * __expf(s.z - ((nib & 4u) ? Mi : Me));
    s.w = ((nib & 8u) ? c0 : c1) * __expf(s.w - ((nib & 8u) ? Mi : Me));
    sr[i] = s;
  }
}

// ================================================================ launch
extern "C" void kernel_launch(void* const* d_in, const int* in_sizes, int n_in,
                              void* d_out, int out_size, void* d_ws, size_t ws_size,
                              hipStream_t stream) {
  const float* seq1  = (const float*)d_in[0];
  const float* seq2  = (const float*)d_in[1];
  const int*   mask  = (const int*)d_in[2];
  const int*   iflag = (const int*)d_in[3];
  const float* wih0  = (const float*)d_in[4];
  const float* whh0  = (const float*)d_in[5];
  const float* bih0  = (const float*)d_in[6];
  const float* bhh0  = (const float*)d_in[7];
  const float* wih1  = (const float*)d_in[8];
  const float* whh1  = (const float*)d_in[9];
  const float* bih1  = (const float*)d_in[10];
  const float* bhh1  = (const float*)d_in[11];
  const float* Wq1   = (const float*)d_in[12];
  const float* Wk1   = (const float*)d_in[13];
  const float* Wv1   = (const float*)d_in[14];
  const float* Wk2   = (const float*)d_in[16];
  const float* Wv2   = (const float*)d_in[17];
  const float* Wffn1 = (const float*)d_in[18];
  const float* bffn1 = (const float*)d_in[19];
  const float* Wffn2 = (const float*)d_in[20];
  const float* bffn2 = (const float*)d_in[21];
  const float* Wone  = (const float*)d_in[22];
  const float* bone  = (const float*)d_in[23];
  const float* W3    = (const float*)d_in[24];
  const float* Wtr   = (const float*)d_in[25];
  const float* btr   = (const float*)d_in[26];
  const float* Wt1   = (const float*)d_in[27];
  const float* bt1   = (const float*)d_in[28];
  const float* Wt2   = (const float*)d_in[29];
  const float* memk  = (const float*)d_in[30];
  const float* memv  = (const float*)d_in[31];
  const float* emb1  = (const float*)d_in[32];
  float* out = (float*)d_out;

  // Workspace layout (byte offsets, all 16B-aligned). Total ≈ 214.1 MB.
  char* wsb = (char*)d_ws;
  float*  TAB    = (float*)(wsb + 0);            // 51,200
  int*    lastp  = (int*)  (wsb + 51200);        // 2,048
  float*  srl    = (float*)(wsb + 53248);        // 524,288
  float*  q11    = (float*)(wsb + 577536);       // 524,288
  ushort* whh0b  = (ushort*)(wsb + 1101824);     // 393,216 (bf16 whh, layer 0)
  ushort* whh1b  = (ushort*)(wsb + 1888256);     // 393,216 (bf16 whh, layer 1)
  ushort* wih0b  = (ushort*)(wsb + 2674688);     // 393,216
  ushort* wih1b  = (ushort*)(wsb + 3067904);     // 393,216
  ushort* w7b    = (ushort*)(wsb + 3461120);     // 7 x 131,072
  ushort* bufS   = (ushort*)(wsb + 4378624);     // 13,107,200  seq2b -> ys1b -> se2b
  float*  se1    = (float*)(wsb + 17485824);     // 26,214,400
  ushort* se1b   = (ushort*)(wsb + 43700224);    // 13,107,200
  float*  giQ    = (float*)(wsb + 56807424);     // 78,643,200  gi -> q1|k1|v1 -> tail
  float*  kv2a   = (float*)(wsb + 135450624);    // 26,214,400  k2 -> att1p
  float*  kv2b   = (float*)(wsb + 161665024);    // 26,214,400  v2 -> att2p
  ushort* ao1b   = (ushort*)(wsb + 187879424);   // 13,107,200
  ushort* ao2b   = (ushort*)(wsb + 200986624);   // 13,107,200

  float* gi = giQ;
  float* q1 = giQ;
  float* k1 = giQ + 6553600;
  float* v1 = giQ + 13107200;
  // tail block (reuses giQ after attn2):
  ushort* embB    = (ushort*)giQ;                             // 20,480,000 B
  float*  sesscat = (float*)((char*)giQ + 20480000);          // 1,048,576
  float*  sess2   = (float*)((char*)giQ + 21528576);          // 524,288
  ushort* sess2b  = (ushort*)((char*)giQ + 22052864);         // 262,144
  float*  betab   = (float*)((char*)giQ + 22315008);          // 4,096
  float*  stats   = (float*)((char*)giQ + 22319104);          // 8,192
  float*  bnd     = out + (size_t)Bsz * VM1;                  // boundary output slot

  ushort* Wq1b = w7b;              ushort* Wk1b = w7b + 65536;
  ushort* Wv1b = w7b + 131072;     ushort* Wk2b = w7b + 196608;
  ushort* Wv2b = w7b + 262144;     ushort* Wf1b = w7b + 327680;
  ushort* Wf2b = w7b + 393216;

  // ---- table / last / q1_1 (fp32 path)
  build_tab<<<50, 256, 0, stream>>>(TAB);
  last_srl_kernel<<<Bsz, 256, 0, stream>>>(mask, seq1, lastp, srl);
  gemm_tile<0, 1><<<dim3(4, 4), 256, 0, stream>>>(srl, Wone, bone, q11, 512, 256, 256);
  add_tab0<<<512, 256, 0, stream>>>(q11);

  // ---- weight casts
  cast_f2b_k<<<6400, 256, 0, stream>>>(seq2, bufS, 1638400);
  cast_f2b_k<<<192, 256, 0, stream>>>(wih0, wih0b, 49152);
  cast_f2b_k<<<192, 256, 0, stream>>>(wih1, wih1b, 49152);
  cast_f2b_k<<<192, 256, 0, stream>>>(whh0, whh0b, 49152);
  cast_f2b_k<<<192, 256, 0, stream>>>(whh1, whh1b, 49152);
  Cast7 c7;
  c7.s[0] = Wq1; c7.s[1] = Wk1; c7.s[2] = Wv1; c7.s[3] = Wk2; c7.s[4] = Wv2;
  c7.s[5] = Wffn1; c7.s[6] = Wffn2;
  c7.d[0] = Wq1b; c7.d[1] = Wk1b; c7.d[2] = Wv1b; c7.d[3] = Wk2b; c7.d[4] = Wv2b;
  c7.d[5] = Wf1b; c7.d[6] = Wf2b;
  cast7_k<<<dim3(64, 7), 256, 0, stream>>>(c7);

  // ---- GRU (gi via MFMA, recurrence via 8-wave/2-sample MFMA kernel, 1 barrier/step)
  mfma_gemm<1, 1><<<dim3(6, 200), 256, 0, stream>>>(bufS, wih0b, bih0, gi, 25600, 768, 256);
  gru_mfma8_kernel<<<256, 512, 0, stream>>>(gi, whh0b, bhh0, bufS, nullptr);
  mfma_gemm<1, 1><<<dim3(6, 200), 256, 0, stream>>>(bufS, wih1b, bih1, gi, 25600, 768, 256);
  gru_mfma8_kernel<<<256, 512, 0, stream>>>(gi, whh1b, bhh1, bufS, mask);   // -> se2 bf16

  // ---- masked seq1 (fp32 + bf16)
  mask_mul_dual<<<25600, 256, 0, stream>>>(seq1, mask, se1, se1b);

  // ---- projections (MFMA); PE is added during attention staging (fused)
  mfma_gemm<0, 0><<<dim3(2, 200), 256, 0, stream>>>(bufS, Wk2b, nullptr, kv2a, 25600, 256, 256);
  mfma_gemm<0, 0><<<dim3(2, 200), 256, 0, stream>>>(bufS, Wv2b, nullptr, kv2b, 25600, 256, 256);
  mfma_gemm<0, 0><<<dim3(2, 200), 256, 0, stream>>>(se1b, Wq1b, nullptr, q1, 25600, 256, 256);
  mfma_gemm<0, 0><<<dim3(2, 200), 256, 0, stream>>>(se1b, Wk1b, nullptr, k1, 25600, 256, 256);
  mfma_gemm<0, 0><<<dim3(2, 200), 256, 0, stream>>>(se1b, Wv1b, nullptr, v1, 25600, 256, 256);

  // ---- attentions (MFMA, fp32 in, bf16 out; PE fused into staging)
  attn_mfma<0, 1, 1><<<Bsz, 256, 0, stream>>>(q1, k1, v1, nullptr, nullptr, mask, ao1b, TAB, lastp);
  attn_mfma<8, 1, 0><<<Bsz, 256, 0, stream>>>(q1, kv2a, kv2b, memk, memv, mask, ao2b, TAB, lastp);
  mfma_gemm<0, 1><<<dim3(2, 200), 256, 0, stream>>>(ao1b, Wf1b, bffn1, kv2a, 25600, 256, 256);
  mfma_gemm<0, 1><<<dim3(2, 200), 256, 0, stream>>>(ao2b, Wf2b, bffn2, kv2b, 25600, 256, 256);

  // ---- pooling + session (fp32; relu(att1p+att2p) fused into alpha)
  alpha_sess_kernel<<<Bsz, 256, 0, stream>>>(kv2a, kv2b, W3, q11, se1, mask, srl, sesscat);
  gemm_tile<0, 1><<<dim3(4, 4), 256, 0, stream>>>(sesscat, Wtr, btr, sess2, 512, 256, 512);
  cast_f2b_k<<<128, 256, 0, stream>>>(sess2, sess2b, 32768);

  // ---- tail gating (fp32) + scoring (MFMA) + fused softmax/final
  hipMemsetAsync(bnd, 0, 4, stream);
  beta_kernel<<<Bsz, 256, 0, stream>>>(sess2, Wt1, bt1, Wt2, betab, bnd);
  cast_f2b_k<<<10000, 256, 0, stream>>>(emb1 + 256, embB, 2560000);
  mfma_gemm<1, 0><<<dim3(313, 4), 256, 0, stream>>>(sess2b, embB, nullptr, out, 512, VM1, 256);
  score_final_fused<<<Bsz, 1024, 0, stream>>>(out, iflag, betab);

  (void)in_sizes; (void)n_in; (void)out_size; (void)ws_size;
}

// Round 10
// 898.161 us; speedup vs baseline: 1.2044x; 1.0157x over previous
//
#include <hip/hip_runtime.h>
#include <hip/hip_bf16.h>
#include <cstdint>
#include <cstddef>

// Problem dims
#define Bsz 512
#define Nsq 50
#define Hd  256
#define VM1 40000
static constexpr float SCALE_C = 0.0625f;   // 1/sqrt(256)
static constexpr float NEG_C   = -1.0e12f;

typedef __attribute__((ext_vector_type(8))) short bf16x8;
typedef __attribute__((ext_vector_type(4))) float f32x4;

__device__ __forceinline__ float sigmoidf_(float x) { return 1.0f / (1.0f + __expf(-x)); }
__device__ __forceinline__ float tanh_fast(float x) {
  float t = fminf(fmaxf(2.0f * x, -60.0f), 60.0f);
  float e = __expf(t);
  return (e - 1.0f) / (e + 1.0f);
}
__device__ __forceinline__ ushort f2b(float x) {   // fp32 -> bf16 (RNE)
  union { float f; uint32_t u; } c; c.f = x;
  uint32_t r = (c.u + 0x7fffu + ((c.u >> 16) & 1u)) >> 16;
  return (ushort)r;
}
__device__ __forceinline__ uint pk2f(float a, float b) {
  return (uint)f2b(a) | ((uint)f2b(b) << 16);
}
__device__ __forceinline__ uint addpe2(uint w, float pa, float pb) {
  // two packed bf16 + two fp32 PE values -> packed bf16
  union { float f; uint32_t u; } lo, hi;
  lo.u = (w & 0xffffu) << 16; hi.u = w & 0xffff0000u;
  return pk2f(lo.f + pa, hi.f + pb);
}

// ---------------------------------------------------------------- TAB (50x256)
__global__ void build_tab(float* __restrict__ TAB) {
  int idx = blockIdx.x * 256 + threadIdx.x;
  int pos = idx >> 8, j = idx & 255;
  int pair = j >> 1;
  float expo = (2.0f * (float)pair) / 256.0f;
  float inv = powf(10000.0f, -expo);
  float ang = (float)pos * inv;
  TAB[idx] = (j & 1) ? cosf(ang) : sinf(ang);
}

// ------------------------------------------------- last[b], sr_l_1 = seq1[b,last]
__global__ __launch_bounds__(256) void last_srl_kernel(const int* __restrict__ mask,
    const float* __restrict__ seq1, int* __restrict__ lastp, float* __restrict__ srl) {
  int b = blockIdx.x, tid = threadIdx.x;
  __shared__ int ls;
  if (tid == 0) {
    int c = 0;
    for (int t = 0; t < Nsq; ++t) c += mask[b * Nsq + t];
    ls = c - 1;
    lastp[b] = c - 1;
  }
  __syncthreads();
  srl[b * Hd + tid] = seq1[((size_t)b * Nsq + ls) * Hd + tid];
}

// ---------------------------------------------------------------- fp32 GEMM (small shapes only)
template <int BT, int BIAS>
__global__ __launch_bounds__(256) void gemm_tile(const float* __restrict__ A,
    const float* __restrict__ B, const float* __restrict__ bias,
    float* __restrict__ C, int M, int N, int K) {
  __shared__ float As[16][132];
  __shared__ float Bs[16][68];
  int bm = blockIdx.y * 128, bn = blockIdx.x * 64;
  int tid = threadIdx.x;
  int tm = (tid >> 4) << 3;
  int tn = (tid & 15) << 2;
  float acc[8][4] = {};
  for (int k0 = 0; k0 < K; k0 += 16) {
#pragma unroll
    for (int u = 0; u < 8; ++u) {
      int i = tid + u * 256;
      int kk = i & 15, m = i >> 4;
      As[kk][m] = A[(size_t)(bm + m) * K + (k0 + kk)];
    }
#pragma unroll
    for (int u = 0; u < 4; ++u) {
      int i = tid + u * 256;
      if (BT) {
        int kk = i & 15, n = i >> 4;
        Bs[kk][n] = B[(size_t)(bn + n) * K + (k0 + kk)];
      } else {
        int n = i & 63, kk = i >> 6;
        Bs[kk][n] = B[(size_t)(k0 + kk) * N + (bn + n)];
      }
    }
    __syncthreads();
#pragma unroll
    for (int kk = 0; kk < 16; ++kk) {
      float a[8], bb[4];
#pragma unroll
      for (int r = 0; r < 8; ++r) a[r] = As[kk][tm + r];
#pragma unroll
      for (int c = 0; c < 4; ++c) bb[c] = Bs[kk][tn + c];
#pragma unroll
      for (int r = 0; r < 8; ++r)
#pragma unroll
        for (int c = 0; c < 4; ++c) acc[r][c] += a[r] * bb[c];
    }
    __syncthreads();
  }
#pragma unroll
  for (int r = 0; r < 8; ++r) {
    size_t row = (size_t)(bm + tm + r) * N + bn;
#pragma unroll
    for (int c = 0; c < 4; ++c) {
      float v = acc[r][c];
      if (BIAS) v += bias[bn + tn + c];
      C[row + tn + c] = v;
    }
  }
}

// ---------------------------------------------------------------- bf16 MFMA GEMM
// C[M,N] = A_bf[M,K] @ (BT ? B_bf[N,K]^T : B_bf[K,N]) (+bias); OUTBF: store bf16.
// tile 128x128, BK=32, 256 threads = 4 waves (each 64x64 quadrant, 4x4 frags of 16x16x32).
// A staged via global_load_lds width=16 into linear [128][32] LDS (m97-proven pattern);
// BT=1 B likewise; BT=0 B keeps the padded transpose-stage (gload_lds can't transpose).
template <int BT, int BIAS, int OUTBF>
__global__ __launch_bounds__(256) void mfma_gemm(const ushort* __restrict__ A,
    const ushort* __restrict__ B, const float* __restrict__ bias,
    void* __restrict__ Cv, int M, int N, int K) {
  __shared__ ushort Asm[128 * 32];   // linear: Asm[r*32+c] = A[bm+r][k0+c]
  __shared__ ushort Bsm[128 * 40];   // BT=1: linear [r*32+c]; BT=0: padded [n*40+k]
  constexpr int SB = BT ? 32 : 40;
  int tid = threadIdx.x;
  int bm = blockIdx.y * 128, bn = blockIdx.x * 128;
  int lane = tid & 63, wave = tid >> 6;
  int quad = lane >> 4, l16 = lane & 15;
  int wm = (wave >> 1) * 64, wn = (wave & 1) * 64;

  // gload_lds chunk mapping: chunk chn = rows [chn*16,+16); lane l -> row chn*16+(l>>2),
  // col (l&3)*8; dest byte = chn*1024 + l*16  (wave-uniform base, HW adds lane*16).
  int chn0 = wave * 2, chn1 = wave * 2 + 1;
  int ra0 = chn0 * 16 + (lane >> 2), ra1 = chn1 * 16 + (lane >> 2);
  int kc = (lane & 3) * 8;
  const ushort* srcA0 = A + (size_t)(bm + ra0) * K + kc;
  const ushort* srcA1 = A + (size_t)(bm + ra1) * K + kc;
  char* dstA0 = (char*)Asm + chn0 * 1024;
  char* dstA1 = (char*)Asm + chn1 * 1024;
  const ushort* srcB0 = nullptr;
  const ushort* srcB1 = nullptr;
  if (BT) {
    int rb0 = bn + ra0; if (rb0 > N - 1) rb0 = N - 1;   // clamp: cols >= N never stored
    int rb1 = bn + ra1; if (rb1 > N - 1) rb1 = N - 1;
    srcB0 = B + (size_t)rb0 * K + kc;
    srcB1 = B + (size_t)rb1 * K + kc;
  }
  char* dstB0 = (char*)Bsm + chn0 * 1024;
  char* dstB1 = (char*)Bsm + chn1 * 1024;

  f32x4 acc[4][4] = {};
  for (int k0 = 0; k0 < K; k0 += 32) {
    __builtin_amdgcn_global_load_lds(
        (const __attribute__((address_space(1))) void*)(srcA0 + k0),
        (__attribute__((address_space(3))) void*)dstA0, 16, 0, 0);
    __builtin_amdgcn_global_load_lds(
        (const __attribute__((address_space(1))) void*)(srcA1 + k0),
        (__attribute__((address_space(3))) void*)dstA1, 16, 0, 0);
    if (BT) {
      __builtin_amdgcn_global_load_lds(
          (const __attribute__((address_space(1))) void*)(srcB0 + k0),
          (__attribute__((address_space(3))) void*)dstB0, 16, 0, 0);
      __builtin_amdgcn_global_load_lds(
          (const __attribute__((address_space(1))) void*)(srcB1 + k0),
          (__attribute__((address_space(3))) void*)dstB1, 16, 0, 0);
    } else {
#pragma unroll
      for (int u = 0; u < 8; ++u) {             // transpose-stage: 2 n per thread
        int idx = tid + u * 256;
        int n2 = (idx & 63) * 2, kk = idx >> 6;
        uint v = *(const uint*)(B + (size_t)(k0 + kk) * N + bn + n2);
        Bsm[n2 * 40 + kk] = (ushort)(v & 0xffffu);
        Bsm[(n2 + 1) * 40 + kk] = (ushort)(v >> 16);
      }
    }
    __syncthreads();                            // drains vmcnt (gload_lds) + lgkm
    bf16x8 af[4], bfr[4];
#pragma unroll
    for (int f = 0; f < 4; ++f) af[f] = *(const bf16x8*)(Asm + (wm + f * 16 + l16) * 32 + quad * 8);
#pragma unroll
    for (int f = 0; f < 4; ++f) bfr[f] = *(const bf16x8*)(Bsm + (wn + f * 16 + l16) * SB + quad * 8);
#pragma unroll
    for (int mf = 0; mf < 4; ++mf)
#pragma unroll
      for (int nf = 0; nf < 4; ++nf)
        acc[mf][nf] = __builtin_amdgcn_mfma_f32_16x16x32_bf16(af[mf], bfr[nf], acc[mf][nf], 0, 0, 0);
    __syncthreads();
  }
#pragma unroll
  for (int mf = 0; mf < 4; ++mf) {
#pragma unroll
    for (int r = 0; r < 4; ++r) {
      int row = bm + wm + mf * 16 + quad * 4 + r;
      size_t rowo = (size_t)row * N;
#pragma unroll
      for (int nf = 0; nf < 4; ++nf) {
        int col = bn + wn + nf * 16 + l16;
        if (col < N) {
          float v = acc[mf][nf][r];
          if (BIAS) v += bias[col];
          if (OUTBF) ((ushort*)Cv)[rowo + col] = f2b(v);
          else       ((float*)Cv)[rowo + col] = v;
        }
      }
    }
  }
}

// ---------------------------------------------------------------- casts
__global__ void cast_f2b_k(const float* __restrict__ s, ushort* __restrict__ d, int n4) {
  int i = blockIdx.x * 256 + threadIdx.x;
  if (i >= n4) return;
  const float4 v = ((const float4*)s)[i];
  ushort4 o; o.x = f2b(v.x); o.y = f2b(v.y); o.z = f2b(v.z); o.w = f2b(v.w);
  ((ushort4*)d)[i] = o;
}

struct Cast7 { const float* s[7]; ushort* d[7]; };
__global__ void cast7_k(Cast7 p) {
  int m = blockIdx.y;
  int i = blockIdx.x * 256 + threadIdx.x;
  const float4 v = ((const float4*)p.s[m])[i];
  ushort4 o; o.x = f2b(v.x); o.y = f2b(v.y); o.z = f2b(v.z); o.w = f2b(v.w);
  ((ushort4*)p.d[m])[i] = o;
}

// ---------------------------------------------------------------- misc elementwise
__global__ void add_tab0(float* __restrict__ q) {
  int idx = blockIdx.x * 256 + threadIdx.x;
  q[idx] += (float)(threadIdx.x & 1);         // TAB[0]: sin(0)=0, cos(0)=1
}

__global__ void mask_cast(const float* __restrict__ x, const int* __restrict__ m,
                          ushort* __restrict__ yb) {
  int idx = blockIdx.x * 256 + threadIdx.x;
  float v = m[idx >> 8] ? x[idx] : 0.0f;
  yb[idx] = f2b(v);
}

// ---------------------------------------------------------------- GRU layer (MFMA, reg-resident weights)
// 256 blocks x 8 waves (512 thr), 2 samples/block. ONE barrier per timestep:
// wave w computes ALL THREE gates for dims [w*32, w*32+32) (whh rows {d, 256+d, 512+d}),
// so its own MFMA output feeds its own 64 lanes' elementwise (2 samples x 32 dims).
// gh handoff via wave-private LDS scratch (same-wave DS ops are in-order -> no barrier).
// hbf double-buffered (write next, read cur) -> no WAR across the single barrier.
__global__ __launch_bounds__(512, 2) void gru_mfma8_kernel(const float* __restrict__ gi,
    const ushort* __restrict__ whhb, const float* __restrict__ bhh,
    ushort* __restrict__ ysb, const int* __restrict__ mask) {
  __shared__ ushort hbf[2][16][264];   // bf16 h, double-buffered (+8 pad)
  __shared__ float  gsc[8][2][3][32];  // per-wave gate scratch [wave][sample][gate][dim]
  int tid = threadIdx.x;
  int lane = tid & 63, wave = tid >> 6;
  int quad = lane >> 4, l16 = lane & 15;
  int s0 = blockIdx.x * 2;

  for (int i = tid; i < 2 * 16 * 264 / 2; i += 512) ((uint*)hbf)[i] = 0u;

  // reg-resident whh slice: wave w, frag nf: rows (nf>>1)*256 + w*32 + (nf&1)*16 + l16
  // (B-frag lane l16 = output row n, quad*8+j = k; same layout as proven mfma_gemm B-read)
  bf16x8 bw[48];
#pragma unroll
  for (int f = 0; f < 48; ++f) {
    int nf = f >> 3, kf = f & 7;
    int row = (nf >> 1) * 256 + wave * 32 + (nf & 1) * 16 + l16;
    bw[f] = *(const bf16x8*)(whhb + (size_t)row * 256 + kf * 32 + quad * 8);
  }

  // elementwise mapping: lane handles sample s = lane>>5, dim d = wave*32 + (lane&31)
  int s = lane >> 5, dloc = lane & 31;
  int d = wave * 32 + dloc;
  float bh0 = bhh[d], bh1 = bhh[256 + d], bh2 = bhh[512 + d];
  const float* gib = gi + (size_t)(s0 + s) * Nsq * 768 + d;
  float g0 = gib[0], g1 = gib[256], g2 = gib[512];
  float hreg = 0.0f;
  const int* mrow = mask + (s0 + s) * Nsq;   // only dereferenced if mask != null
  ushort* yrow = ysb + ((size_t)(s0 + s) * Nsq) * 256 + d;
  __syncthreads();

  int cur = 0;
  for (int t = 0; t < Nsq; ++t) {
    int tn = (t + 1 < Nsq) ? t + 1 : t;
    float p0 = gib[tn * 768], p1 = gib[tn * 768 + 256], p2 = gib[tn * 768 + 512];

    // ---- gh = h @ whh_slice^T  (A rows = samples; only rows 0..1 nonzero)
    f32x4 acc[6] = {};
#pragma unroll
    for (int kf = 0; kf < 8; ++kf) {
      bf16x8 a = *(const bf16x8*)&hbf[cur][l16][kf * 32 + quad * 8];
#pragma unroll
      for (int nf = 0; nf < 6; ++nf)
        acc[nf] = __builtin_amdgcn_mfma_f32_16x16x32_bf16(a, bw[nf * 8 + kf], acc[nf], 0, 0, 0);
    }
    // C layout: col = l16, row = quad*4 + reg = sample (rows 0,1 valid -> quad 0)
    if (quad == 0) {
#pragma unroll
      for (int g = 0; g < 3; ++g)
#pragma unroll
        for (int j = 0; j < 2; ++j) {
          gsc[wave][0][g][j * 16 + l16] = acc[g * 2 + j][0];
          gsc[wave][1][g][j * 16 + l16] = acc[g * 2 + j][1];
        }
    }
    __builtin_amdgcn_sched_barrier(0);   // pin gsc writes before reads (same-wave RAW)

    // ---- elementwise, fully in-wave (no block barrier needed for gh)
    {
      float ghr = gsc[wave][s][0][dloc];
      float ghz = gsc[wave][s][1][dloc];
      float ghn = gsc[wave][s][2][dloc];
      float rr = sigmoidf_(g0 + ghr + bh0);
      float zz = sigmoidf_(g1 + ghz + bh1);
      float nn = tanh_fast(g2 + rr * (ghn + bh2));
      float h2 = (1.0f - zz) * nn + zz * hreg;
      hreg = h2;
      hbf[cur ^ 1][s][d] = f2b(h2);
      float ov = h2;
      if (mask) ov = mrow[t] ? h2 : 0.0f;
      yrow[t * 256] = f2b(ov);
    }
    g0 = p0; g1 = p1; g2 = p2;
    cur ^= 1;
    __syncthreads();   // hbf[next] visible to all waves for step t+1
  }
}

// ---------------------------------------------------------------- MFMA attention
// One block per batch sample, 256 threads = 4 waves.
// q/kseq/vseq are bf16 [.,256]; kmem/vmem fp32. S = Q K^T via MFMA; masked softmax; O = P V.
// NMEM = 0 (attn1) or 8 (attn2: mem rows prepended). Output bf16, mask-zeroed.
// PEQ/PEKV: add PE table TAB[abs(t-last[b])*256+c] (fp32) while staging (fused add_pe3).
template <int NMEM, int PEQ, int PEKV>
__global__ __launch_bounds__(256) void attn_mfma(const ushort* __restrict__ q1,
    const ushort* __restrict__ kseq, const ushort* __restrict__ vseq,
    const float* __restrict__ kmem, const float* __restrict__ vmem,
    const int* __restrict__ mask, ushort* __restrict__ out,
    const float* __restrict__ TAB, const int* __restrict__ lastp) {
  constexpr int NK = NMEM + Nsq;            // valid K/V rows (50 or 58)
  __shared__ ushort KV[64][264];            // Q -> K -> V staging (bf16)
  __shared__ float Ss[64][66];              // scores fp32
  __shared__ ushort Ps[64][72];             // probabilities bf16
  __shared__ int msk[64];
  int tid = threadIdx.x;
  int lane = tid & 63, wave = tid >> 6;
  int quad = lane >> 4, l16 = lane & 15;
  int b = blockIdx.x;
  int last = lastp[b];

  if (tid < 64) msk[tid] = (tid < Nsq) ? mask[b * Nsq + tid] : 0;

  // ---- stage Q (rows t<50, else 0); bf16 src, PE added in fp32
#pragma unroll
  for (int it = 0; it < 8; ++it) {
    int idx = tid + it * 256;
    int r = idx >> 5, c8 = (idx & 31) * 8;
    uint4 o4 = make_uint4(0u, 0u, 0u, 0u);
    if (r < Nsq) {
      uint4 v = *(const uint4*)(q1 + (size_t)(b * Nsq + r) * 256 + c8);
      if (PEQ) {
        const float* pe = TAB + abs(r - last) * 256 + c8;
        float4 pa = *(const float4*)pe;
        float4 pb = *(const float4*)(pe + 4);
        o4.x = addpe2(v.x, pa.x, pa.y);
        o4.y = addpe2(v.y, pa.z, pa.w);
        o4.z = addpe2(v.z, pb.x, pb.y);
        o4.w = addpe2(v.w, pb.z, pb.w);
      } else {
        o4 = v;
      }
    }
    *(uint4*)&KV[r][c8] = o4;
  }
  __syncthreads();
  // Q A-frags: wave w owns t rows [w*16, w*16+16)
  bf16x8 qa[8];
#pragma unroll
  for (int kf = 0; kf < 8; ++kf)
    qa[kf] = *(const bf16x8*)&KV[wave * 16 + l16][kf * 32 + quad * 8];
  __syncthreads();

  // ---- stage K (rows: [0,NMEM) mem fp32, [NMEM,NK) seq bf16, else 0); PE on seq rows
#pragma unroll
  for (int it = 0; it < 8; ++it) {
    int idx = tid + it * 256;
    int r = idx >> 5, c8 = (idx & 31) * 8;
    uint4 o4 = make_uint4(0u, 0u, 0u, 0u);
    if (r < NK) {
      if (NMEM > 0 && r < NMEM) {
        const float* src = kmem + (size_t)r * 256 + c8;
        float4 a = *(const float4*)src;
        float4 c = *(const float4*)(src + 4);
        o4.x = pk2f(a.x, a.y); o4.y = pk2f(a.z, a.w);
        o4.z = pk2f(c.x, c.y); o4.w = pk2f(c.z, c.w);
      } else {
        uint4 v = *(const uint4*)(kseq + (size_t)(b * Nsq + (r - NMEM)) * 256 + c8);
        if (PEKV) {
          const float* pe = TAB + abs((r - NMEM) - last) * 256 + c8;
          float4 pa = *(const float4*)pe;
          float4 pb = *(const float4*)(pe + 4);
          o4.x = addpe2(v.x, pa.x, pa.y);
          o4.y = addpe2(v.y, pa.z, pa.w);
          o4.z = addpe2(v.z, pb.x, pb.y);
          o4.w = addpe2(v.w, pb.z, pb.w);
        } else {
          o4 = v;
        }
      }
    }
    *(uint4*)&KV[r][c8] = o4;
  }
  __syncthreads();

  // ---- S = Q K^T  (wave w: rows [w*16, +16) x all 64 cols)
  {
    f32x4 acc[4] = {};
#pragma unroll
    for (int kf = 0; kf < 8; ++kf) {
#pragma unroll
      for (int nf = 0; nf < 4; ++nf) {
        bf16x8 bf = *(const bf16x8*)&KV[nf * 16 + l16][kf * 32 + quad * 8];
        acc[nf] = __builtin_amdgcn_mfma_f32_16x16x32_bf16(qa[kf], bf, acc[nf], 0, 0, 0);
      }
    }
#pragma unroll
    for (int nf = 0; nf < 4; ++nf)
#pragma unroll
      for (int r = 0; r < 4; ++r)
        Ss[wave * 16 + quad * 4 + r][nf * 16 + l16] = acc[nf][r];
  }
  __syncthreads();

  // ---- stage V over K region (all threads) ...
#pragma unroll
  for (int it = 0; it < 8; ++it) {
    int idx = tid + it * 256;
    int r = idx >> 5, c8 = (idx & 31) * 8;
    uint4 o4 = make_uint4(0u, 0u, 0u, 0u);
    if (r < NK) {
      if (NMEM > 0 && r < NMEM) {
        const float* src = vmem + (size_t)r * 256 + c8;
        float4 a = *(const float4*)src;
        float4 c = *(const float4*)(src + 4);
        o4.x = pk2f(a.x, a.y); o4.y = pk2f(a.z, a.w);
        o4.z = pk2f(c.x, c.y); o4.w = pk2f(c.z, c.w);
      } else {
        uint4 v = *(const uint4*)(vseq + (size_t)(b * Nsq + (r - NMEM)) * 256 + c8);
        if (PEKV) {
          const float* pe = TAB + abs((r - NMEM) - last) * 256 + c8;
          float4 pa = *(const float4*)pe;
          float4 pb = *(const float4*)(pe + 4);
          o4.x = addpe2(v.x, pa.x, pa.y);
          o4.y = addpe2(v.y, pa.z, pa.w);
          o4.z = addpe2(v.z, pb.x, pb.y);
          o4.w = addpe2(v.w, pb.z, pb.w);
        } else {
          o4 = v;
        }
      }
    }
    *(uint4*)&KV[r][c8] = o4;
  }
  // ... while lane-per-row softmax runs on wave 0
  if (tid < 64) {
    int t = tid;
    if (t < Nsq) {
      float m = -1e30f;
      for (int j = 0; j < NK; ++j) {
        bool ok = (j < NMEM) || (((j - NMEM) <= t) && (msk[j - NMEM] != 0));
        if (ok) m = fmaxf(m, Ss[t][j] * SCALE_C);
      }
      float sum = 0.0f;
      for (int j = 0; j < NK; ++j) {
        bool ok = (j < NMEM) || (((j - NMEM) <= t) && (msk[j - NMEM] != 0));
        if (ok) sum += __expf(Ss[t][j] * SCALE_C - m);
      }
      float inv = 1.0f / sum;
      for (int j = 0; j < 64; ++j) {
        float p = 0.0f;
        if (j < NK) {
          bool ok = (j < NMEM) || (((j - NMEM) <= t) && (msk[j - NMEM] != 0));
          if (ok) p = __expf(Ss[t][j] * SCALE_C - m) * inv;
        }
        Ps[t][j] = f2b(p);
      }
    } else {
      for (int j = 0; j < 64; ++j) Ps[t][j] = 0;
    }
  }
  __syncthreads();

  // ---- O = P V  (wave w: all 64 t-rows x h in [w*64, +64))
  {
    f32x4 o[4][4] = {};
#pragma unroll
    for (int kf = 0; kf < 2; ++kf) {
      bf16x8 pa[4];
#pragma unroll
      for (int mf = 0; mf < 4; ++mf)
        pa[mf] = *(const bf16x8*)&Ps[mf * 16 + l16][kf * 32 + quad * 8];
#pragma unroll
      for (int nf = 0; nf < 4; ++nf) {
        int h = wave * 64 + nf * 16 + l16;
        ushort e0 = KV[kf * 32 + quad * 8 + 0][h];
        ushort e1 = KV[kf * 32 + quad * 8 + 1][h];
        ushort e2 = KV[kf * 32 + quad * 8 + 2][h];
        ushort e3 = KV[kf * 32 + quad * 8 + 3][h];
        ushort e4 = KV[kf * 32 + quad * 8 + 4][h];
        ushort e5 = KV[kf * 32 + quad * 8 + 5][h];
        ushort e6 = KV[kf * 32 + quad * 8 + 6][h];
        ushort e7 = KV[kf * 32 + quad * 8 + 7][h];
        bf16x8 vb = {(short)e0, (short)e1, (short)e2, (short)e3,
                     (short)e4, (short)e5, (short)e6, (short)e7};
#pragma unroll
        for (int mf = 0; mf < 4; ++mf)
          o[mf][nf] = __builtin_amdgcn_mfma_f32_16x16x32_bf16(pa[mf], vb, o[mf][nf], 0, 0, 0);
      }
    }
#pragma unroll
    for (int mf = 0; mf < 4; ++mf) {
#pragma unroll
      for (int r = 0; r < 4; ++r) {
        int t = mf * 16 + quad * 4 + r;
        if (t < Nsq) {
          int zero = (msk[t] == 0);
#pragma unroll
          for (int nf = 0; nf < 4; ++nf) {
            int h = wave * 64 + nf * 16 + l16;
            float val = zero ? 0.0f : o[mf][nf][r];
            out[((size_t)(b * Nsq + t)) * 256 + h] = f2b(val);
          }
        }
      }
    }
  }
}

// ---------------------------------------------------------------- alpha + sess (→ sesscat)
// att = relu(att1p + att2p) computed inline (fused relu_add).
// se1 = seq1 masked; masked rows contribute exactly 0 via ash (exp underflow) -> read seq1 raw.
__global__ __launch_bounds__(256) void alpha_sess_kernel(const float* __restrict__ att1,
    const float* __restrict__ att2,
    const float* __restrict__ W3, const float* __restrict__ q11,
    const float* __restrict__ seq1, const int* __restrict__ mask,
    const float* __restrict__ srl, float* __restrict__ sesscat) {
  int b = blockIdx.x, tid = threadIdx.x;
  __shared__ float red[256];
  __shared__ float ash[50];
  red[tid] = q11[b * Hd + tid] * W3[256 + tid];
  __syncthreads();
  for (int s = 128; s; s >>= 1) { if (tid < s) red[tid] += red[tid + s]; __syncthreads(); }
  float cq = red[0];
  float aval = 0.0f;
  if (tid < 50) {
    float s = cq;
    const float* a1 = att1 + ((size_t)b * Nsq + tid) * Hd;
    const float* a2 = att2 + ((size_t)b * Nsq + tid) * Hd;
    for (int hh = 0; hh < 256; ++hh) s += fmaxf(a1[hh] + a2[hh], 0.0f) * W3[hh];
    aval = mask[b * Nsq + tid] ? s : NEG_C;
  }
  if (tid < 64) {
    float s = (tid < 50) ? aval : NEG_C;
    float m = s;
    for (int off = 32; off; off >>= 1) m = fmaxf(m, __shfl_xor(m, off));
    float e = expf(s - m);
    float sum = e;
    for (int off = 32; off; off >>= 1) sum += __shfl_xor(sum, off);
    if (tid < 50) ash[tid] = e / sum;
  }
  __syncthreads();
  float acc = 0.0f;
  const float* se = seq1 + (size_t)b * Nsq * Hd;
  for (int t = 0; t < Nsq; ++t) acc += ash[t] * se[t * 256 + tid];
  sesscat[(size_t)b * 512 + tid] = acc;
  sesscat[(size_t)b * 512 + 256 + tid] = srl[b * Hd + tid];
}

// ---------------------------------------------------------------- beta + boundary (fp32)
__global__ __launch_bounds__(256) void beta_kernel(const float* __restrict__ sess2,
    const float* __restrict__ Wt1, const float* __restrict__ bt1,
    const float* __restrict__ Wt2, float* __restrict__ beta, float* __restrict__ bnd) {
  int b = blockIdx.x, tid = threadIdx.x;
  __shared__ float xs[256];
  __shared__ float r0[256], r1[256];
  xs[tid] = sess2[b * Hd + tid];
  __syncthreads();
  float hsum = bt1[tid];
  for (int k = 0; k < 256; ++k) hsum += xs[k] * Wt1[k * 256 + tid];
  float hid = fmaxf(hsum, 0.0f);
  r0[tid] = hid * Wt2[tid * 2 + 0];
  r1[tid] = hid * Wt2[tid * 2 + 1];
  __syncthreads();
  for (int s = 128; s; s >>= 1) {
    if (tid < s) { r0[tid] += r0[tid + s]; r1[tid] += r1[tid + s]; }
    __syncthreads();
  }
  if (tid == 0) {
    float t0 = r0[0], t1 = r1[0];
    float m = fmaxf(t0, t1);
    float e0 = expf(t0 - m), e1 = expf(t1 - m);
    float bb0 = e0 / (e0 + e1), bb1 = e1 / (e0 + e1);
    beta[b * 2] = bb0; beta[b * 2 + 1] = bb1;
    atomicAdd(bnd, fabsf(bb0 - bb1) * (1.0f / 512.0f));
  }
}

// ---------------------------------------------------------------- fused score softmax + final
// One block (1024 thr) per row b. Flags packed once into a 5 KB LDS bitmask (pass 1);
// passes 2-3 never re-read flag. No intermediate stores: pass 2 only sums, pass 3
// recomputes the exp and writes fin directly. Score row (160 KB) stays L3-resident
// across passes. Each element contributes to exactly one side (exp(NEG-M) == 0).
__global__ __launch_bounds__(1024) void score_final_fused(float* __restrict__ score,
    const int* __restrict__ flag, const float* __restrict__ beta) {
  int b = blockIdx.x, tid = threadIdx.x;
  float4* sr = (float4*)(score + (size_t)b * VM1);
  const int4* fr = (const int4*)(flag + (size_t)b * VM1);
  constexpr int NV = VM1 / 4;        // 10000 int4/float4 groups
  constexpr int NW = (NV + 7) / 8;   // 1250 bitmask words (4 bits per group)

  __shared__ uint bits[NW];
  __shared__ float red[1024], red2[1024];

  for (int i = tid; i < NW; i += 1024) bits[i] = 0u;
  __syncthreads();

  // ---- pass 1: per-side maxes + flag bitmask
  float mi = -INFINITY, me = -INFINITY;
  for (int i = tid; i < NV; i += 1024) {
    float4 s = sr[i];
    int4 f = fr[i];
    uint nib = (f.x ? 1u : 0u) | (f.y ? 2u : 0u) | (f.z ? 4u : 0u) | (f.w ? 8u : 0u);
    if (nib) atomicOr(&bits[i >> 3], nib << ((i & 7) * 4));
    if (f.x) mi = fmaxf(mi, s.x); else me = fmaxf(me, s.x);
    if (f.y) mi = fmaxf(mi, s.y); else me = fmaxf(me, s.y);
    if (f.z) mi = fmaxf(mi, s.z); else me = fmaxf(me, s.z);
    if (f.w) mi = fmaxf(mi, s.w); else me = fmaxf(me, s.w);
  }
  red[tid] = mi; red2[tid] = me;
  __syncthreads();
  for (int s = 512; s; s >>= 1) {
    if (tid < s) { red[tid] = fmaxf(red[tid], red[tid + s]); red2[tid] = fmaxf(red2[tid], red2[tid + s]); }
    __syncthreads();
  }
  float Mi = red[0], Me = red2[0];
  __syncthreads();

  // ---- pass 2: per-side sums (no stores; score re-read from L3)
  float si = 0.0f, se = 0.0f;
  for (int i = tid; i < NV; i += 1024) {
    float4 s = sr[i];
    uint nib = bits[i >> 3] >> ((i & 7) * 4);
    float e0 = __expf(s.x - ((nib & 1u) ? Mi : Me));
    float e1 = __expf(s.y - ((nib & 2u) ? Mi : Me));
    float e2 = __expf(s.z - ((nib & 4u) ? Mi : Me));
    float e3 = __expf(s.w - ((nib & 8u) ? Mi : Me));
    si += ((nib & 1u) ? e0 : 0.0f) + ((nib & 2u) ? e1 : 0.0f)
        + ((nib & 4u) ? e2 : 0.0f) + ((nib & 8u) ? e3 : 0.0f);
    se += ((nib & 1u) ? 0.0f : e0) + ((nib & 2u) ? 0.0f : e1)
        + ((nib & 4u) ? 0.0f : e2) + ((nib & 8u) ? 0.0f : e3);
  }
  red[tid] = si; red2[tid] = se;
  __syncthreads();
  for (int s = 512; s; s >>= 1) {
    if (tid < s) { red[tid] += red[tid + s]; red2[tid] += red2[tid + s]; }
    __syncthreads();
  }
  float c0 = beta[b * 2] / red[0];
  float c1 = beta[b * 2 + 1] / red2[0];
  __syncthreads();

  // ---- pass 3: recompute exp, write fin in place
  for (int i = tid; i < NV; i += 1024) {
    float4 s = sr[i];
    uint nib = bits[i >> 3] >> ((i & 7) * 4);
    s.x = ((nib & 1u) ? c0 : c1) * __expf(s.x - ((nib & 1u) ? Mi : Me));
    s.y = ((nib & 2u) ? c0 : c1) * __expf(s.y - ((nib & 2u) ? Mi : Me));
    s.z = ((nib & 4u) ? c0 : c1) * __expf(s.z - ((nib & 4u) ? Mi : Me));
    s.w = ((nib & 8u) ? c0 : c1) * __expf(s.w - ((nib & 8u) ? Mi : Me));
    sr[i] = s;
  }
}

// ================================================================ launch
extern "C" void kernel_launch(void* const* d_in, const int* in_sizes, int n_in,
                              void* d_out, int out_size, void* d_ws, size_t ws_size,
                              hipStream_t stream) {
  const float* seq1  = (const float*)d_in[0];
  const float* seq2  = (const float*)d_in[1];
  const int*   mask  = (const int*)d_in[2];
  const int*   iflag = (const int*)d_in[3];
  const float* wih0  = (const float*)d_in[4];
  const float* whh0  = (const float*)d_in[5];
  const float* bih0  = (const float*)d_in[6];
  const float* bhh0  = (const float*)d_in[7];
  const float* wih1  = (const float*)d_in[8];
  const float* whh1  = (const float*)d_in[9];
  const float* bih1  = (const float*)d_in[10];
  const float* bhh1  = (const float*)d_in[11];
  const float* Wq1   = (const float*)d_in[12];
  const float* Wk1   = (const float*)d_in[13];
  const float* Wv1   = (const float*)d_in[14];
  const float* Wk2   = (const float*)d_in[16];
  const float* Wv2   = (const float*)d_in[17];
  const float* Wffn1 = (const float*)d_in[18];
  const float* bffn1 = (const float*)d_in[19];
  const float* Wffn2 = (const float*)d_in[20];
  const float* bffn2 = (const float*)d_in[21];
  const float* Wone  = (const float*)d_in[22];
  const float* bone  = (const float*)d_in[23];
  const float* W3    = (const float*)d_in[24];
  const float* Wtr   = (const float*)d_in[25];
  const float* btr   = (const float*)d_in[26];
  const float* Wt1   = (const float*)d_in[27];
  const float* bt1   = (const float*)d_in[28];
  const float* Wt2   = (const float*)d_in[29];
  const float* memk  = (const float*)d_in[30];
  const float* memv  = (const float*)d_in[31];
  const float* emb1  = (const float*)d_in[32];
  float* out = (float*)d_out;

  // Workspace layout (byte offsets, all 16B-aligned). Total ≈ 214.1 MB.
  char* wsb = (char*)d_ws;
  float*  TAB    = (float*)(wsb + 0);            // 51,200
  int*    lastp  = (int*)  (wsb + 51200);        // 2,048
  float*  srl    = (float*)(wsb + 53248);        // 524,288
  float*  q11    = (float*)(wsb + 577536);       // 524,288
  ushort* whh0b  = (ushort*)(wsb + 1101824);     // 393,216 (bf16 whh, layer 0)
  ushort* whh1b  = (ushort*)(wsb + 1888256);     // 393,216 (bf16 whh, layer 1)
  ushort* wih0b  = (ushort*)(wsb + 2674688);     // 393,216
  ushort* wih1b  = (ushort*)(wsb + 3067904);     // 393,216
  ushort* w7b    = (ushort*)(wsb + 3461120);     // 7 x 131,072
  ushort* bufS   = (ushort*)(wsb + 4378624);     // 13,107,200  seq2b -> ys1b -> se2b
  float*  se1    = (float*)(wsb + 17485824);     // (unused now)
  ushort* se1b   = (ushort*)(wsb + 43700224);    // 13,107,200
  float*  giQ    = (float*)(wsb + 56807424);     // 78,643,200  gi -> q1b|k1b|v1b -> tail
  float*  kv2a   = (float*)(wsb + 135450624);    // 26,214,400  k2b|v2b -> att1p
  float*  kv2b   = (float*)(wsb + 161665024);    // 26,214,400  att2p
  ushort* ao1b   = (ushort*)(wsb + 187879424);   // 13,107,200
  ushort* ao2b   = (ushort*)(wsb + 200986624);   // 13,107,200

  float* gi = giQ;
  // bf16 projection outputs (giQ region, dead-after-GRU):
  ushort* q1b = (ushort*)giQ;                    // 13,107,200 B
  ushort* k1b = q1b + 6553600;                   // 13,107,200 B
  ushort* v1b = q1b + 13107200;                  // 13,107,200 B
  ushort* k2b = (ushort*)kv2a;                   // 13,107,200 B (dead before FFN1 writes kv2a)
  ushort* v2b = k2b + 6553600;                   // 13,107,200 B
  // tail block (reuses giQ after attn2):
  ushort* embB    = (ushort*)giQ;                             // 20,480,000 B
  float*  sesscat = (float*)((char*)giQ + 20480000);          // 1,048,576
  float*  sess2   = (float*)((char*)giQ + 21528576);          // 524,288
  ushort* sess2b  = (ushort*)((char*)giQ + 22052864);         // 262,144
  float*  betab   = (float*)((char*)giQ + 22315008);          // 4,096
  float*  bnd     = out + (size_t)Bsz * VM1;                  // boundary output slot

  ushort* Wq1b = w7b;              ushort* Wk1b = w7b + 65536;
  ushort* Wv1b = w7b + 131072;     ushort* Wk2b = w7b + 196608;
  ushort* Wv2b = w7b + 262144;     ushort* Wf1b = w7b + 327680;
  ushort* Wf2b = w7b + 393216;

  // ---- table / last / q1_1 (fp32 path)
  build_tab<<<50, 256, 0, stream>>>(TAB);
  last_srl_kernel<<<Bsz, 256, 0, stream>>>(mask, seq1, lastp, srl);
  gemm_tile<0, 1><<<dim3(4, 4), 256, 0, stream>>>(srl, Wone, bone, q11, 512, 256, 256);
  add_tab0<<<512, 256, 0, stream>>>(q11);

  // ---- weight casts
  cast_f2b_k<<<6400, 256, 0, stream>>>(seq2, bufS, 1638400);
  cast_f2b_k<<<192, 256, 0, stream>>>(wih0, wih0b, 49152);
  cast_f2b_k<<<192, 256, 0, stream>>>(wih1, wih1b, 49152);
  cast_f2b_k<<<192, 256, 0, stream>>>(whh0, whh0b, 49152);
  cast_f2b_k<<<192, 256, 0, stream>>>(whh1, whh1b, 49152);
  Cast7 c7;
  c7.s[0] = Wq1; c7.s[1] = Wk1; c7.s[2] = Wv1; c7.s[3] = Wk2; c7.s[4] = Wv2;
  c7.s[5] = Wffn1; c7.s[6] = Wffn2;
  c7.d[0] = Wq1b; c7.d[1] = Wk1b; c7.d[2] = Wv1b; c7.d[3] = Wk2b; c7.d[4] = Wv2b;
  c7.d[5] = Wf1b; c7.d[6] = Wf2b;
  cast7_k<<<dim3(64, 7), 256, 0, stream>>>(c7);

  // ---- GRU (gi via MFMA, recurrence via 8-wave/2-sample MFMA kernel, 1 barrier/step)
  mfma_gemm<1, 1, 0><<<dim3(6, 200), 256, 0, stream>>>(bufS, wih0b, bih0, gi, 25600, 768, 256);
  gru_mfma8_kernel<<<256, 512, 0, stream>>>(gi, whh0b, bhh0, bufS, nullptr);
  mfma_gemm<1, 1, 0><<<dim3(6, 200), 256, 0, stream>>>(bufS, wih1b, bih1, gi, 25600, 768, 256);
  gru_mfma8_kernel<<<256, 512, 0, stream>>>(gi, whh1b, bhh1, bufS, mask);   // -> se2 bf16

  // ---- masked seq1 (bf16 only; alpha_sess reads seq1 raw — ash zeros masked rows exactly)
  mask_cast<<<25600, 256, 0, stream>>>(seq1, mask, se1b);

  // ---- projections (MFMA, bf16 out); PE is added during attention staging (fused)
  mfma_gemm<0, 0, 1><<<dim3(2, 200), 256, 0, stream>>>(bufS, Wk2b, nullptr, k2b, 25600, 256, 256);
  mfma_gemm<0, 0, 1><<<dim3(2, 200), 256, 0, stream>>>(bufS, Wv2b, nullptr, v2b, 25600, 256, 256);
  mfma_gemm<0, 0, 1><<<dim3(2, 200), 256, 0, stream>>>(se1b, Wq1b, nullptr, q1b, 25600, 256, 256);
  mfma_gemm<0, 0, 1><<<dim3(2, 200), 256, 0, stream>>>(se1b, Wk1b, nullptr, k1b, 25600, 256, 256);
  mfma_gemm<0, 0, 1><<<dim3(2, 200), 256, 0, stream>>>(se1b, Wv1b, nullptr, v1b, 25600, 256, 256);

  // ---- attentions (MFMA, bf16 in, bf16 out; PE fused into staging)
  attn_mfma<0, 1, 1><<<Bsz, 256, 0, stream>>>(q1b, k1b, v1b, nullptr, nullptr, mask, ao1b, TAB, lastp);
  attn_mfma<8, 1, 0><<<Bsz, 256, 0, stream>>>(q1b, k2b, v2b, memk, memv, mask, ao2b, TAB, lastp);
  mfma_gemm<0, 1, 0><<<dim3(2, 200), 256, 0, stream>>>(ao1b, Wf1b, bffn1, kv2a, 25600, 256, 256);
  mfma_gemm<0, 1, 0><<<dim3(2, 200), 256, 0, stream>>>(ao2b, Wf2b, bffn2, kv2b, 25600, 256, 256);

  // ---- pooling + session (fp32; relu(att1p+att2p) fused into alpha)
  alpha_sess_kernel<<<Bsz, 256, 0, stream>>>(kv2a, kv2b, W3, q11, seq1, mask, srl, sesscat);
  gemm_tile<0, 1><<<dim3(4, 4), 256, 0, stream>>>(sesscat, Wtr, btr, sess2, 512, 256, 512);
  cast_f2b_k<<<128, 256, 0, stream>>>(sess2, sess2b, 32768);

  // ---- tail gating (fp32) + scoring (MFMA) + fused softmax/final
  hipMemsetAsync(bnd, 0, 4, stream);
  beta_kernel<<<Bsz, 256, 0, stream>>>(sess2, Wt1, bt1, Wt2, betab, bnd);
  cast_f2b_k<<<10000, 256, 0, stream>>>(emb1 + 256, embB, 2560000);
  mfma_gemm<1, 0, 0><<<dim3(313, 4), 256, 0, stream>>>(sess2b, embB, nullptr, out, 512, VM1, 256);
  score_final_fused<<<Bsz, 1024, 0, stream>>>(out, iflag, betab);

  (void)in_sizes; (void)n_in; (void)out_size; (void)ws_size; (void)se1;
}